// Round 2
// baseline (2404.558 us; speedup 1.0000x reference)
//
#include <hip/hip_runtime.h>
#include <hip/hip_bf16.h>

// Problem constants
#define NN   20000          // nodes
#define DIN_ 92             // atom feature dim
#define CC   128            // hidden dim
#define EE   640000         // edges
#define ESL  (EE + NN)      // edges + self loops = 660000
#define BN_EPS 1e-5f

// ---------------------------------------------------------------------------
// Dual-dtype helpers: flags[0]=1 -> floats are fp32 (else bf16)
//                     flags[1]=1 -> edge_index is int64 (else int32)
// ---------------------------------------------------------------------------
static __device__ __forceinline__ float ldf(const void* p, int i, int f32) {
    return f32 ? ((const float*)p)[i]
               : __bfloat162float(((const __hip_bfloat16*)p)[i]);
}
static __device__ __forceinline__ void stf(void* p, int i, float v, int f32) {
    if (f32) ((float*)p)[i] = v;
    else     ((__hip_bfloat16*)p)[i] = __float2bfloat16(v);
}
static __device__ __forceinline__ void edge_sd(const void* ei, int e, int i64,
                                               int& s, int& d) {
    if (e < EE) {
        if (i64) { s = (int)((const long long*)ei)[e]; d = (int)((const long long*)ei)[EE + e]; }
        else     { s = ((const int*)ei)[e];            d = ((const int*)ei)[EE + e]; }
    } else { s = e - EE; d = s; }   // self loop
}
static __device__ __forceinline__ float leaky02(float x) { return x > 0.f ? x : 0.2f * x; }

// ---------------------------------------------------------------------------
// Runtime dtype detection (runs every launch; writes flags into ws)
// ---------------------------------------------------------------------------
__global__ void detect_kernel(const unsigned int* __restrict__ x0,
                              const unsigned int* __restrict__ ei,
                              int* __restrict__ flags)
{
    __shared__ int cnt_band, cnt_zero;
    if (threadIdx.x == 0) { cnt_band = 0; cnt_zero = 0; }
    __syncthreads();
    // float mode: low 16 bits of each word are a bf16 value iff data is bf16
    unsigned w  = x0[threadIdx.x];
    unsigned eb = ((w & 0xFFFFu) >> 7) & 0xFFu;   // exponent of low-half-as-bf16
    if (eb >= 90u && eb <= 140u) atomicAdd(&cnt_band, 1);
    // int mode: odd 32-bit words are all zero iff int64 (values < 2^31)
    if (ei[2 * threadIdx.x + 1] == 0u) atomicAdd(&cnt_zero, 1);
    __syncthreads();
    if (threadIdx.x == 0) {
        flags[0] = (cnt_band < 200) ? 1 : 0;   // 1 = fp32
        flags[1] = (cnt_zero >= 250) ? 1 : 0;  // 1 = int64
    }
}

// ---------------------------------------------------------------------------
// Generic small-N GEMM: C[M,NC] = (A [+A2] [+abias]) @ W + bias
// A: external (dual-dtype) if a_ext, else fp32 workspace. W/bias/abias external.
// ---------------------------------------------------------------------------
template<int K, int NC, int ROWS>
__global__ __launch_bounds__(NC) void gemm_kernel(
    const void* __restrict__ A, int a_ext,
    const float* __restrict__ A2, const void* __restrict__ abias,
    const void* __restrict__ W, const void* __restrict__ bias,
    float* __restrict__ Cout, int M, const int* __restrict__ flags)
{
    const int f32 = flags[0];
    __shared__ float As[ROWS][K];
    const int row0 = blockIdx.x * ROWS;
    for (int idx = threadIdx.x; idx < ROWS * K; idx += NC) {
        int r = idx / K, k = idx - r * K;
        int row = row0 + r;
        float v = 0.f;
        if (row < M) {
            int g = row * K + k;
            v = a_ext ? ldf(A, g, f32) : ((const float*)A)[g];
            if (A2)    v += A2[g];
            if (abias) v += ldf(abias, k, f32);
        }
        As[r][k] = v;
    }
    __syncthreads();
    const int col = threadIdx.x;
    float acc[ROWS];
#pragma unroll
    for (int r = 0; r < ROWS; r++) acc[r] = 0.f;
    for (int k = 0; k < K; k++) {
        float w = ldf(W, k * NC + col, f32);
#pragma unroll
        for (int r = 0; r < ROWS; r++) acc[r] += As[r][k] * w;
    }
    float b = bias ? ldf(bias, col, f32) : 0.f;
#pragma unroll
    for (int r = 0; r < ROWS; r++) {
        int row = row0 + r;
        if (row < M) Cout[row * NC + col] = acc[r] + b;
    }
}

// ---------------------------------------------------------------------------
// BatchNorm (training): column sums / sumsq over node axis
// ---------------------------------------------------------------------------
__global__ void bn_stats_kernel(const float* __restrict__ Y,
                                float* __restrict__ sums, float* __restrict__ sumsq)
{
    int c  = threadIdx.x & (CC - 1);
    int rg = threadIdx.x >> 7;
    int stride = gridDim.x * 2;
    float s = 0.f, q = 0.f;
    for (int r = blockIdx.x * 2 + rg; r < NN; r += stride) {
        float v = Y[r * CC + c];
        s += v; q += v * v;
    }
    atomicAdd(&sums[c], s);
    atomicAdd(&sumsq[c], q);
}

__global__ void bn_relu_kernel(const float* __restrict__ Y, float* __restrict__ X,
                               const float* __restrict__ sums, const float* __restrict__ sumsq,
                               const void* __restrict__ g, const void* __restrict__ be,
                               const int* __restrict__ flags)
{
    const int f32 = flags[0];
    int idx = blockIdx.x * blockDim.x + threadIdx.x;
    if (idx >= NN * CC) return;
    int c = idx & (CC - 1);
    float mean = sums[c] * (1.f / NN);
    float var  = sumsq[c] * (1.f / NN) - mean * mean;
    float inv  = rsqrtf(fmaxf(var, 0.f) + BN_EPS);
    float v = (Y[idx] - mean) * inv * ldf(g, c, f32) + ldf(be, c, f32);
    X[idx] = v > 0.f ? v : 0.f;
}

// ---------------------------------------------------------------------------
// GIN aggregation: AGG[dst] += X[src]
// ---------------------------------------------------------------------------
__global__ void gin_scatter_kernel(const float* __restrict__ X, float* __restrict__ AGG,
                                   const void* __restrict__ ei, const int* __restrict__ flags)
{
    const int i64 = flags[1];
    int idx = blockIdx.x * blockDim.x + threadIdx.x;   // < EE*CC
    int e = idx >> 7, c = idx & 127;
    int s, d;
    if (i64) { s = (int)((const long long*)ei)[e]; d = (int)((const long long*)ei)[EE + e]; }
    else     { s = ((const int*)ei)[e];            d = ((const int*)ei)[EE + e]; }
    atomicAdd(&AGG[d * CC + c], X[s * CC + c]);
}

// ---------------------------------------------------------------------------
// VAE reparameterization + write zin/mu/logvar outputs
// ---------------------------------------------------------------------------
__global__ void z_kernel(const float* __restrict__ MU, const float* __restrict__ LV,
                         const void* __restrict__ eps,
                         float* __restrict__ Z, void* __restrict__ out,
                         const int* __restrict__ flags)
{
    const int f32 = flags[0];
    int idx = blockIdx.x * blockDim.x + threadIdx.x;
    if (idx >= NN * CC) return;
    float mu = MU[idx], lv = LV[idx];
    float z = ldf(eps, idx, f32) * expf(0.5f * lv) + mu;
    Z[idx] = z;
    stf(out, idx, z, f32);                  // zin
    stf(out, 2 * NN * CC + idx, mu, f32);   // mu
    stf(out, 3 * NN * CC + idx, lv, f32);   // logvar
}

// ---------------------------------------------------------------------------
// GAT attention scores per (node, head)
// ---------------------------------------------------------------------------
__global__ void att_kernel(const float* __restrict__ HHp,
                           const void* __restrict__ att_src, const void* __restrict__ att_dst,
                           float* __restrict__ AS, float* __restrict__ AD,
                           const int* __restrict__ flags)
{
    const int f32 = flags[0];
    int wid  = (blockIdx.x * blockDim.x + threadIdx.x) >> 6;
    int lane = threadIdx.x & 63;
    if (wid >= NN * 2) return;
    int n = wid >> 1, h = wid & 1;
    int base = n * 256 + h * CC;
    float v1 = HHp[base + lane], v2 = HHp[base + lane + 64];
    float s = v1 * ldf(att_src, h * CC + lane, f32) + v2 * ldf(att_src, h * CC + lane + 64, f32);
    float d = v1 * ldf(att_dst, h * CC + lane, f32) + v2 * ldf(att_dst, h * CC + lane + 64, f32);
#pragma unroll
    for (int off = 32; off; off >>= 1) {
        s += __shfl_down(s, off);
        d += __shfl_down(d, off);
    }
    if (lane == 0) { AS[wid] = s; AD[wid] = d; }
}

// segment max via order-preserving uint encoding (DMAX zeroed beforehand;
// every node has a self-loop so every slot gets at least one real value)
__global__ void edge_max_kernel(const void* __restrict__ ei,
                                const float* __restrict__ AS, const float* __restrict__ AD,
                                unsigned int* __restrict__ DMAXE, const int* __restrict__ flags)
{
    const int i64 = flags[1];
    int idx = blockIdx.x * blockDim.x + threadIdx.x;
    if (idx >= ESL * 2) return;
    int e = idx >> 1, h = idx & 1, s, d;
    edge_sd(ei, e, i64, s, d);
    float l = leaky02(AS[s * 2 + h] + AD[d * 2 + h]);
    unsigned int ub = __float_as_uint(l);
    ub = (ub & 0x80000000u) ? ~ub : (ub | 0x80000000u);
    atomicMax(&DMAXE[d * 2 + h], ub);
}

__global__ void decode_max_kernel(float* __restrict__ DMAX)
{
    int idx = blockIdx.x * blockDim.x + threadIdx.x;
    if (idx >= NN * 2) return;
    unsigned int u = ((unsigned int*)DMAX)[idx];
    unsigned int bits = (u & 0x80000000u) ? (u & 0x7fffffffu) : ~u;
    DMAX[idx] = __uint_as_float(bits);
}

__global__ void edge_exp_kernel(const void* __restrict__ ei,
                                const float* __restrict__ AS, const float* __restrict__ AD,
                                const float* __restrict__ DMAX, float* __restrict__ DSUM,
                                const int* __restrict__ flags)
{
    const int i64 = flags[1];
    int idx = blockIdx.x * blockDim.x + threadIdx.x;
    if (idx >= ESL * 2) return;
    int e = idx >> 1, h = idx & 1, s, d;
    edge_sd(ei, e, i64, s, d);
    float l = leaky02(AS[s * 2 + h] + AD[d * 2 + h]);
    atomicAdd(&DSUM[d * 2 + h], expf(l - DMAX[d * 2 + h]));
}

// message passing: OUT[dst,h,:] += alpha * HH[src,h,:]  (block = 1 edge)
__global__ void gat_message_kernel(const void* __restrict__ ei,
                                   const float* __restrict__ HHp,
                                   const float* __restrict__ AS, const float* __restrict__ AD,
                                   const float* __restrict__ DMAX, const float* __restrict__ DSUM,
                                   float* __restrict__ OUT, const int* __restrict__ flags)
{
    const int i64 = flags[1];
    int e = blockIdx.x;
    int h = threadIdx.x >> 7, c = threadIdx.x & 127;
    int s, d;
    edge_sd(ei, e, i64, s, d);
    float l = leaky02(AS[s * 2 + h] + AD[d * 2 + h]);
    float alpha = expf(l - DMAX[d * 2 + h]) / DSUM[d * 2 + h];
    atomicAdd(&OUT[d * 256 + h * CC + c], alpha * HHp[s * 256 + h * CC + c]);
}

__global__ void store_out_kernel(const float* __restrict__ srcv, void* __restrict__ out,
                                 int off, const int* __restrict__ flags)
{
    const int f32 = flags[0];
    int idx = blockIdx.x * blockDim.x + threadIdx.x;
    if (idx >= NN * CC) return;
    stf(out, off + idx, srcv[idx], f32);
}

// ---------------------------------------------------------------------------
extern "C" void kernel_launch(void* const* d_in, const int* in_sizes, int n_in,
                              void* d_out, int out_size, void* d_ws, size_t ws_size,
                              hipStream_t stream)
{
    const void* xin    = d_in[0];
    const void* ei     = d_in[1];
    const void* eps    = d_in[2];
    const void* W_emb  = d_in[3];
    const void* b_emb  = d_in[4];
    const void* g_emb  = d_in[5];
    const void* be_emb = d_in[6];
    const void* W1     = d_in[7];
    const void* b1     = d_in[8];
    const void* g1     = d_in[9];
    const void* be1    = d_in[10];
    const void* W2     = d_in[11];
    const void* b2     = d_in[12];
    const void* W_mu   = d_in[13];
    const void* b_mu   = d_in[14];
    const void* W_var  = d_in[15];
    const void* b_var  = d_in[16];
    const void* W_gat  = d_in[17];
    const void* attS   = d_in[18];
    const void* attD   = d_in[19];
    const void* b_gat  = d_in[20];
    const void* W_dec  = d_in[21];
    const void* b_dec  = d_in[22];

    // workspace layout (fp32 elements): 5*NB + tail = 51.9 MB
    float* ws = (float*)d_ws;
    const size_t NB = (size_t)NN * CC;       // 2,560,000
    float* B0 = ws;
    float* B1 = ws + 1 * NB;
    float* B2 = ws + 2 * NB;
    float* B3 = ws + 3 * NB;
    float* B4 = ws + 4 * NB;
    float* TAIL  = ws + 5 * NB;
    float* AS    = TAIL;                     // 40000
    float* AD    = TAIL + 40000;             // 40000
    float* DSUM  = TAIL + 80000;             // 40000
    float* DMAX  = TAIL + 120000;            // 40000
    float* SUMS  = TAIL + 160000;            // 128
    float* SUMSQ = TAIL + 160128;            // 128
    int*   FLAGS = (int*)(TAIL + 160256);    // 16

    detect_kernel<<<1, 256, 0, stream>>>((const unsigned int*)xin,
                                         (const unsigned int*)ei, FLAGS);

    // -------- Stage A: atom embedding = relu(BN(x @ W_emb + b_emb)) --------
    hipMemsetAsync(SUMS, 0, 2 * CC * sizeof(float), stream);
    gemm_kernel<DIN_, CC, 4><<<NN / 4, CC, 0, stream>>>(
        xin, 1, nullptr, nullptr, W_emb, b_emb, B1, NN, FLAGS);
    bn_stats_kernel<<<256, 256, 0, stream>>>(B1, SUMS, SUMSQ);
    bn_relu_kernel<<<(NN * CC) / 256, 256, 0, stream>>>(B1, B0, SUMS, SUMSQ, g_emb, be_emb, FLAGS);

    // -------- Stage B: GIN x2 (shared weights): x = W2( relu(BN(W1(x+agg))) ) --------
    for (int t = 0; t < 2; t++) {
        hipMemsetAsync(B2, 0, NB * sizeof(float), stream);
        gin_scatter_kernel<<<(EE * CC) / 256, 256, 0, stream>>>(B0, B2, ei, FLAGS);
        hipMemsetAsync(SUMS, 0, 2 * CC * sizeof(float), stream);
        gemm_kernel<CC, CC, 4><<<NN / 4, CC, 0, stream>>>(
            B0, 0, B2, nullptr, W1, b1, B1, NN, FLAGS);
        bn_stats_kernel<<<256, 256, 0, stream>>>(B1, SUMS, SUMSQ);
        bn_relu_kernel<<<(NN * CC) / 256, 256, 0, stream>>>(B1, B1, SUMS, SUMSQ, g1, be1, FLAGS);
        gemm_kernel<CC, CC, 4><<<NN / 4, CC, 0, stream>>>(
            B1, 0, nullptr, nullptr, W2, b2, B0, NN, FLAGS);
    }

    // -------- Stage C: VAE heads (x in B0 -> MU B1, LV B2, Z B3) --------
    gemm_kernel<CC, CC, 4><<<NN / 4, CC, 0, stream>>>(
        B0, 0, nullptr, nullptr, W_mu, b_mu, B1, NN, FLAGS);
    gemm_kernel<CC, CC, 4><<<NN / 4, CC, 0, stream>>>(
        B0, 0, nullptr, nullptr, W_var, b_var, B2, NN, FLAGS);
    z_kernel<<<(NN * CC) / 256, 256, 0, stream>>>(B1, B2, eps, B3, d_out, FLAGS);

    // -------- Stage D: GAT x2 (shared weights) --------
    // zcur: B3 (t=0) then B4; HH spans B0|B1; OUT spans B2|B3 (zcur dead by then)
    float* zc = B3;
    for (int t = 0; t < 2; t++) {
        float* HHb = B0;   // N x 256
        float* OUT = B2;   // N x 256
        gemm_kernel<CC, 2 * CC, 4><<<NN / 4, 2 * CC, 0, stream>>>(
            zc, 0, nullptr, nullptr, W_gat, nullptr, HHb, NN, FLAGS);
        att_kernel<<<(NN * 2) / 4, 256, 0, stream>>>(HHb, attS, attD, AS, AD, FLAGS);
        hipMemsetAsync(DSUM, 0, 2 * 40000 * sizeof(float), stream);  // DSUM + DMAX
        edge_max_kernel<<<(ESL * 2 + 255) / 256, 256, 0, stream>>>(
            ei, AS, AD, (unsigned int*)DMAX, FLAGS);
        decode_max_kernel<<<(NN * 2 + 255) / 256, 256, 0, stream>>>(DMAX);
        edge_exp_kernel<<<(ESL * 2 + 255) / 256, 256, 0, stream>>>(
            ei, AS, AD, DMAX, DSUM, FLAGS);
        hipMemsetAsync(OUT, 0, 2 * NB * sizeof(float), stream);
        gat_message_kernel<<<ESL, 256, 0, stream>>>(
            ei, HHb, AS, AD, DMAX, DSUM, OUT, FLAGS);
        gemm_kernel<2 * CC, CC, 4><<<NN / 4, CC, 0, stream>>>(
            OUT, 0, nullptr, b_gat, W_dec, b_dec, B4, NN, FLAGS);
        zc = B4;
    }

    // zout
    store_out_kernel<<<(NN * CC) / 256, 256, 0, stream>>>(zc, d_out, NN * CC, FLAGS);
}

// Round 3
// 1166.906 us; speedup vs baseline: 2.0606x; 2.0606x over previous
//
#include <hip/hip_runtime.h>
#include <hip/hip_bf16.h>

// Problem constants
#define NN   20000          // nodes
#define DIN_ 92             // atom feature dim
#define CC   128            // hidden dim
#define EE   640000         // edges (self loops handled explicitly)
#define BN_EPS 1e-5f
#define NEG_INF (-3.0e38f)

// ---------------------------------------------------------------------------
// Dual-dtype helpers: flags[0]=1 -> floats are fp32 (else bf16)
//                     flags[1]=1 -> edge_index is int64 (else int32)
// ---------------------------------------------------------------------------
static __device__ __forceinline__ float ldf(const void* p, int i, int f32) {
    return f32 ? ((const float*)p)[i]
               : __bfloat162float(((const __hip_bfloat16*)p)[i]);
}
static __device__ __forceinline__ void stf(void* p, int i, float v, int f32) {
    if (f32) ((float*)p)[i] = v;
    else     ((__hip_bfloat16*)p)[i] = __float2bfloat16(v);
}
static __device__ __forceinline__ float leaky02(float x) { return x > 0.f ? x : 0.2f * x; }

// ---------------------------------------------------------------------------
// Runtime dtype detection (runs every launch; writes flags into ws)
// ---------------------------------------------------------------------------
__global__ void detect_kernel(const unsigned int* __restrict__ x0,
                              const unsigned int* __restrict__ ei,
                              int* __restrict__ flags)
{
    __shared__ int cnt_band, cnt_zero;
    if (threadIdx.x == 0) { cnt_band = 0; cnt_zero = 0; }
    __syncthreads();
    unsigned w  = x0[threadIdx.x];
    unsigned eb = ((w & 0xFFFFu) >> 7) & 0xFFu;
    if (eb >= 90u && eb <= 140u) atomicAdd(&cnt_band, 1);
    if (ei[2 * threadIdx.x + 1] == 0u) atomicAdd(&cnt_zero, 1);
    __syncthreads();
    if (threadIdx.x == 0) {
        flags[0] = (cnt_band < 200) ? 1 : 0;   // 1 = fp32
        flags[1] = (cnt_zero >= 250) ? 1 : 0;  // 1 = int64
    }
}

// ---------------------------------------------------------------------------
// CSR build: histogram -> single-block scan -> scatter (sorted by dst)
// ---------------------------------------------------------------------------
__global__ void hist_kernel(const void* __restrict__ ei, int* __restrict__ deg,
                            const int* __restrict__ flags)
{
    int e = blockIdx.x * blockDim.x + threadIdx.x;
    if (e >= EE) return;
    const int i64 = flags[1];
    int d = i64 ? (int)((const long long*)ei)[EE + e] : ((const int*)ei)[EE + e];
    atomicAdd(&deg[d], 1);
}

__global__ __launch_bounds__(256) void scan_kernel(const int* __restrict__ deg,
                                                   int* __restrict__ off,
                                                   int* __restrict__ cur)
{
    __shared__ int ssum[256];
    const int CH = (NN + 255) / 256;   // 79
    int tid = threadIdx.x;
    int base = tid * CH;
    int s = 0;
    for (int i = 0; i < CH; i++) { int idx = base + i; if (idx < NN) s += deg[idx]; }
    ssum[tid] = s;
    __syncthreads();
    for (int st = 1; st < 256; st <<= 1) {
        int t = (tid >= st) ? ssum[tid - st] : 0;
        __syncthreads();
        ssum[tid] += t;
        __syncthreads();
    }
    int run = ssum[tid] - s;           // exclusive prefix
    for (int i = 0; i < CH; i++) {
        int idx = base + i;
        if (idx < NN) { off[idx] = run; cur[idx] = run; run += deg[idx]; }
    }
    if (tid == 255) off[NN] = ssum[255];
}

__global__ void scatter_kernel(const void* __restrict__ ei, int* __restrict__ cur,
                               int* __restrict__ csr, const int* __restrict__ flags)
{
    int e = blockIdx.x * blockDim.x + threadIdx.x;
    if (e >= EE) return;
    const int i64 = flags[1];
    int s, d;
    if (i64) { s = (int)((const long long*)ei)[e]; d = (int)((const long long*)ei)[EE + e]; }
    else     { s = ((const int*)ei)[e];            d = ((const int*)ei)[EE + e]; }
    int pos = atomicAdd(&cur[d], 1);
    csr[pos] = s;
}

// ---------------------------------------------------------------------------
// Generic small-N GEMM: C[M,NC] = (A [+abias]) @ W + bias
// ---------------------------------------------------------------------------
template<int K, int NC, int ROWS>
__global__ __launch_bounds__(NC) void gemm_kernel(
    const void* __restrict__ A, int a_ext,
    const void* __restrict__ abias,
    const void* __restrict__ W, const void* __restrict__ bias,
    float* __restrict__ Cout, int M, const int* __restrict__ flags)
{
    const int f32 = flags[0];
    __shared__ float As[ROWS][K];
    const int row0 = blockIdx.x * ROWS;
    for (int idx = threadIdx.x; idx < ROWS * K; idx += NC) {
        int r = idx / K, k = idx - r * K;
        int row = row0 + r;
        float v = 0.f;
        if (row < M) {
            int g = row * K + k;
            v = a_ext ? ldf(A, g, f32) : ((const float*)A)[g];
            if (abias) v += ldf(abias, k, f32);
        }
        As[r][k] = v;
    }
    __syncthreads();
    const int col = threadIdx.x;
    float acc[ROWS];
#pragma unroll
    for (int r = 0; r < ROWS; r++) acc[r] = 0.f;
    for (int k = 0; k < K; k++) {
        float w = ldf(W, k * NC + col, f32);
#pragma unroll
        for (int r = 0; r < ROWS; r++) acc[r] += As[r][k] * w;
    }
    float b = bias ? ldf(bias, col, f32) : 0.f;
#pragma unroll
    for (int r = 0; r < ROWS; r++) {
        int row = row0 + r;
        if (row < M) Cout[row * NC + col] = acc[r] + b;
    }
}

// ---------------------------------------------------------------------------
// BatchNorm (training): column sums / sumsq, then normalize+ReLU
// ---------------------------------------------------------------------------
__global__ void bn_stats_kernel(const float* __restrict__ Y,
                                float* __restrict__ sums, float* __restrict__ sumsq)
{
    int c  = threadIdx.x & (CC - 1);
    int rg = threadIdx.x >> 7;
    int stride = gridDim.x * 2;
    float s = 0.f, q = 0.f;
    for (int r = blockIdx.x * 2 + rg; r < NN; r += stride) {
        float v = Y[r * CC + c];
        s += v; q += v * v;
    }
    atomicAdd(&sums[c], s);
    atomicAdd(&sumsq[c], q);
}

__global__ void bn_relu_kernel(const float* __restrict__ Y, float* __restrict__ X,
                               const float* __restrict__ sums, const float* __restrict__ sumsq,
                               const void* __restrict__ g, const void* __restrict__ be,
                               const int* __restrict__ flags)
{
    const int f32 = flags[0];
    int idx = blockIdx.x * blockDim.x + threadIdx.x;
    if (idx >= NN * CC) return;
    int c = idx & (CC - 1);
    float mean = sums[c] * (1.f / NN);
    float var  = sumsq[c] * (1.f / NN) - mean * mean;
    float inv  = rsqrtf(fmaxf(var, 0.f) + BN_EPS);
    float v = (Y[idx] - mean) * inv * ldf(g, c, f32) + ldf(be, c, f32);
    X[idx] = v > 0.f ? v : 0.f;
}

// ---------------------------------------------------------------------------
// GIN: H[d] = X[d] + sum_{s in N(d)} X[s]   (CSR gather, no atomics)
// ---------------------------------------------------------------------------
__global__ __launch_bounds__(128) void gin_gather_kernel(
    const float* __restrict__ X, float* __restrict__ H,
    const int* __restrict__ off, const int* __restrict__ csr)
{
    int d = blockIdx.x, c = threadIdx.x;
    int b = off[d], e = off[d + 1];
    float acc = X[d * CC + c];
    __shared__ int ssrc[128];
    for (int chunk = b; chunk < e; chunk += 128) {
        int n = min(128, e - chunk);
        if (c < n) ssrc[c] = csr[chunk + c];
        __syncthreads();
        for (int j = 0; j < n; j++) acc += X[ssrc[j] * CC + c];
        __syncthreads();
    }
    H[d * CC + c] = acc;
}

// ---------------------------------------------------------------------------
// VAE reparameterization + write zin/mu/logvar outputs
// ---------------------------------------------------------------------------
__global__ void z_kernel(const float* __restrict__ MU, const float* __restrict__ LV,
                         const void* __restrict__ eps,
                         float* __restrict__ Z, void* __restrict__ out,
                         const int* __restrict__ flags)
{
    const int f32 = flags[0];
    int idx = blockIdx.x * blockDim.x + threadIdx.x;
    if (idx >= NN * CC) return;
    float mu = MU[idx], lv = LV[idx];
    float z = ldf(eps, idx, f32) * expf(0.5f * lv) + mu;
    Z[idx] = z;
    stf(out, idx, z, f32);                  // zin
    stf(out, 2 * NN * CC + idx, mu, f32);   // mu
    stf(out, 3 * NN * CC + idx, lv, f32);   // logvar
}

// ---------------------------------------------------------------------------
// GAT attention scores per (node, head)
// ---------------------------------------------------------------------------
__global__ void att_kernel(const float* __restrict__ HHp,
                           const void* __restrict__ att_src, const void* __restrict__ att_dst,
                           float* __restrict__ AS, float* __restrict__ AD,
                           const int* __restrict__ flags)
{
    const int f32 = flags[0];
    int wid  = (blockIdx.x * blockDim.x + threadIdx.x) >> 6;
    int lane = threadIdx.x & 63;
    if (wid >= NN * 2) return;
    int n = wid >> 1, h = wid & 1;
    int base = n * 256 + h * CC;
    float v1 = HHp[base + lane], v2 = HHp[base + lane + 64];
    float s = v1 * ldf(att_src, h * CC + lane, f32) + v2 * ldf(att_src, h * CC + lane + 64, f32);
    float d = v1 * ldf(att_dst, h * CC + lane, f32) + v2 * ldf(att_dst, h * CC + lane + 64, f32);
#pragma unroll
    for (int off = 32; off; off >>= 1) {
        s += __shfl_down(s, off);
        d += __shfl_down(d, off);
    }
    if (lane == 0) { AS[wid] = s; AD[wid] = d; }
}

// ---------------------------------------------------------------------------
// GAT softmax stats per (node, head): wave loops CSR edge list + self loop
// ---------------------------------------------------------------------------
__global__ void gat_stats_kernel(const float* __restrict__ AS, const float* __restrict__ AD,
                                 const int* __restrict__ off, const int* __restrict__ csr,
                                 float* __restrict__ DMAX, float* __restrict__ DINV)
{
    int wid  = (blockIdx.x * blockDim.x + threadIdx.x) >> 6;
    int lane = threadIdx.x & 63;
    if (wid >= NN * 2) return;
    int n = wid >> 1, h = wid & 1;
    int b = off[n], e = off[n + 1];
    float adh = AD[n * 2 + h];
    float self_l = leaky02(AS[n * 2 + h] + adh);
    float m = (lane == 0) ? self_l : NEG_INF;
    for (int i = b + lane; i < e; i += 64) {
        int s = csr[i];
        m = fmaxf(m, leaky02(AS[s * 2 + h] + adh));
    }
#pragma unroll
    for (int o = 32; o; o >>= 1) m = fmaxf(m, __shfl_xor(m, o));
    float sum = (lane == 0) ? expf(self_l - m) : 0.f;
    for (int i = b + lane; i < e; i += 64) {
        int s = csr[i];
        sum += expf(leaky02(AS[s * 2 + h] + adh) - m);
    }
#pragma unroll
    for (int o = 32; o; o >>= 1) sum += __shfl_xor(sum, o);
    if (lane == 0) { DMAX[wid] = m; DINV[wid] = 1.f / sum; }
}

// ---------------------------------------------------------------------------
// GAT aggregation + fused decoder: per node d,
//   out[h,c] = sum_e alpha_e * HH[s_e, h, c]  (+ self loop) + b_gat
//   Z[d, :]  = out @ W_dec + b_dec
// ---------------------------------------------------------------------------
__global__ __launch_bounds__(256) void gat_agg_dec_kernel(
    const float* __restrict__ HHp,
    const float* __restrict__ AS, const float* __restrict__ AD,
    const float* __restrict__ DMAX, const float* __restrict__ DINV,
    const int* __restrict__ off, const int* __restrict__ csr,
    const void* __restrict__ b_gat, const void* __restrict__ W_dec,
    const void* __restrict__ b_dec,
    float* __restrict__ Zout, const int* __restrict__ flags)
{
    const int f32 = flags[0];
    int d = blockIdx.x;
    int t = threadIdx.x, h = t >> 7, c = t & 127;
    float adh = AD[d * 2 + h], m = DMAX[d * 2 + h], inv = DINV[d * 2 + h];
    // self loop
    float a0 = expf(leaky02(AS[d * 2 + h] + adh) - m) * inv;
    float acc = a0 * HHp[d * 256 + t];
    int b = off[d], e = off[d + 1];
    __shared__ int ssrc[64];
    for (int chunk = b; chunk < e; chunk += 64) {
        int n = min(64, e - chunk);
        if (t < n) ssrc[t] = csr[chunk + t];
        __syncthreads();
        for (int j = 0; j < n; j++) {
            int s = ssrc[j];
            float al = expf(leaky02(AS[s * 2 + h] + adh) - m) * inv;
            acc += al * HHp[s * 256 + t];
        }
        __syncthreads();
    }
    // fused decoder matvec: Z[d,c] = sum_j (acc_j + b_gat_j) * W_dec[j,c] + b_dec[c]
    __shared__ float sh[256];
    __shared__ float so[128];
    sh[t] = acc + ldf(b_gat, t, f32);
    __syncthreads();
    float o = 0.f;
    int j0 = h * 128;
    for (int j = 0; j < 128; j++)
        o += sh[j0 + j] * ldf(W_dec, (j0 + j) * 128 + c, f32);
    if (h == 1) so[c] = o;
    __syncthreads();
    if (h == 0) Zout[d * 128 + c] = o + so[c] + ldf(b_dec, c, f32);
}

__global__ void store_out_kernel(const float* __restrict__ srcv, void* __restrict__ out,
                                 int off, const int* __restrict__ flags)
{
    const int f32 = flags[0];
    int idx = blockIdx.x * blockDim.x + threadIdx.x;
    if (idx >= NN * CC) return;
    stf(out, off + idx, srcv[idx], f32);
}

// ---------------------------------------------------------------------------
extern "C" void kernel_launch(void* const* d_in, const int* in_sizes, int n_in,
                              void* d_out, int out_size, void* d_ws, size_t ws_size,
                              hipStream_t stream)
{
    const void* xin    = d_in[0];
    const void* ei     = d_in[1];
    const void* eps    = d_in[2];
    const void* W_emb  = d_in[3];
    const void* b_emb  = d_in[4];
    const void* g_emb  = d_in[5];
    const void* be_emb = d_in[6];
    const void* W1     = d_in[7];
    const void* b1     = d_in[8];
    const void* g1     = d_in[9];
    const void* be1    = d_in[10];
    const void* W2     = d_in[11];
    const void* b2     = d_in[12];
    const void* W_mu   = d_in[13];
    const void* b_mu   = d_in[14];
    const void* W_var  = d_in[15];
    const void* b_var  = d_in[16];
    const void* W_gat  = d_in[17];
    const void* attS   = d_in[18];
    const void* attD   = d_in[19];
    const void* b_gat  = d_in[20];
    const void* W_dec  = d_in[21];
    const void* b_dec  = d_in[22];

    // workspace layout (fp32 elements): 4*NB + tail ≈ 44.3 MB
    float* ws = (float*)d_ws;
    const size_t NB = (size_t)NN * CC;       // 2,560,000
    float* B0 = ws;
    float* B1 = ws + 1 * NB;
    float* B2 = ws + 2 * NB;
    float* B3 = ws + 3 * NB;
    float* TAIL  = ws + 4 * NB;
    float* AS    = TAIL;                     // 40000
    float* AD    = TAIL + 40000;             // 40000
    float* DMAX  = TAIL + 80000;             // 40000
    float* DINV  = TAIL + 120000;            // 40000
    float* SUMS  = TAIL + 160000;            // 128
    float* SUMSQ = TAIL + 160128;            // 128
    int*   FLAGS = (int*)(TAIL + 160256);    // 16
    int*   DEG   = (int*)(TAIL + 160272);    // 20000
    int*   OFF   = DEG + 20000;              // 20001
    int*   CUR   = OFF + 20001;              // 20000
    int*   CSR   = CUR + 20000;              // 640000

    detect_kernel<<<1, 256, 0, stream>>>((const unsigned int*)xin,
                                         (const unsigned int*)ei, FLAGS);

    // -------- CSR build (sorted by destination) --------
    hipMemsetAsync(DEG, 0, NN * sizeof(int), stream);
    hist_kernel<<<(EE + 255) / 256, 256, 0, stream>>>(ei, DEG, FLAGS);
    scan_kernel<<<1, 256, 0, stream>>>(DEG, OFF, CUR);
    scatter_kernel<<<(EE + 255) / 256, 256, 0, stream>>>(ei, CUR, CSR, FLAGS);

    // -------- Stage A: atom embedding = relu(BN(x @ W_emb + b_emb)) --------
    hipMemsetAsync(SUMS, 0, 2 * CC * sizeof(float), stream);
    gemm_kernel<DIN_, CC, 4><<<NN / 4, CC, 0, stream>>>(
        xin, 1, nullptr, W_emb, b_emb, B1, NN, FLAGS);
    bn_stats_kernel<<<256, 256, 0, stream>>>(B1, SUMS, SUMSQ);
    bn_relu_kernel<<<(NN * CC) / 256, 256, 0, stream>>>(B1, B0, SUMS, SUMSQ, g_emb, be_emb, FLAGS);

    // -------- Stage B: GIN x2 (shared weights): x = W2( relu(BN(W1(x+agg))) ) --------
    for (int t = 0; t < 2; t++) {
        gin_gather_kernel<<<NN, 128, 0, stream>>>(B0, B1, OFF, CSR);
        hipMemsetAsync(SUMS, 0, 2 * CC * sizeof(float), stream);
        gemm_kernel<CC, CC, 4><<<NN / 4, CC, 0, stream>>>(
            B1, 0, nullptr, W1, b1, B2, NN, FLAGS);
        bn_stats_kernel<<<256, 256, 0, stream>>>(B2, SUMS, SUMSQ);
        bn_relu_kernel<<<(NN * CC) / 256, 256, 0, stream>>>(B2, B2, SUMS, SUMSQ, g1, be1, FLAGS);
        gemm_kernel<CC, CC, 4><<<NN / 4, CC, 0, stream>>>(
            B2, 0, nullptr, W2, b2, B0, NN, FLAGS);
    }

    // -------- Stage C: VAE heads (x in B0 -> MU B1, LV B2, Z B3) --------
    gemm_kernel<CC, CC, 4><<<NN / 4, CC, 0, stream>>>(
        B0, 0, nullptr, W_mu, b_mu, B1, NN, FLAGS);
    gemm_kernel<CC, CC, 4><<<NN / 4, CC, 0, stream>>>(
        B0, 0, nullptr, W_var, b_var, B2, NN, FLAGS);
    z_kernel<<<(NN * CC) / 256, 256, 0, stream>>>(B1, B2, eps, B3, d_out, FLAGS);

    // -------- Stage D: GAT x2 (shared weights), decoder fused --------
    float* zc = B3;
    float* znext[2] = { B2, B3 };
    for (int t = 0; t < 2; t++) {
        float* HHb = B0;   // spans B0|B1 (N x 256)
        gemm_kernel<CC, 2 * CC, 4><<<NN / 4, 2 * CC, 0, stream>>>(
            zc, 0, nullptr, W_gat, nullptr, HHb, NN, FLAGS);
        att_kernel<<<(NN * 2) / 4, 256, 0, stream>>>(HHb, attS, attD, AS, AD, FLAGS);
        gat_stats_kernel<<<(NN * 2) / 4, 256, 0, stream>>>(AS, AD, OFF, CSR, DMAX, DINV);
        gat_agg_dec_kernel<<<NN, 256, 0, stream>>>(
            HHb, AS, AD, DMAX, DINV, OFF, CSR, b_gat, W_dec, b_dec, znext[t], FLAGS);
        zc = znext[t];
    }

    // zout
    store_out_kernel<<<(NN * CC) / 256, 256, 0, stream>>>(zc, d_out, NN * CC, FLAGS);
}

// Round 4
// 996.093 us; speedup vs baseline: 2.4140x; 1.1715x over previous
//
#include <hip/hip_runtime.h>
#include <hip/hip_bf16.h>

// Problem constants
#define NN   20000          // nodes
#define DIN_ 92             // atom feature dim
#define CC   128            // hidden dim
#define EE   640000         // edges (self loops handled explicitly)
#define BN_EPS 1e-5f
#define NEG_INF (-3.0e38f)

// ---------------------------------------------------------------------------
// Dual-dtype helpers: flags[0]=1 -> floats are fp32 (else bf16)
//                     flags[1]=1 -> edge_index is int64 (else int32)
// ---------------------------------------------------------------------------
static __device__ __forceinline__ float ldf(const void* p, int i, int f32) {
    return f32 ? ((const float*)p)[i]
               : __bfloat162float(((const __hip_bfloat16*)p)[i]);
}
static __device__ __forceinline__ void stf(void* p, int i, float v, int f32) {
    if (f32) ((float*)p)[i] = v;
    else     ((__hip_bfloat16*)p)[i] = __float2bfloat16(v);
}
static __device__ __forceinline__ float leaky02(float x) { return x > 0.f ? x : 0.2f * x; }

// ---------------------------------------------------------------------------
// Runtime dtype detection (runs every launch; writes flags into ws)
// ---------------------------------------------------------------------------
__global__ void detect_kernel(const unsigned int* __restrict__ x0,
                              const unsigned int* __restrict__ ei,
                              int* __restrict__ flags)
{
    __shared__ int cnt_band, cnt_zero;
    if (threadIdx.x == 0) { cnt_band = 0; cnt_zero = 0; }
    __syncthreads();
    unsigned w  = x0[threadIdx.x];
    unsigned eb = ((w & 0xFFFFu) >> 7) & 0xFFu;
    if (eb >= 90u && eb <= 140u) atomicAdd(&cnt_band, 1);
    if (ei[2 * threadIdx.x + 1] == 0u) atomicAdd(&cnt_zero, 1);
    __syncthreads();
    if (threadIdx.x == 0) {
        flags[0] = (cnt_band < 200) ? 1 : 0;   // 1 = fp32
        flags[1] = (cnt_zero >= 250) ? 1 : 0;  // 1 = int64
    }
}

// convert external (bf16|fp32) vector to fp32 workspace
__global__ void cvt_kernel(const void* __restrict__ src, float* __restrict__ dst,
                           int n, const int* __restrict__ flags)
{
    const int f32 = flags[0];
    int i = blockIdx.x * blockDim.x + threadIdx.x;
    if (i < n) dst[i] = ldf(src, i, f32);
}

// ---------------------------------------------------------------------------
// CSR build: histogram -> single-block scan -> scatter (sorted by dst)
// ---------------------------------------------------------------------------
__global__ void hist_kernel(const void* __restrict__ ei, int* __restrict__ deg,
                            const int* __restrict__ flags)
{
    int e = blockIdx.x * blockDim.x + threadIdx.x;
    if (e >= EE) return;
    const int i64 = flags[1];
    int d = i64 ? (int)((const long long*)ei)[EE + e] : ((const int*)ei)[EE + e];
    atomicAdd(&deg[d], 1);
}

__global__ __launch_bounds__(256) void scan_kernel(const int* __restrict__ deg,
                                                   int* __restrict__ off,
                                                   int* __restrict__ cur)
{
    __shared__ int ssum[256];
    const int CH = (NN + 255) / 256;   // 79
    int tid = threadIdx.x;
    int base = tid * CH;
    int s = 0;
    for (int i = 0; i < CH; i++) { int idx = base + i; if (idx < NN) s += deg[idx]; }
    ssum[tid] = s;
    __syncthreads();
    for (int st = 1; st < 256; st <<= 1) {
        int t = (tid >= st) ? ssum[tid - st] : 0;
        __syncthreads();
        ssum[tid] += t;
        __syncthreads();
    }
    int run = ssum[tid] - s;           // exclusive prefix
    for (int i = 0; i < CH; i++) {
        int idx = base + i;
        if (idx < NN) { off[idx] = run; cur[idx] = run; run += deg[idx]; }
    }
    if (tid == 255) off[NN] = ssum[255];
}

__global__ void scatter_kernel(const void* __restrict__ ei, int* __restrict__ cur,
                               int* __restrict__ csr, const int* __restrict__ flags)
{
    int e = blockIdx.x * blockDim.x + threadIdx.x;
    if (e >= EE) return;
    const int i64 = flags[1];
    int s, d;
    if (i64) { s = (int)((const long long*)ei)[e]; d = (int)((const long long*)ei)[EE + e]; }
    else     { s = ((const int*)ei)[e];            d = ((const int*)ei)[EE + e]; }
    int pos = atomicAdd(&cur[d], 1);
    csr[pos] = s;
}

// ---------------------------------------------------------------------------
// GEMM: C[M,NC] = (A [+abias]) @ W + bias, W pre-converted fp32, 8 rows/block
// ---------------------------------------------------------------------------
template<int K, int NC, int ROWS>
__global__ __launch_bounds__(NC) void gemm_kernel(
    const void* __restrict__ A, int a_ext,
    const void* __restrict__ abias,
    const float* __restrict__ W, const void* __restrict__ bias,
    float* __restrict__ Cout, const int* __restrict__ flags)
{
    const int f32 = flags[0];
    __shared__ float As[ROWS][K];
    const int row0 = blockIdx.x * ROWS;
    for (int idx = threadIdx.x; idx < ROWS * K; idx += NC) {
        int r = idx / K, k = idx - r * K;
        int g = (row0 + r) * K + k;
        float v = a_ext ? ldf(A, g, f32) : ((const float*)A)[g];
        if (abias) v += ldf(abias, k, f32);
        As[r][k] = v;
    }
    __syncthreads();
    const int col = threadIdx.x;
    float acc[ROWS];
#pragma unroll
    for (int r = 0; r < ROWS; r++) acc[r] = 0.f;
    for (int k = 0; k < K; k += 4) {
        float w0 = W[(k + 0) * NC + col];
        float w1 = W[(k + 1) * NC + col];
        float w2 = W[(k + 2) * NC + col];
        float w3 = W[(k + 3) * NC + col];
#pragma unroll
        for (int r = 0; r < ROWS; r++)
            acc[r] += As[r][k] * w0 + As[r][k + 1] * w1
                    + As[r][k + 2] * w2 + As[r][k + 3] * w3;
    }
    float b = bias ? ldf(bias, col, f32) : 0.f;
#pragma unroll
    for (int r = 0; r < ROWS; r++)
        Cout[(row0 + r) * NC + col] = acc[r] + b;
}

// ---------------------------------------------------------------------------
// BatchNorm (training): column sums / sumsq, then normalize+ReLU
// ---------------------------------------------------------------------------
__global__ void bn_stats_kernel(const float* __restrict__ Y,
                                float* __restrict__ sums, float* __restrict__ sumsq)
{
    int c  = threadIdx.x & (CC - 1);
    int rg = threadIdx.x >> 7;
    int stride = gridDim.x * 2;
    float s = 0.f, q = 0.f;
    for (int r = blockIdx.x * 2 + rg; r < NN; r += stride) {
        float v = Y[r * CC + c];
        s += v; q += v * v;
    }
    atomicAdd(&sums[c], s);
    atomicAdd(&sumsq[c], q);
}

__global__ void bn_relu_kernel(const float* __restrict__ Y, float* __restrict__ X,
                               const float* __restrict__ sums, const float* __restrict__ sumsq,
                               const void* __restrict__ g, const void* __restrict__ be,
                               const int* __restrict__ flags)
{
    const int f32 = flags[0];
    int idx = blockIdx.x * blockDim.x + threadIdx.x;
    if (idx >= NN * CC) return;
    int c = idx & (CC - 1);
    float mean = sums[c] * (1.f / NN);
    float var  = sumsq[c] * (1.f / NN) - mean * mean;
    float inv  = rsqrtf(fmaxf(var, 0.f) + BN_EPS);
    float v = (Y[idx] - mean) * inv * ldf(g, c, f32) + ldf(be, c, f32);
    X[idx] = v > 0.f ? v : 0.f;
}

// ---------------------------------------------------------------------------
// GIN: H[d] = X[d] + sum_{s in N(d)} X[s]   (float4 gather, 4 edges in flight)
// ---------------------------------------------------------------------------
__global__ __launch_bounds__(128) void gin_gather_kernel(
    const float4* __restrict__ X4, float4* __restrict__ H4,
    const int* __restrict__ off, const int* __restrict__ csr)
{
    int d = blockIdx.x, t = threadIdx.x;
    int g = t >> 5, u = t & 31;        // 4 edge-groups x 32 quads (128 ch)
    float4 acc = make_float4(0.f, 0.f, 0.f, 0.f);
    if (g == 0) acc = X4[d * 32 + u];
    int b = off[d], e = off[d + 1];
    __shared__ int ssrc[64];
    __shared__ float4 sred[128];
    for (int chunk = b; chunk < e; chunk += 64) {
        int n = min(64, e - chunk);
        if (t < n) ssrc[t] = csr[chunk + t];
        __syncthreads();
        for (int j = g; j < n; j += 4) {
            float4 v = X4[ssrc[j] * 32 + u];
            acc.x += v.x; acc.y += v.y; acc.z += v.z; acc.w += v.w;
        }
        __syncthreads();
    }
    sred[t] = acc;
    __syncthreads();
    if (t < 32) {
        float4 a = sred[t], b4 = sred[t + 32], c4 = sred[t + 64], d4 = sred[t + 96];
        a.x += b4.x + c4.x + d4.x;
        a.y += b4.y + c4.y + d4.y;
        a.z += b4.z + c4.z + d4.z;
        a.w += b4.w + c4.w + d4.w;
        H4[d * 32 + t] = a;
    }
}

// ---------------------------------------------------------------------------
// VAE reparameterization + write zin/mu/logvar outputs
// ---------------------------------------------------------------------------
__global__ void z_kernel(const float* __restrict__ MU, const float* __restrict__ LV,
                         const void* __restrict__ eps,
                         float* __restrict__ Z, void* __restrict__ out,
                         const int* __restrict__ flags)
{
    const int f32 = flags[0];
    int idx = blockIdx.x * blockDim.x + threadIdx.x;
    if (idx >= NN * CC) return;
    float mu = MU[idx], lv = LV[idx];
    float z = ldf(eps, idx, f32) * expf(0.5f * lv) + mu;
    Z[idx] = z;
    stf(out, idx, z, f32);                  // zin
    stf(out, 2 * NN * CC + idx, mu, f32);   // mu
    stf(out, 3 * NN * CC + idx, lv, f32);   // logvar
}

// ---------------------------------------------------------------------------
// GAT attention scores per (node, head)
// ---------------------------------------------------------------------------
__global__ void att_kernel(const float* __restrict__ HHp,
                           const void* __restrict__ att_src, const void* __restrict__ att_dst,
                           float* __restrict__ AS, float* __restrict__ AD,
                           const int* __restrict__ flags)
{
    const int f32 = flags[0];
    int wid  = (blockIdx.x * blockDim.x + threadIdx.x) >> 6;
    int lane = threadIdx.x & 63;
    if (wid >= NN * 2) return;
    int n = wid >> 1, h = wid & 1;
    int base = n * 256 + h * CC;
    float v1 = HHp[base + lane], v2 = HHp[base + lane + 64];
    float s = v1 * ldf(att_src, h * CC + lane, f32) + v2 * ldf(att_src, h * CC + lane + 64, f32);
    float d = v1 * ldf(att_dst, h * CC + lane, f32) + v2 * ldf(att_dst, h * CC + lane + 64, f32);
#pragma unroll
    for (int off = 32; off; off >>= 1) {
        s += __shfl_down(s, off);
        d += __shfl_down(d, off);
    }
    if (lane == 0) { AS[wid] = s; AD[wid] = d; }
}

// ---------------------------------------------------------------------------
// GAT softmax stats per (node, head): wave loops CSR edge list + self loop
// ---------------------------------------------------------------------------
__global__ void gat_stats_kernel(const float* __restrict__ AS, const float* __restrict__ AD,
                                 const int* __restrict__ off, const int* __restrict__ csr,
                                 float* __restrict__ DMAX, float* __restrict__ DINV)
{
    int wid  = (blockIdx.x * blockDim.x + threadIdx.x) >> 6;
    int lane = threadIdx.x & 63;
    if (wid >= NN * 2) return;
    int n = wid >> 1, h = wid & 1;
    int b = off[n], e = off[n + 1];
    float adh = AD[n * 2 + h];
    float self_l = leaky02(AS[n * 2 + h] + adh);
    float m = (lane == 0) ? self_l : NEG_INF;
    for (int i = b + lane; i < e; i += 64) {
        int s = csr[i];
        m = fmaxf(m, leaky02(AS[s * 2 + h] + adh));
    }
#pragma unroll
    for (int o = 32; o; o >>= 1) m = fmaxf(m, __shfl_xor(m, o));
    float sum = (lane == 0) ? expf(self_l - m) : 0.f;
    for (int i = b + lane; i < e; i += 64) {
        int s = csr[i];
        sum += expf(leaky02(AS[s * 2 + h] + adh) - m);
    }
#pragma unroll
    for (int o = 32; o; o >>= 1) sum += __shfl_xor(sum, o);
    if (lane == 0) { DMAX[wid] = m; DINV[wid] = 1.f / sum; }
}

// ---------------------------------------------------------------------------
// GAT aggregation + fused decoder. Per node d:
//   alpha computed ONCE per (edge,head) into LDS; float4 gather, 4 edges in
//   flight; LDS reduce; then Z[d,:] = (out + b_gat) @ W_dec + b_dec.
// ---------------------------------------------------------------------------
__global__ __launch_bounds__(256) void gat_agg_dec_kernel(
    const float4* __restrict__ HH4,
    const float* __restrict__ AS, const float* __restrict__ AD,
    const float* __restrict__ DMAX, const float* __restrict__ DINV,
    const int* __restrict__ off, const int* __restrict__ csr,
    const void* __restrict__ b_gat, const float* __restrict__ W_dec,
    const void* __restrict__ b_dec,
    float* __restrict__ Zout, const int* __restrict__ flags)
{
    const int f32 = flags[0];
    int d = blockIdx.x, t = threadIdx.x;
    int g = t >> 6, u = t & 63;        // 4 edge-groups x 64 quads (256 ch)
    int hu = u >> 5;                   // head of this channel quad
    float ad0 = AD[d * 2], ad1 = AD[d * 2 + 1];
    float m0 = DMAX[d * 2], m1 = DMAX[d * 2 + 1];
    float i0 = DINV[d * 2], i1 = DINV[d * 2 + 1];
    float4 acc = make_float4(0.f, 0.f, 0.f, 0.f);
    if (g == 0) {      // self loop
        float adh = hu ? ad1 : ad0;
        float a0 = expf(leaky02(AS[d * 2 + hu] + adh) - (hu ? m1 : m0)) * (hu ? i1 : i0);
        float4 v = HH4[d * 64 + u];
        acc = make_float4(a0 * v.x, a0 * v.y, a0 * v.z, a0 * v.w);
    }
    int b = off[d], e = off[d + 1];
    __shared__ int ssrc[64];
    __shared__ float salpha[2][64];
    __shared__ float4 sred[256];
    for (int chunk = b; chunk < e; chunk += 64) {
        int n = min(64, e - chunk);
        if (t < n) ssrc[t] = csr[chunk + t];
        __syncthreads();
        if (t < 128) {
            int j = t & 63, hh = t >> 6;
            if (j < n) {
                int s = ssrc[j];
                float adh = hh ? ad1 : ad0;
                salpha[hh][j] = expf(leaky02(AS[s * 2 + hh] + adh) - (hh ? m1 : m0))
                              * (hh ? i1 : i0);
            }
        }
        __syncthreads();
        for (int j = g; j < n; j += 4) {
            float al = salpha[hu][j];
            float4 v = HH4[ssrc[j] * 64 + u];
            acc.x += al * v.x; acc.y += al * v.y;
            acc.z += al * v.z; acc.w += al * v.w;
        }
        __syncthreads();
    }
    sred[t] = acc;
    __syncthreads();
    __shared__ float sh[256];
    __shared__ float so[128];
    if (t < 64) {
        float4 a = sred[t], b4 = sred[t + 64], c4 = sred[t + 128], d4 = sred[t + 192];
        sh[4 * t + 0] = a.x + b4.x + c4.x + d4.x + ldf(b_gat, 4 * t + 0, f32);
        sh[4 * t + 1] = a.y + b4.y + c4.y + d4.y + ldf(b_gat, 4 * t + 1, f32);
        sh[4 * t + 2] = a.z + b4.z + c4.z + d4.z + ldf(b_gat, 4 * t + 2, f32);
        sh[4 * t + 3] = a.w + b4.w + c4.w + d4.w + ldf(b_gat, 4 * t + 3, f32);
    }
    __syncthreads();
    // decoder matvec: Z[d,c] = sum_j sh[j] * W_dec[j,c] + b_dec[c]
    int h = t >> 7, c = t & 127, j0 = h * 128;
    float o = 0.f;
    for (int j = 0; j < 128; j += 4) {
        o += sh[j0 + j]     * W_dec[(j0 + j)     * 128 + c]
           + sh[j0 + j + 1] * W_dec[(j0 + j + 1) * 128 + c]
           + sh[j0 + j + 2] * W_dec[(j0 + j + 2) * 128 + c]
           + sh[j0 + j + 3] * W_dec[(j0 + j + 3) * 128 + c];
    }
    if (h == 1) so[c] = o;
    __syncthreads();
    if (h == 0) Zout[d * 128 + c] = o + so[c] + ldf(b_dec, c, f32);
}

__global__ void store_out_kernel(const float* __restrict__ srcv, void* __restrict__ out,
                                 int off, const int* __restrict__ flags)
{
    const int f32 = flags[0];
    int idx = blockIdx.x * blockDim.x + threadIdx.x;
    if (idx >= NN * CC) return;
    stf(out, off + idx, srcv[idx], f32);
}

// ---------------------------------------------------------------------------
extern "C" void kernel_launch(void* const* d_in, const int* in_sizes, int n_in,
                              void* d_out, int out_size, void* d_ws, size_t ws_size,
                              hipStream_t stream)
{
    const void* xin    = d_in[0];
    const void* ei     = d_in[1];
    const void* eps    = d_in[2];
    const void* W_emb  = d_in[3];
    const void* b_emb  = d_in[4];
    const void* g_emb  = d_in[5];
    const void* be_emb = d_in[6];
    const void* W1     = d_in[7];
    const void* b1     = d_in[8];
    const void* g1     = d_in[9];
    const void* be1    = d_in[10];
    const void* W2     = d_in[11];
    const void* b2     = d_in[12];
    const void* W_mu   = d_in[13];
    const void* b_mu   = d_in[14];
    const void* W_var  = d_in[15];
    const void* b_var  = d_in[16];
    const void* W_gat  = d_in[17];
    const void* attS   = d_in[18];
    const void* attD   = d_in[19];
    const void* b_gat  = d_in[20];
    const void* W_dec  = d_in[21];
    const void* b_dec  = d_in[22];

    // workspace layout (fp32 elements): 4*NB + tail ≈ 45 MB
    float* ws = (float*)d_ws;
    const size_t NB = (size_t)NN * CC;       // 2,560,000
    float* B0 = ws;
    float* B1 = ws + 1 * NB;
    float* B2 = ws + 2 * NB;
    float* B3 = ws + 3 * NB;
    float* TAIL  = ws + 4 * NB;
    float* AS    = TAIL;                     // 40000
    float* AD    = TAIL + 40000;             // 40000
    float* DMAX  = TAIL + 80000;             // 40000
    float* DINV  = TAIL + 120000;            // 40000
    float* SUMS  = TAIL + 160000;            // 128
    float* SUMSQ = TAIL + 160128;            // 128
    int*   FLAGS = (int*)(TAIL + 160256);    // 16
    int*   DEG   = (int*)(TAIL + 160272);    // 20000
    int*   OFF   = DEG + 20000;              // 20001
    int*   CUR   = OFF + 20001;              // 20000
    int*   CSR   = CUR + 20000;              // 640000
    float* WF    = (float*)(CSR + 640000);   // fp32 weights
    float* WFemb = WF;                       // 92*128  = 11776
    float* WF1   = WFemb + 92 * 128;         // 16384
    float* WF2   = WF1 + 128 * 128;          // 16384
    float* WFmu  = WF2 + 128 * 128;          // 16384
    float* WFvar = WFmu + 128 * 128;         // 16384
    float* WFgat = WFvar + 128 * 128;        // 32768
    float* WFdec = WFgat + 128 * 256;        // 32768

    detect_kernel<<<1, 256, 0, stream>>>((const unsigned int*)xin,
                                         (const unsigned int*)ei, FLAGS);

    // -------- weight conversion to fp32 --------
    cvt_kernel<<<(92 * 128 + 255) / 256, 256, 0, stream>>>(W_emb, WFemb, 92 * 128, FLAGS);
    cvt_kernel<<<64, 256, 0, stream>>>(W1, WF1, 128 * 128, FLAGS);
    cvt_kernel<<<64, 256, 0, stream>>>(W2, WF2, 128 * 128, FLAGS);
    cvt_kernel<<<64, 256, 0, stream>>>(W_mu, WFmu, 128 * 128, FLAGS);
    cvt_kernel<<<64, 256, 0, stream>>>(W_var, WFvar, 128 * 128, FLAGS);
    cvt_kernel<<<128, 256, 0, stream>>>(W_gat, WFgat, 128 * 256, FLAGS);
    cvt_kernel<<<128, 256, 0, stream>>>(W_dec, WFdec, 256 * 128, FLAGS);

    // -------- CSR build (sorted by destination) --------
    hipMemsetAsync(DEG, 0, NN * sizeof(int), stream);
    hist_kernel<<<(EE + 255) / 256, 256, 0, stream>>>(ei, DEG, FLAGS);
    scan_kernel<<<1, 256, 0, stream>>>(DEG, OFF, CUR);
    scatter_kernel<<<(EE + 255) / 256, 256, 0, stream>>>(ei, CUR, CSR, FLAGS);

    // -------- Stage A: atom embedding = relu(BN(x @ W_emb + b_emb)) --------
    hipMemsetAsync(SUMS, 0, 2 * CC * sizeof(float), stream);
    gemm_kernel<DIN_, CC, 8><<<NN / 8, CC, 0, stream>>>(
        xin, 1, nullptr, WFemb, b_emb, B1, FLAGS);
    bn_stats_kernel<<<256, 256, 0, stream>>>(B1, SUMS, SUMSQ);
    bn_relu_kernel<<<(NN * CC) / 256, 256, 0, stream>>>(B1, B0, SUMS, SUMSQ, g_emb, be_emb, FLAGS);

    // -------- Stage B: GIN x2 (shared weights): x = W2( relu(BN(W1(x+agg))) ) --------
    for (int t = 0; t < 2; t++) {
        gin_gather_kernel<<<NN, 128, 0, stream>>>((const float4*)B0, (float4*)B1, OFF, CSR);
        hipMemsetAsync(SUMS, 0, 2 * CC * sizeof(float), stream);
        gemm_kernel<CC, CC, 8><<<NN / 8, CC, 0, stream>>>(
            B1, 0, nullptr, WF1, b1, B2, FLAGS);
        bn_stats_kernel<<<256, 256, 0, stream>>>(B2, SUMS, SUMSQ);
        bn_relu_kernel<<<(NN * CC) / 256, 256, 0, stream>>>(B2, B2, SUMS, SUMSQ, g1, be1, FLAGS);
        gemm_kernel<CC, CC, 8><<<NN / 8, CC, 0, stream>>>(
            B2, 0, nullptr, WF2, b2, B0, FLAGS);
    }

    // -------- Stage C: VAE heads (x in B0 -> MU B1, LV B2, Z B3) --------
    gemm_kernel<CC, CC, 8><<<NN / 8, CC, 0, stream>>>(
        B0, 0, nullptr, WFmu, b_mu, B1, FLAGS);
    gemm_kernel<CC, CC, 8><<<NN / 8, CC, 0, stream>>>(
        B0, 0, nullptr, WFvar, b_var, B2, FLAGS);
    z_kernel<<<(NN * CC) / 256, 256, 0, stream>>>(B1, B2, eps, B3, d_out, FLAGS);

    // -------- Stage D: GAT x2 (shared weights), decoder fused --------
    float* zc = B3;
    float* znext[2] = { B2, B3 };
    for (int t = 0; t < 2; t++) {
        float* HHb = B0;   // spans B0|B1 (N x 256)
        gemm_kernel<CC, 2 * CC, 8><<<NN / 8, 2 * CC, 0, stream>>>(
            zc, 0, nullptr, WFgat, nullptr, HHb, FLAGS);
        att_kernel<<<(NN * 2) / 4, 256, 0, stream>>>(HHb, attS, attD, AS, AD, FLAGS);
        gat_stats_kernel<<<(NN * 2) / 4, 256, 0, stream>>>(AS, AD, OFF, CSR, DMAX, DINV);
        gat_agg_dec_kernel<<<NN, 256, 0, stream>>>(
            (const float4*)HHb, AS, AD, DMAX, DINV, OFF, CSR,
            b_gat, WFdec, b_dec, znext[t], FLAGS);
        zc = znext[t];
    }

    // zout
    store_out_kernel<<<(NN * CC) / 256, 256, 0, stream>>>(zc, d_out, NN * CC, FLAGS);
}

// Round 5
// 941.752 us; speedup vs baseline: 2.5533x; 1.0577x over previous
//
#include <hip/hip_runtime.h>
#include <hip/hip_bf16.h>

// Problem constants
#define NN   20000          // nodes
#define DIN_ 92             // atom feature dim
#define CC   128            // hidden dim
#define EE   640000         // edges (self loops handled explicitly)
#define BN_EPS 1e-5f
#define NEG_INF (-3.0e38f)

// ---------------------------------------------------------------------------
// Dual-dtype helpers: flags[0]=1 -> external floats are fp32 (else bf16)
//                     flags[1]=1 -> edge_index is int64 (else int32)
// Internal activations are ALWAYS bf16; accumulators/stats/weights fp32.
// ---------------------------------------------------------------------------
static __device__ __forceinline__ float b2f(__hip_bfloat16 v) { return __bfloat162float(v); }
static __device__ __forceinline__ float ldf(const void* p, int i, int f32) {
    return f32 ? ((const float*)p)[i]
               : __bfloat162float(((const __hip_bfloat16*)p)[i]);
}
static __device__ __forceinline__ void stf(void* p, int i, float v, int f32) {
    if (f32) ((float*)p)[i] = v;
    else     ((__hip_bfloat16*)p)[i] = __float2bfloat16(v);
}
static __device__ __forceinline__ float leaky02(float x) { return x > 0.f ? x : 0.2f * x; }

static __device__ __forceinline__ float4 bf4(uint2 w) {
    union { uint2 u; __hip_bfloat16 b[4]; } x; x.u = w;
    return make_float4(b2f(x.b[0]), b2f(x.b[1]), b2f(x.b[2]), b2f(x.b[3]));
}
static __device__ __forceinline__ uint2 f4bf(float4 v) {
    union { uint2 u; __hip_bfloat16 b[4]; } x;
    x.b[0] = __float2bfloat16(v.x); x.b[1] = __float2bfloat16(v.y);
    x.b[2] = __float2bfloat16(v.z); x.b[3] = __float2bfloat16(v.w);
    return x.u;
}

// ---------------------------------------------------------------------------
// Runtime dtype detection (runs every launch; writes flags into ws)
// ---------------------------------------------------------------------------
__global__ void detect_kernel(const unsigned int* __restrict__ x0,
                              const unsigned int* __restrict__ ei,
                              int* __restrict__ flags)
{
    __shared__ int cnt_band, cnt_zero;
    if (threadIdx.x == 0) { cnt_band = 0; cnt_zero = 0; }
    __syncthreads();
    unsigned w  = x0[threadIdx.x];
    unsigned eb = ((w & 0xFFFFu) >> 7) & 0xFFu;
    if (eb >= 90u && eb <= 140u) atomicAdd(&cnt_band, 1);
    if (ei[2 * threadIdx.x + 1] == 0u) atomicAdd(&cnt_zero, 1);
    __syncthreads();
    if (threadIdx.x == 0) {
        flags[0] = (cnt_band < 200) ? 1 : 0;   // 1 = fp32
        flags[1] = (cnt_zero >= 250) ? 1 : 0;  // 1 = int64
    }
}

// convert external (bf16|fp32) vector to fp32 workspace
__global__ void cvt_kernel(const void* __restrict__ src, float* __restrict__ dst,
                           int n, const int* __restrict__ flags)
{
    const int f32 = flags[0];
    int i = blockIdx.x * blockDim.x + threadIdx.x;
    if (i < n) dst[i] = ldf(src, i, f32);
}

// ---------------------------------------------------------------------------
// CSR build: histogram -> single-block scan -> scatter (sorted by dst)
// ---------------------------------------------------------------------------
__global__ void hist_kernel(const void* __restrict__ ei, int* __restrict__ deg,
                            const int* __restrict__ flags)
{
    int e = blockIdx.x * blockDim.x + threadIdx.x;
    if (e >= EE) return;
    const int i64 = flags[1];
    int d = i64 ? (int)((const long long*)ei)[EE + e] : ((const int*)ei)[EE + e];
    atomicAdd(&deg[d], 1);
}

__global__ __launch_bounds__(256) void scan_kernel(const int* __restrict__ deg,
                                                   int* __restrict__ off,
                                                   int* __restrict__ cur)
{
    __shared__ int ssum[256];
    const int CH = (NN + 255) / 256;   // 79
    int tid = threadIdx.x;
    int base = tid * CH;
    int s = 0;
    for (int i = 0; i < CH; i++) { int idx = base + i; if (idx < NN) s += deg[idx]; }
    ssum[tid] = s;
    __syncthreads();
    for (int st = 1; st < 256; st <<= 1) {
        int t = (tid >= st) ? ssum[tid - st] : 0;
        __syncthreads();
        ssum[tid] += t;
        __syncthreads();
    }
    int run = ssum[tid] - s;           // exclusive prefix
    for (int i = 0; i < CH; i++) {
        int idx = base + i;
        if (idx < NN) { off[idx] = run; cur[idx] = run; run += deg[idx]; }
    }
    if (tid == 255) off[NN] = ssum[255];
}

__global__ void scatter_kernel(const void* __restrict__ ei, int* __restrict__ cur,
                               int* __restrict__ csr, const int* __restrict__ flags)
{
    int e = blockIdx.x * blockDim.x + threadIdx.x;
    if (e >= EE) return;
    const int i64 = flags[1];
    int s, d;
    if (i64) { s = (int)((const long long*)ei)[e]; d = (int)((const long long*)ei)[EE + e]; }
    else     { s = ((const int*)ei)[e];            d = ((const int*)ei)[EE + e]; }
    int pos = atomicAdd(&cur[d], 1);
    csr[pos] = s;
}

// ---------------------------------------------------------------------------
// GEMM: C[M,NC] = A @ W + bias. W fp32 (pre-converted), 8 rows/block.
// a_mode: 0 = internal bf16, 1 = external dual-dtype. OUT_BF: bf16 store.
// ---------------------------------------------------------------------------
template<int K, int NC, int ROWS, int OUT_BF>
__global__ __launch_bounds__(NC) void gemm_kernel(
    const void* __restrict__ A, int a_mode,
    const float* __restrict__ W, const void* __restrict__ bias,
    void* __restrict__ Cout, const int* __restrict__ flags)
{
    const int f32 = flags[0];
    __shared__ float As[ROWS][K];
    const int row0 = blockIdx.x * ROWS;
    for (int idx = threadIdx.x; idx < ROWS * K; idx += NC) {
        int r = idx / K, k = idx - r * K;
        int g = (row0 + r) * K + k;
        As[r][k] = a_mode ? ldf(A, g, f32)
                          : b2f(((const __hip_bfloat16*)A)[g]);
    }
    __syncthreads();
    const int col = threadIdx.x;
    float acc[ROWS];
#pragma unroll
    for (int r = 0; r < ROWS; r++) acc[r] = 0.f;
    for (int k = 0; k < K; k += 4) {
        float w0 = W[(k + 0) * NC + col];
        float w1 = W[(k + 1) * NC + col];
        float w2 = W[(k + 2) * NC + col];
        float w3 = W[(k + 3) * NC + col];
#pragma unroll
        for (int r = 0; r < ROWS; r++)
            acc[r] += As[r][k] * w0 + As[r][k + 1] * w1
                    + As[r][k + 2] * w2 + As[r][k + 3] * w3;
    }
    float b = bias ? ldf(bias, col, f32) : 0.f;
#pragma unroll
    for (int r = 0; r < ROWS; r++) {
        int o = (row0 + r) * NC + col;
        float v = acc[r] + b;
        if (OUT_BF) ((__hip_bfloat16*)Cout)[o] = __float2bfloat16(v);
        else        ((float*)Cout)[o] = v;
    }
}

// ---------------------------------------------------------------------------
// BatchNorm (training): column sums / sumsq (fp32 Y), then normalize+ReLU->bf16
// ---------------------------------------------------------------------------
__global__ void bn_stats_kernel(const float* __restrict__ Y,
                                float* __restrict__ sums, float* __restrict__ sumsq)
{
    int c  = threadIdx.x & (CC - 1);
    int rg = threadIdx.x >> 7;
    int stride = gridDim.x * 2;
    float s = 0.f, q = 0.f;
    for (int r = blockIdx.x * 2 + rg; r < NN; r += stride) {
        float v = Y[r * CC + c];
        s += v; q += v * v;
    }
    atomicAdd(&sums[c], s);
    atomicAdd(&sumsq[c], q);
}

__global__ void bn_relu_kernel(const float* __restrict__ Y, __hip_bfloat16* __restrict__ X,
                               const float* __restrict__ sums, const float* __restrict__ sumsq,
                               const void* __restrict__ g, const void* __restrict__ be,
                               const int* __restrict__ flags)
{
    const int f32 = flags[0];
    int idx = blockIdx.x * blockDim.x + threadIdx.x;
    if (idx >= NN * CC) return;
    int c = idx & (CC - 1);
    float mean = sums[c] * (1.f / NN);
    float var  = sumsq[c] * (1.f / NN) - mean * mean;
    float inv  = rsqrtf(fmaxf(var, 0.f) + BN_EPS);
    float v = (Y[idx] - mean) * inv * ldf(g, c, f32) + ldf(be, c, f32);
    X[idx] = __float2bfloat16(v > 0.f ? v : 0.f);
}

// ---------------------------------------------------------------------------
// GIN: H[d] = X[d] + sum_{s in N(d)} X[s]   (bf16 rows, uint2 = 4ch gather)
// ---------------------------------------------------------------------------
__global__ __launch_bounds__(128) void gin_gather_kernel(
    const uint2* __restrict__ X2, uint2* __restrict__ H2,
    const int* __restrict__ off, const int* __restrict__ csr)
{
    int d = blockIdx.x, t = threadIdx.x;
    int g = t >> 5, u = t & 31;        // 4 edge-groups x 32 ch-quads (128 ch)
    float4 acc = make_float4(0.f, 0.f, 0.f, 0.f);
    if (g == 0) acc = bf4(X2[d * 32 + u]);
    int b = off[d], e = off[d + 1];
    __shared__ int ssrc[64];
    __shared__ float4 sred[128];
    for (int chunk = b; chunk < e; chunk += 64) {
        int n = min(64, e - chunk);
        if (t < n) ssrc[t] = csr[chunk + t];
        __syncthreads();
        for (int j = g; j < n; j += 4) {
            float4 v = bf4(X2[ssrc[j] * 32 + u]);
            acc.x += v.x; acc.y += v.y; acc.z += v.z; acc.w += v.w;
        }
        __syncthreads();
    }
    sred[t] = acc;
    __syncthreads();
    if (t < 32) {
        float4 a = sred[t], b4 = sred[t + 32], c4 = sred[t + 64], d4 = sred[t + 96];
        a.x += b4.x + c4.x + d4.x;
        a.y += b4.y + c4.y + d4.y;
        a.z += b4.z + c4.z + d4.z;
        a.w += b4.w + c4.w + d4.w;
        H2[d * 32 + t] = f4bf(a);
    }
}

// ---------------------------------------------------------------------------
// VAE reparameterization + write zin/mu/logvar outputs; Z stored bf16
// ---------------------------------------------------------------------------
__global__ void z_kernel(const float* __restrict__ MU, const float* __restrict__ LV,
                         const void* __restrict__ eps,
                         __hip_bfloat16* __restrict__ Z, void* __restrict__ out,
                         const int* __restrict__ flags)
{
    const int f32 = flags[0];
    int idx = blockIdx.x * blockDim.x + threadIdx.x;
    if (idx >= NN * CC) return;
    float mu = MU[idx], lv = LV[idx];
    float z = ldf(eps, idx, f32) * expf(0.5f * lv) + mu;
    Z[idx] = __float2bfloat16(z);
    stf(out, idx, z, f32);                  // zin
    stf(out, 2 * NN * CC + idx, mu, f32);   // mu
    stf(out, 3 * NN * CC + idx, lv, f32);   // logvar
}

// ---------------------------------------------------------------------------
// GAT attention scores per (node, head), bf16 HH
// ---------------------------------------------------------------------------
__global__ void att_kernel(const __hip_bfloat16* __restrict__ HHb,
                           const void* __restrict__ att_src, const void* __restrict__ att_dst,
                           float* __restrict__ AS, float* __restrict__ AD,
                           const int* __restrict__ flags)
{
    const int f32 = flags[0];
    int wid  = (blockIdx.x * blockDim.x + threadIdx.x) >> 6;
    int lane = threadIdx.x & 63;
    if (wid >= NN * 2) return;
    int n = wid >> 1, h = wid & 1;
    int base = n * 256 + h * CC;
    float v1 = b2f(HHb[base + lane]), v2 = b2f(HHb[base + lane + 64]);
    float s = v1 * ldf(att_src, h * CC + lane, f32) + v2 * ldf(att_src, h * CC + lane + 64, f32);
    float d = v1 * ldf(att_dst, h * CC + lane, f32) + v2 * ldf(att_dst, h * CC + lane + 64, f32);
#pragma unroll
    for (int off = 32; off; off >>= 1) {
        s += __shfl_down(s, off);
        d += __shfl_down(d, off);
    }
    if (lane == 0) { AS[wid] = s; AD[wid] = d; }
}

// ---------------------------------------------------------------------------
// GAT softmax stats per (node, head): wave loops CSR edge list + self loop
// ---------------------------------------------------------------------------
__global__ void gat_stats_kernel(const float* __restrict__ AS, const float* __restrict__ AD,
                                 const int* __restrict__ off, const int* __restrict__ csr,
                                 float* __restrict__ DMAX, float* __restrict__ DINV)
{
    int wid  = (blockIdx.x * blockDim.x + threadIdx.x) >> 6;
    int lane = threadIdx.x & 63;
    if (wid >= NN * 2) return;
    int n = wid >> 1, h = wid & 1;
    int b = off[n], e = off[n + 1];
    float adh = AD[n * 2 + h];
    float self_l = leaky02(AS[n * 2 + h] + adh);
    float m = (lane == 0) ? self_l : NEG_INF;
    for (int i = b + lane; i < e; i += 64) {
        int s = csr[i];
        m = fmaxf(m, leaky02(AS[s * 2 + h] + adh));
    }
#pragma unroll
    for (int o = 32; o; o >>= 1) m = fmaxf(m, __shfl_xor(m, o));
    float sum = (lane == 0) ? expf(self_l - m) : 0.f;
    for (int i = b + lane; i < e; i += 64) {
        int s = csr[i];
        sum += expf(leaky02(AS[s * 2 + h] + adh) - m);
    }
#pragma unroll
    for (int o = 32; o; o >>= 1) sum += __shfl_xor(sum, o);
    if (lane == 0) { DMAX[wid] = m; DINV[wid] = 1.f / sum; }
}

// ---------------------------------------------------------------------------
// GAT aggregation + fused decoder. bf16 HH rows (256ch = 64 uint2).
// alpha once per (edge,head) into LDS; 4 edges in flight; fp32 accumulate;
// Z[d,:] = (out + b_gat) @ W_dec + b_dec, stored bf16.
// ---------------------------------------------------------------------------
__global__ __launch_bounds__(256) void gat_agg_dec_kernel(
    const uint2* __restrict__ HH2,
    const float* __restrict__ AS, const float* __restrict__ AD,
    const float* __restrict__ DMAX, const float* __restrict__ DINV,
    const int* __restrict__ off, const int* __restrict__ csr,
    const void* __restrict__ b_gat, const float* __restrict__ W_dec,
    const void* __restrict__ b_dec,
    __hip_bfloat16* __restrict__ Zout, const int* __restrict__ flags)
{
    const int f32 = flags[0];
    int d = blockIdx.x, t = threadIdx.x;
    int g = t >> 6, u = t & 63;        // 4 edge-groups x 64 ch-quads (256 ch)
    int hu = u >> 5;                   // head of this channel quad
    float ad0 = AD[d * 2], ad1 = AD[d * 2 + 1];
    float m0 = DMAX[d * 2], m1 = DMAX[d * 2 + 1];
    float i0 = DINV[d * 2], i1 = DINV[d * 2 + 1];
    float4 acc = make_float4(0.f, 0.f, 0.f, 0.f);
    if (g == 0) {      // self loop
        float adh = hu ? ad1 : ad0;
        float a0 = expf(leaky02(AS[d * 2 + hu] + adh) - (hu ? m1 : m0)) * (hu ? i1 : i0);
        float4 v = bf4(HH2[d * 64 + u]);
        acc = make_float4(a0 * v.x, a0 * v.y, a0 * v.z, a0 * v.w);
    }
    int b = off[d], e = off[d + 1];
    __shared__ int ssrc[64];
    __shared__ float salpha[2][64];
    __shared__ float4 sred[256];
    for (int chunk = b; chunk < e; chunk += 64) {
        int n = min(64, e - chunk);
        if (t < n) ssrc[t] = csr[chunk + t];
        __syncthreads();
        if (t < 128) {
            int j = t & 63, hh = t >> 6;
            if (j < n) {
                int s = ssrc[j];
                float adh = hh ? ad1 : ad0;
                salpha[hh][j] = expf(leaky02(AS[s * 2 + hh] + adh) - (hh ? m1 : m0))
                              * (hh ? i1 : i0);
            }
        }
        __syncthreads();
        for (int j = g; j < n; j += 4) {
            float al = salpha[hu][j];
            float4 v = bf4(HH2[ssrc[j] * 64 + u]);
            acc.x += al * v.x; acc.y += al * v.y;
            acc.z += al * v.z; acc.w += al * v.w;
        }
        __syncthreads();
    }
    sred[t] = acc;
    __syncthreads();
    __shared__ float sh[256];
    __shared__ float so[128];
    if (t < 64) {
        float4 a = sred[t], b4 = sred[t + 64], c4 = sred[t + 128], d4 = sred[t + 192];
        sh[4 * t + 0] = a.x + b4.x + c4.x + d4.x + ldf(b_gat, 4 * t + 0, f32);
        sh[4 * t + 1] = a.y + b4.y + c4.y + d4.y + ldf(b_gat, 4 * t + 1, f32);
        sh[4 * t + 2] = a.z + b4.z + c4.z + d4.z + ldf(b_gat, 4 * t + 2, f32);
        sh[4 * t + 3] = a.w + b4.w + c4.w + d4.w + ldf(b_gat, 4 * t + 3, f32);
    }
    __syncthreads();
    // decoder matvec: Z[d,c] = sum_j sh[j] * W_dec[j,c] + b_dec[c]
    int h = t >> 7, c = t & 127, j0 = h * 128;
    float o = 0.f;
    for (int j = 0; j < 128; j += 4) {
        o += sh[j0 + j]     * W_dec[(j0 + j)     * 128 + c]
           + sh[j0 + j + 1] * W_dec[(j0 + j + 1) * 128 + c]
           + sh[j0 + j + 2] * W_dec[(j0 + j + 2) * 128 + c]
           + sh[j0 + j + 3] * W_dec[(j0 + j + 3) * 128 + c];
    }
    if (h == 1) so[c] = o;
    __syncthreads();
    if (h == 0) Zout[d * 128 + c] = __float2bfloat16(o + so[c] + ldf(b_dec, c, f32));
}

__global__ void store_out_kernel(const __hip_bfloat16* __restrict__ srcv,
                                 void* __restrict__ out,
                                 int off, const int* __restrict__ flags)
{
    const int f32 = flags[0];
    int idx = blockIdx.x * blockDim.x + threadIdx.x;
    if (idx >= NN * CC) return;
    stf(out, off + idx, b2f(srcv[idx]), f32);
}

// ---------------------------------------------------------------------------
extern "C" void kernel_launch(void* const* d_in, const int* in_sizes, int n_in,
                              void* d_out, int out_size, void* d_ws, size_t ws_size,
                              hipStream_t stream)
{
    const void* xin    = d_in[0];
    const void* ei     = d_in[1];
    const void* eps    = d_in[2];
    const void* W_emb  = d_in[3];
    const void* b_emb  = d_in[4];
    const void* g_emb  = d_in[5];
    const void* be_emb = d_in[6];
    const void* W1     = d_in[7];
    const void* b1     = d_in[8];
    const void* g1     = d_in[9];
    const void* be1    = d_in[10];
    const void* W2     = d_in[11];
    const void* b2     = d_in[12];
    const void* W_mu   = d_in[13];
    const void* b_mu   = d_in[14];
    const void* W_var  = d_in[15];
    const void* b_var  = d_in[16];
    const void* W_gat  = d_in[17];
    const void* attS   = d_in[18];
    const void* attD   = d_in[19];
    const void* b_gat  = d_in[20];
    const void* W_dec  = d_in[21];
    const void* b_dec  = d_in[22];

    // workspace layout (fp32 elements): 4*NB fp32-sized slots + tail ≈ 45 MB
    float* ws = (float*)d_ws;
    const size_t NB = (size_t)NN * CC;       // 2,560,000
    float* B0 = ws;                          // fp32 Y/MU; later bf16 HH (N x 256)
    float* B1 = ws + 1 * NB;                 // fp32 Y2/LV
    float* B2 = ws + 2 * NB;                 // bf16 Xbf | Hbf
    float* B3 = ws + 3 * NB;                 // bf16 Zbf | Zoutbf
    __hip_bfloat16* Xbf   = (__hip_bfloat16*)B2;       // N x 128
    __hip_bfloat16* Hbf   = Xbf + NB;                  // N x 128
    __hip_bfloat16* Zbf   = (__hip_bfloat16*)B3;       // N x 128
    __hip_bfloat16* Zobf  = Zbf + NB;                  // N x 128
    __hip_bfloat16* HHbf  = (__hip_bfloat16*)B0;       // N x 256 (= full B0)
    float* TAIL  = ws + 4 * NB;
    float* AS    = TAIL;                     // 40000
    float* AD    = TAIL + 40000;             // 40000
    float* DMAX  = TAIL + 80000;             // 40000
    float* DINV  = TAIL + 120000;            // 40000
    float* SUMS  = TAIL + 160000;            // 128
    float* SUMSQ = TAIL + 160128;            // 128
    int*   FLAGS = (int*)(TAIL + 160256);    // 16
    int*   DEG   = (int*)(TAIL + 160272);    // 20000
    int*   OFF   = DEG + 20000;              // 20001
    int*   CUR   = OFF + 20001;              // 20000
    int*   CSR   = CUR + 20000;              // 640000
    float* WF    = (float*)(CSR + 640000);   // fp32 weights
    float* WFemb = WF;                       // 92*128
    float* WF1   = WFemb + 92 * 128;
    float* WF2   = WF1 + 128 * 128;
    float* WFmu  = WF2 + 128 * 128;
    float* WFvar = WFmu + 128 * 128;
    float* WFgat = WFvar + 128 * 128;        // 128*256
    float* WFdec = WFgat + 128 * 256;        // 256*128

    detect_kernel<<<1, 256, 0, stream>>>((const unsigned int*)xin,
                                         (const unsigned int*)ei, FLAGS);

    // -------- weight conversion to fp32 --------
    cvt_kernel<<<(92 * 128 + 255) / 256, 256, 0, stream>>>(W_emb, WFemb, 92 * 128, FLAGS);
    cvt_kernel<<<64, 256, 0, stream>>>(W1, WF1, 128 * 128, FLAGS);
    cvt_kernel<<<64, 256, 0, stream>>>(W2, WF2, 128 * 128, FLAGS);
    cvt_kernel<<<64, 256, 0, stream>>>(W_mu, WFmu, 128 * 128, FLAGS);
    cvt_kernel<<<64, 256, 0, stream>>>(W_var, WFvar, 128 * 128, FLAGS);
    cvt_kernel<<<128, 256, 0, stream>>>(W_gat, WFgat, 128 * 256, FLAGS);
    cvt_kernel<<<128, 256, 0, stream>>>(W_dec, WFdec, 256 * 128, FLAGS);

    // -------- CSR build (sorted by destination) --------
    hipMemsetAsync(DEG, 0, NN * sizeof(int), stream);
    hist_kernel<<<(EE + 255) / 256, 256, 0, stream>>>(ei, DEG, FLAGS);
    scan_kernel<<<1, 256, 0, stream>>>(DEG, OFF, CUR);
    scatter_kernel<<<(EE + 255) / 256, 256, 0, stream>>>(ei, CUR, CSR, FLAGS);

    // -------- Stage A: atom embedding = relu(BN(x @ W_emb + b_emb)) -> Xbf --------
    hipMemsetAsync(SUMS, 0, 2 * CC * sizeof(float), stream);
    gemm_kernel<DIN_, CC, 8, 0><<<NN / 8, CC, 0, stream>>>(
        xin, 1, WFemb, b_emb, B1, FLAGS);
    bn_stats_kernel<<<256, 256, 0, stream>>>(B1, SUMS, SUMSQ);
    bn_relu_kernel<<<(NN * CC) / 256, 256, 0, stream>>>(B1, Xbf, SUMS, SUMSQ, g_emb, be_emb, FLAGS);

    // -------- Stage B: GIN x2 (shared weights): x = W2( relu(BN(W1(x+agg))) ) --------
    for (int t = 0; t < 2; t++) {
        gin_gather_kernel<<<NN, 128, 0, stream>>>((const uint2*)Xbf, (uint2*)Hbf, OFF, CSR);
        hipMemsetAsync(SUMS, 0, 2 * CC * sizeof(float), stream);
        gemm_kernel<CC, CC, 8, 0><<<NN / 8, CC, 0, stream>>>(
            Hbf, 0, WF1, b1, B1, FLAGS);
        bn_stats_kernel<<<256, 256, 0, stream>>>(B1, SUMS, SUMSQ);
        bn_relu_kernel<<<(NN * CC) / 256, 256, 0, stream>>>(B1, Hbf, SUMS, SUMSQ, g1, be1, FLAGS);
        gemm_kernel<CC, CC, 8, 1><<<NN / 8, CC, 0, stream>>>(
            Hbf, 0, WF2, b2, Xbf, FLAGS);
    }

    // -------- Stage C: VAE heads (Xbf -> MU B0, LV B1, Z -> Zbf + out) --------
    gemm_kernel<CC, CC, 8, 0><<<NN / 8, CC, 0, stream>>>(
        Xbf, 0, WFmu, b_mu, B0, FLAGS);
    gemm_kernel<CC, CC, 8, 0><<<NN / 8, CC, 0, stream>>>(
        Xbf, 0, WFvar, b_var, B1, FLAGS);
    z_kernel<<<(NN * CC) / 256, 256, 0, stream>>>(B0, B1, eps, Zbf, d_out, FLAGS);

    // -------- Stage D: GAT x2 (shared weights), decoder fused --------
    const __hip_bfloat16* zc = Zbf;
    for (int t = 0; t < 2; t++) {
        gemm_kernel<CC, 2 * CC, 8, 1><<<NN / 8, 2 * CC, 0, stream>>>(
            zc, 0, WFgat, nullptr, HHbf, FLAGS);
        att_kernel<<<(NN * 2) / 4, 256, 0, stream>>>(HHbf, attS, attD, AS, AD, FLAGS);
        gat_stats_kernel<<<(NN * 2) / 4, 256, 0, stream>>>(AS, AD, OFF, CSR, DMAX, DINV);
        gat_agg_dec_kernel<<<NN, 256, 0, stream>>>(
            (const uint2*)HHbf, AS, AD, DMAX, DINV, OFF, CSR,
            b_gat, WFdec, b_dec, Zobf, FLAGS);
        zc = Zobf;
    }

    // zout
    store_out_kernel<<<(NN * CC) / 256, 256, 0, stream>>>(Zobf, d_out, NN * CC, FLAGS);
}

// Round 6
// 879.400 us; speedup vs baseline: 2.7343x; 1.0709x over previous
//
#include <hip/hip_runtime.h>
#include <hip/hip_bf16.h>

// Problem constants
#define NN   20000          // nodes
#define DIN_ 92             // atom feature dim
#define CC   128            // hidden dim
#define EE   640000         // edges (self loops handled explicitly)
#define BN_EPS 1e-5f
#define NEG_INF (-3.0e38f)

// ---------------------------------------------------------------------------
// Dual-dtype helpers: flags[0]=1 -> external floats are fp32 (else bf16)
//                     flags[1]=1 -> edge_index is int64 (else int32)
// Internal activations bf16; accumulators/stats/weights fp32.
// ---------------------------------------------------------------------------
static __device__ __forceinline__ float b2f(__hip_bfloat16 v) { return __bfloat162float(v); }
static __device__ __forceinline__ float ldf(const void* p, int i, int f32) {
    return f32 ? ((const float*)p)[i]
               : __bfloat162float(((const __hip_bfloat16*)p)[i]);
}
static __device__ __forceinline__ void stf(void* p, int i, float v, int f32) {
    if (f32) ((float*)p)[i] = v;
    else     ((__hip_bfloat16*)p)[i] = __float2bfloat16(v);
}
static __device__ __forceinline__ float leaky02(float x) { return x > 0.f ? x : 0.2f * x; }

static __device__ __forceinline__ float4 bf4(uint2 w) {
    union { uint2 u; __hip_bfloat16 b[4]; } x; x.u = w;
    return make_float4(b2f(x.b[0]), b2f(x.b[1]), b2f(x.b[2]), b2f(x.b[3]));
}
static __device__ __forceinline__ uint2 f4bf(float4 v) {
    union { uint2 u; __hip_bfloat16 b[4]; } x;
    x.b[0] = __float2bfloat16(v.x); x.b[1] = __float2bfloat16(v.y);
    x.b[2] = __float2bfloat16(v.z); x.b[3] = __float2bfloat16(v.w);
    return x.u;
}

// ---------------------------------------------------------------------------
// Runtime dtype detection
// ---------------------------------------------------------------------------
__global__ void detect_kernel(const unsigned int* __restrict__ x0,
                              const unsigned int* __restrict__ ei,
                              int* __restrict__ flags)
{
    __shared__ int cnt_band, cnt_zero;
    if (threadIdx.x == 0) { cnt_band = 0; cnt_zero = 0; }
    __syncthreads();
    unsigned w  = x0[threadIdx.x];
    unsigned eb = ((w & 0xFFFFu) >> 7) & 0xFFu;
    if (eb >= 90u && eb <= 140u) atomicAdd(&cnt_band, 1);
    if (ei[2 * threadIdx.x + 1] == 0u) atomicAdd(&cnt_zero, 1);
    __syncthreads();
    if (threadIdx.x == 0) {
        flags[0] = (cnt_band < 200) ? 1 : 0;   // 1 = fp32
        flags[1] = (cnt_zero >= 250) ? 1 : 0;  // 1 = int64
    }
}

// ---------------------------------------------------------------------------
// Single merged weight-conversion kernel (compile-time region table)
// ---------------------------------------------------------------------------
#define SZ_EMB (92 * 128)
#define SZ_SQ  (128 * 128)
#define SZ_GAT (128 * 256)
#define B0_ (SZ_EMB)
#define B1_ (B0_ + SZ_SQ)
#define B2_ (B1_ + SZ_SQ)
#define B3_ (B2_ + SZ_SQ)
#define B4_ (B3_ + SZ_SQ)
#define B5_ (B4_ + SZ_GAT)
#define B6_ (B5_ + SZ_GAT)   // total = 142848

__global__ void cvt_all_kernel(const void* __restrict__ w_emb, const void* __restrict__ w1,
                               const void* __restrict__ w2, const void* __restrict__ wmu,
                               const void* __restrict__ wvar, const void* __restrict__ wgat,
                               const void* __restrict__ wdec,
                               float* __restrict__ dst, const int* __restrict__ flags)
{
    const int f32 = flags[0];
    int i = blockIdx.x * blockDim.x + threadIdx.x;
    if (i >= B6_) return;
    float v;
    if      (i < B0_) v = ldf(w_emb, i, f32);
    else if (i < B1_) v = ldf(w1,   i - B0_, f32);
    else if (i < B2_) v = ldf(w2,   i - B1_, f32);
    else if (i < B3_) v = ldf(wmu,  i - B2_, f32);
    else if (i < B4_) v = ldf(wvar, i - B3_, f32);
    else if (i < B5_) v = ldf(wgat, i - B4_, f32);
    else              v = ldf(wdec, i - B5_, f32);
    dst[i] = v;
}

// ---------------------------------------------------------------------------
// CSR build: histogram -> single-block scan -> scatter (sorted by dst)
// ---------------------------------------------------------------------------
__global__ void hist_kernel(const void* __restrict__ ei, int* __restrict__ deg,
                            const int* __restrict__ flags)
{
    int e = blockIdx.x * blockDim.x + threadIdx.x;
    if (e >= EE) return;
    const int i64 = flags[1];
    int d = i64 ? (int)((const long long*)ei)[EE + e] : ((const int*)ei)[EE + e];
    atomicAdd(&deg[d], 1);
}

__global__ __launch_bounds__(256) void scan_kernel(const int* __restrict__ deg,
                                                   int* __restrict__ off,
                                                   int* __restrict__ cur)
{
    __shared__ int ssum[256];
    const int CH = (NN + 255) / 256;   // 79
    int tid = threadIdx.x;
    int base = tid * CH;
    int s = 0;
    for (int i = 0; i < CH; i++) { int idx = base + i; if (idx < NN) s += deg[idx]; }
    ssum[tid] = s;
    __syncthreads();
    for (int st = 1; st < 256; st <<= 1) {
        int t = (tid >= st) ? ssum[tid - st] : 0;
        __syncthreads();
        ssum[tid] += t;
        __syncthreads();
    }
    int run = ssum[tid] - s;           // exclusive prefix
    for (int i = 0; i < CH; i++) {
        int idx = base + i;
        if (idx < NN) { off[idx] = run; cur[idx] = run; run += deg[idx]; }
    }
    if (tid == 255) off[NN] = ssum[255];
}

__global__ void scatter_kernel(const void* __restrict__ ei, int* __restrict__ cur,
                               int* __restrict__ csr, const int* __restrict__ flags)
{
    int e = blockIdx.x * blockDim.x + threadIdx.x;
    if (e >= EE) return;
    const int i64 = flags[1];
    int s, d;
    if (i64) { s = (int)((const long long*)ei)[e]; d = (int)((const long long*)ei)[EE + e]; }
    else     { s = ((const int*)ei)[e];            d = ((const int*)ei)[EE + e]; }
    int pos = atomicAdd(&cur[d], 1);
    csr[pos] = s;
}

// ---------------------------------------------------------------------------
// GEMM: C[M,NC] = (A [+abias]) @ W + bias. W fp32 pre-converted, 16 rows/block.
// a_mode: 0 internal bf16, 1 external dual. OUT_MODE: 0 fp32, 1 bf16, 2 ext dual.
// ---------------------------------------------------------------------------
template<int K, int NC, int ROWS, int OUT_MODE>
__global__ __launch_bounds__(NC) void gemm_kernel(
    const void* __restrict__ A, int a_mode,
    const void* __restrict__ abias,
    const float* __restrict__ W, const void* __restrict__ bias,
    void* __restrict__ Cout, int out_off, const int* __restrict__ flags)
{
    const int f32 = flags[0];
    __shared__ float As[ROWS][K];
    const int row0 = blockIdx.x * ROWS;
    for (int idx = threadIdx.x; idx < ROWS * K; idx += NC) {
        int r = idx / K, k = idx - r * K;
        int g = (row0 + r) * K + k;
        float v = a_mode ? ldf(A, g, f32) : b2f(((const __hip_bfloat16*)A)[g]);
        if (abias) v += ldf(abias, k, f32);
        As[r][k] = v;
    }
    __syncthreads();
    const int col = threadIdx.x;
    float acc[ROWS];
#pragma unroll
    for (int r = 0; r < ROWS; r++) acc[r] = 0.f;
    for (int k = 0; k < K; k += 4) {
        float w0 = W[(k + 0) * NC + col];
        float w1 = W[(k + 1) * NC + col];
        float w2 = W[(k + 2) * NC + col];
        float w3 = W[(k + 3) * NC + col];
#pragma unroll
        for (int r = 0; r < ROWS; r++)
            acc[r] += As[r][k] * w0 + As[r][k + 1] * w1
                    + As[r][k + 2] * w2 + As[r][k + 3] * w3;
    }
    float b = bias ? ldf(bias, col, f32) : 0.f;
#pragma unroll
    for (int r = 0; r < ROWS; r++) {
        int o = (row0 + r) * NC + col;
        float v = acc[r] + b;
        if (OUT_MODE == 0)      ((float*)Cout)[o] = v;
        else if (OUT_MODE == 1) ((__hip_bfloat16*)Cout)[o] = __float2bfloat16(v);
        else                    stf(Cout, out_off + o, v, f32);
    }
}

// ---------------------------------------------------------------------------
// BatchNorm (training): column sums / sumsq (fp32 Y), normalize+ReLU -> bf16
// ---------------------------------------------------------------------------
__global__ void bn_stats_kernel(const float* __restrict__ Y,
                                float* __restrict__ sums, float* __restrict__ sumsq)
{
    int c  = threadIdx.x & (CC - 1);
    int rg = threadIdx.x >> 7;
    int stride = gridDim.x * 2;
    float s = 0.f, q = 0.f;
    for (int r = blockIdx.x * 2 + rg; r < NN; r += stride) {
        float v = Y[r * CC + c];
        s += v; q += v * v;
    }
    atomicAdd(&sums[c], s);
    atomicAdd(&sumsq[c], q);
}

__global__ void bn_relu_kernel(const float* __restrict__ Y, __hip_bfloat16* __restrict__ X,
                               const float* __restrict__ sums, const float* __restrict__ sumsq,
                               const void* __restrict__ g, const void* __restrict__ be,
                               const int* __restrict__ flags)
{
    const int f32 = flags[0];
    int idx = blockIdx.x * blockDim.x + threadIdx.x;
    if (idx >= NN * CC) return;
    int c = idx & (CC - 1);
    float mean = sums[c] * (1.f / NN);
    float var  = sumsq[c] * (1.f / NN) - mean * mean;
    float inv  = rsqrtf(fmaxf(var, 0.f) + BN_EPS);
    float v = (Y[idx] - mean) * inv * ldf(g, c, f32) + ldf(be, c, f32);
    X[idx] = __float2bfloat16(v > 0.f ? v : 0.f);
}

// ---------------------------------------------------------------------------
// GIN: H[d] = X[d] + sum_{s in N(d)} X[s]   (bf16 rows, uint2 = 4ch gather)
// ---------------------------------------------------------------------------
__global__ __launch_bounds__(128) void gin_gather_kernel(
    const uint2* __restrict__ X2, uint2* __restrict__ H2,
    const int* __restrict__ off, const int* __restrict__ csr)
{
    int d = blockIdx.x, t = threadIdx.x;
    int g = t >> 5, u = t & 31;        // 4 edge-groups x 32 ch-quads (128 ch)
    float4 acc = make_float4(0.f, 0.f, 0.f, 0.f);
    if (g == 0) acc = bf4(X2[d * 32 + u]);
    int b = off[d], e = off[d + 1];
    __shared__ int ssrc[64];
    __shared__ float4 sred[128];
    for (int chunk = b; chunk < e; chunk += 64) {
        int n = min(64, e - chunk);
        if (t < n) ssrc[t] = csr[chunk + t];
        __syncthreads();
        for (int j = g; j < n; j += 4) {
            float4 v = bf4(X2[ssrc[j] * 32 + u]);
            acc.x += v.x; acc.y += v.y; acc.z += v.z; acc.w += v.w;
        }
        __syncthreads();
    }
    sred[t] = acc;
    __syncthreads();
    if (t < 32) {
        float4 a = sred[t], b4 = sred[t + 32], c4 = sred[t + 64], d4 = sred[t + 96];
        a.x += b4.x + c4.x + d4.x;
        a.y += b4.y + c4.y + d4.y;
        a.z += b4.z + c4.z + d4.z;
        a.w += b4.w + c4.w + d4.w;
        H2[d * 32 + t] = f4bf(a);
    }
}

// ---------------------------------------------------------------------------
// VAE reparameterization + write zin/mu/logvar outputs; Z stored bf16
// ---------------------------------------------------------------------------
__global__ void z_kernel(const float* __restrict__ MU, const float* __restrict__ LV,
                         const void* __restrict__ eps,
                         __hip_bfloat16* __restrict__ Z, void* __restrict__ out,
                         const int* __restrict__ flags)
{
    const int f32 = flags[0];
    int idx = blockIdx.x * blockDim.x + threadIdx.x;
    if (idx >= NN * CC) return;
    float mu = MU[idx], lv = LV[idx];
    float z = ldf(eps, idx, f32) * expf(0.5f * lv) + mu;
    Z[idx] = __float2bfloat16(z);
    stf(out, idx, z, f32);                  // zin
    stf(out, 2 * NN * CC + idx, mu, f32);   // mu
    stf(out, 3 * NN * CC + idx, lv, f32);   // logvar
}

// ---------------------------------------------------------------------------
// GAT attention scores per (node, head), bf16 HH
// ---------------------------------------------------------------------------
__global__ void att_kernel(const __hip_bfloat16* __restrict__ HHb,
                           const void* __restrict__ att_src, const void* __restrict__ att_dst,
                           float* __restrict__ AS, float* __restrict__ AD,
                           const int* __restrict__ flags)
{
    const int f32 = flags[0];
    int wid  = (blockIdx.x * blockDim.x + threadIdx.x) >> 6;
    int lane = threadIdx.x & 63;
    if (wid >= NN * 2) return;
    int n = wid >> 1, h = wid & 1;
    int base = n * 256 + h * CC;
    float v1 = b2f(HHb[base + lane]), v2 = b2f(HHb[base + lane + 64]);
    float s = v1 * ldf(att_src, h * CC + lane, f32) + v2 * ldf(att_src, h * CC + lane + 64, f32);
    float d = v1 * ldf(att_dst, h * CC + lane, f32) + v2 * ldf(att_dst, h * CC + lane + 64, f32);
#pragma unroll
    for (int off = 32; off; off >>= 1) {
        s += __shfl_down(s, off);
        d += __shfl_down(d, off);
    }
    if (lane == 0) { AS[wid] = s; AD[wid] = d; }
}

// ---------------------------------------------------------------------------
// GAT softmax stats per (node, head)
// ---------------------------------------------------------------------------
__global__ void gat_stats_kernel(const float* __restrict__ AS, const float* __restrict__ AD,
                                 const int* __restrict__ off, const int* __restrict__ csr,
                                 float* __restrict__ DMAX, float* __restrict__ DINV)
{
    int wid  = (blockIdx.x * blockDim.x + threadIdx.x) >> 6;
    int lane = threadIdx.x & 63;
    if (wid >= NN * 2) return;
    int n = wid >> 1, h = wid & 1;
    int b = off[n], e = off[n + 1];
    float adh = AD[n * 2 + h];
    float self_l = leaky02(AS[n * 2 + h] + adh);
    float m = (lane == 0) ? self_l : NEG_INF;
    for (int i = b + lane; i < e; i += 64) {
        int s = csr[i];
        m = fmaxf(m, leaky02(AS[s * 2 + h] + adh));
    }
#pragma unroll
    for (int o = 32; o; o >>= 1) m = fmaxf(m, __shfl_xor(m, o));
    float sum = (lane == 0) ? expf(self_l - m) : 0.f;
    for (int i = b + lane; i < e; i += 64) {
        int s = csr[i];
        sum += expf(leaky02(AS[s * 2 + h] + adh) - m);
    }
#pragma unroll
    for (int o = 32; o; o >>= 1) sum += __shfl_xor(sum, o);
    if (lane == 0) { DMAX[wid] = m; DINV[wid] = 1.f / sum; }
}

// ---------------------------------------------------------------------------
// GAT aggregation (no decoder): OUT[d,h,:] = sum alpha * HH[s,h,:] (+self loop)
// bf16 rows; alpha once per (edge,head) into LDS; fp32 accumulate.
// ---------------------------------------------------------------------------
__global__ __launch_bounds__(256) void gat_agg_kernel(
    const uint2* __restrict__ HH2,
    const float* __restrict__ AS, const float* __restrict__ AD,
    const float* __restrict__ DMAX, const float* __restrict__ DINV,
    const int* __restrict__ off, const int* __restrict__ csr,
    uint2* __restrict__ OUT2)
{
    int d = blockIdx.x, t = threadIdx.x;
    int g = t >> 6, u = t & 63;        // 4 edge-groups x 64 ch-quads (256 ch)
    int hu = u >> 5;                   // head of this channel quad
    float ad0 = AD[d * 2], ad1 = AD[d * 2 + 1];
    float m0 = DMAX[d * 2], m1 = DMAX[d * 2 + 1];
    float i0 = DINV[d * 2], i1 = DINV[d * 2 + 1];
    float4 acc = make_float4(0.f, 0.f, 0.f, 0.f);
    if (g == 0) {      // self loop
        float adh = hu ? ad1 : ad0;
        float a0 = expf(leaky02(AS[d * 2 + hu] + adh) - (hu ? m1 : m0)) * (hu ? i1 : i0);
        float4 v = bf4(HH2[d * 64 + u]);
        acc = make_float4(a0 * v.x, a0 * v.y, a0 * v.z, a0 * v.w);
    }
    int b = off[d], e = off[d + 1];
    __shared__ int ssrc[64];
    __shared__ float salpha[2][64];
    __shared__ float4 sred[256];
    for (int chunk = b; chunk < e; chunk += 64) {
        int n = min(64, e - chunk);
        if (t < n) ssrc[t] = csr[chunk + t];
        __syncthreads();
        if (t < 128) {
            int j = t & 63, hh = t >> 6;
            if (j < n) {
                int s = ssrc[j];
                float adh = hh ? ad1 : ad0;
                salpha[hh][j] = expf(leaky02(AS[s * 2 + hh] + adh) - (hh ? m1 : m0))
                              * (hh ? i1 : i0);
            }
        }
        __syncthreads();
        for (int j = g; j < n; j += 4) {
            float al = salpha[hu][j];
            float4 v = bf4(HH2[ssrc[j] * 64 + u]);
            acc.x += al * v.x; acc.y += al * v.y;
            acc.z += al * v.z; acc.w += al * v.w;
        }
        __syncthreads();
    }
    sred[t] = acc;
    __syncthreads();
    if (t < 64) {
        float4 a = sred[t], b4 = sred[t + 64], c4 = sred[t + 128], d4 = sred[t + 192];
        a.x += b4.x + c4.x + d4.x;
        a.y += b4.y + c4.y + d4.y;
        a.z += b4.z + c4.z + d4.z;
        a.w += b4.w + c4.w + d4.w;
        OUT2[d * 64 + t] = f4bf(a);
    }
}

// ---------------------------------------------------------------------------
extern "C" void kernel_launch(void* const* d_in, const int* in_sizes, int n_in,
                              void* d_out, int out_size, void* d_ws, size_t ws_size,
                              hipStream_t stream)
{
    const void* xin    = d_in[0];
    const void* ei     = d_in[1];
    const void* eps    = d_in[2];
    const void* W_emb  = d_in[3];
    const void* b_emb  = d_in[4];
    const void* g_emb  = d_in[5];
    const void* be_emb = d_in[6];
    const void* W1     = d_in[7];
    const void* b1     = d_in[8];
    const void* g1     = d_in[9];
    const void* be1    = d_in[10];
    const void* W2     = d_in[11];
    const void* b2     = d_in[12];
    const void* W_mu   = d_in[13];
    const void* b_mu   = d_in[14];
    const void* W_var  = d_in[15];
    const void* b_var  = d_in[16];
    const void* W_gat  = d_in[17];
    const void* attS   = d_in[18];
    const void* attD   = d_in[19];
    const void* b_gat  = d_in[20];
    const void* W_dec  = d_in[21];
    const void* b_dec  = d_in[22];

    // workspace layout (fp32 slots): 4*NB + tail ≈ 45 MB
    float* ws = (float*)d_ws;
    const size_t NB = (size_t)NN * CC;       // 2,560,000
    float* B0 = ws;                          // fp32 MU | bf16 HH (N x 256)
    float* B1 = ws + 1 * NB;                 // fp32 Y/LV | bf16 OUT (N x 256)
    float* B2 = ws + 2 * NB;                 // bf16 Xbf | Hbf
    float* B3 = ws + 3 * NB;                 // bf16 Zbf | Zobf
    __hip_bfloat16* Xbf   = (__hip_bfloat16*)B2;       // N x 128
    __hip_bfloat16* Hbf   = Xbf + NB;                  // N x 128
    __hip_bfloat16* Zbf   = (__hip_bfloat16*)B3;       // N x 128
    __hip_bfloat16* Zobf  = Zbf + NB;                  // N x 128
    __hip_bfloat16* HHbf  = (__hip_bfloat16*)B0;       // N x 256
    __hip_bfloat16* OUTbf = (__hip_bfloat16*)B1;       // N x 256
    float* TAIL  = ws + 4 * NB;
    float* AS    = TAIL;                     // 40000
    float* AD    = TAIL + 40000;             // 40000
    float* DMAX  = TAIL + 80000;             // 40000
    float* DINV  = TAIL + 120000;            // 40000
    float* SUMS  = TAIL + 160000;            // 128
    float* SUMSQ = TAIL + 160128;            // 128
    int*   FLAGS = (int*)(TAIL + 160256);    // 16
    int*   DEG   = (int*)(TAIL + 160272);    // 20000
    int*   OFF   = DEG + 20000;              // 20001
    int*   CUR   = OFF + 20001;              // 20000
    int*   CSR   = CUR + 20000;              // 640000
    float* WF    = (float*)(CSR + 640000);   // fp32 weights, 142848 floats
    float* WFemb = WF;
    float* WF1   = WF + B0_;
    float* WF2   = WF + B1_;
    float* WFmu  = WF + B2_;
    float* WFvar = WF + B3_;
    float* WFgat = WF + B4_;
    float* WFdec = WF + B5_;

    detect_kernel<<<1, 256, 0, stream>>>((const unsigned int*)xin,
                                         (const unsigned int*)ei, FLAGS);

    // -------- merged weight conversion --------
    cvt_all_kernel<<<(B6_ + 255) / 256, 256, 0, stream>>>(
        W_emb, W1, W2, W_mu, W_var, W_gat, W_dec, WF, FLAGS);

    // -------- CSR build (sorted by destination) --------
    hipMemsetAsync(DEG, 0, NN * sizeof(int), stream);
    hist_kernel<<<(EE + 255) / 256, 256, 0, stream>>>(ei, DEG, FLAGS);
    scan_kernel<<<1, 256, 0, stream>>>(DEG, OFF, CUR);
    scatter_kernel<<<(EE + 255) / 256, 256, 0, stream>>>(ei, CUR, CSR, FLAGS);

    // -------- Stage A: atom embedding = relu(BN(x @ W_emb + b_emb)) -> Xbf ----
    hipMemsetAsync(SUMS, 0, 2 * CC * sizeof(float), stream);
    gemm_kernel<DIN_, CC, 16, 0><<<NN / 16, CC, 0, stream>>>(
        xin, 1, nullptr, WFemb, b_emb, B1, 0, FLAGS);
    bn_stats_kernel<<<256, 256, 0, stream>>>(B1, SUMS, SUMSQ);
    bn_relu_kernel<<<(NN * CC) / 256, 256, 0, stream>>>(B1, Xbf, SUMS, SUMSQ, g_emb, be_emb, FLAGS);

    // -------- Stage B: GIN x2: x = W2( relu(BN(W1(x+agg))) ) --------
    for (int t = 0; t < 2; t++) {
        gin_gather_kernel<<<NN, 128, 0, stream>>>((const uint2*)Xbf, (uint2*)Hbf, OFF, CSR);
        hipMemsetAsync(SUMS, 0, 2 * CC * sizeof(float), stream);
        gemm_kernel<CC, CC, 16, 0><<<NN / 16, CC, 0, stream>>>(
            Hbf, 0, nullptr, WF1, b1, B1, 0, FLAGS);
        bn_stats_kernel<<<256, 256, 0, stream>>>(B1, SUMS, SUMSQ);
        bn_relu_kernel<<<(NN * CC) / 256, 256, 0, stream>>>(B1, Hbf, SUMS, SUMSQ, g1, be1, FLAGS);
        gemm_kernel<CC, CC, 16, 1><<<NN / 16, CC, 0, stream>>>(
            Hbf, 0, nullptr, WF2, b2, Xbf, 0, FLAGS);
    }

    // -------- Stage C: VAE heads (Xbf -> MU B0, LV B1, Z -> Zbf + out) --------
    gemm_kernel<CC, CC, 16, 0><<<NN / 16, CC, 0, stream>>>(
        Xbf, 0, nullptr, WFmu, b_mu, B0, 0, FLAGS);
    gemm_kernel<CC, CC, 16, 0><<<NN / 16, CC, 0, stream>>>(
        Xbf, 0, nullptr, WFvar, b_var, B1, 0, FLAGS);
    z_kernel<<<(NN * CC) / 256, 256, 0, stream>>>(B0, B1, eps, Zbf, d_out, FLAGS);

    // -------- Stage D: GAT x2; decoder as standalone GEMM --------
    const __hip_bfloat16* zc = Zbf;
    for (int t = 0; t < 2; t++) {
        gemm_kernel<CC, 2 * CC, 16, 1><<<NN / 16, 2 * CC, 0, stream>>>(
            zc, 0, nullptr, WFgat, nullptr, HHbf, 0, FLAGS);
        att_kernel<<<(NN * 2) / 4, 256, 0, stream>>>(HHbf, attS, attD, AS, AD, FLAGS);
        gat_stats_kernel<<<(NN * 2) / 4, 256, 0, stream>>>(AS, AD, OFF, CSR, DMAX, DINV);
        gat_agg_kernel<<<NN, 256, 0, stream>>>(
            (const uint2*)HHbf, AS, AD, DMAX, DINV, OFF, CSR, (uint2*)OUTbf);
        if (t == 0) {
            gemm_kernel<2 * CC, CC, 16, 1><<<NN / 16, CC, 0, stream>>>(
                OUTbf, 0, b_gat, WFdec, b_dec, Zobf, 0, FLAGS);
            zc = Zobf;
        } else {
            // final layer: write zout straight to d_out (dual-dtype)
            gemm_kernel<2 * CC, CC, 16, 2><<<NN / 16, CC, 0, stream>>>(
                OUTbf, 0, b_gat, WFdec, b_dec, d_out, NN * CC, FLAGS);
        }
    }
}

// Round 7
// 647.348 us; speedup vs baseline: 3.7145x; 1.3585x over previous
//
#include <hip/hip_runtime.h>
#include <hip/hip_bf16.h>

// Problem constants
#define NN   20000          // nodes
#define DIN_ 92             // atom feature dim
#define CC   128            // hidden dim
#define EE   640000         // edges (self loops handled explicitly)
#define BN_EPS 1e-5f
#define NEG_INF (-3.0e38f)

typedef short short8 __attribute__((ext_vector_type(8)));
typedef float floatx4 __attribute__((ext_vector_type(4)));

// ---------------------------------------------------------------------------
// Dual-dtype helpers: flags[0]=1 -> external floats are fp32 (else bf16)
//                     flags[1]=1 -> edge_index is int64 (else int32)
// Internal activations bf16; accumulators/stats fp32; GEMMs via bf16 MFMA.
// ---------------------------------------------------------------------------
static __device__ __forceinline__ float b2f(__hip_bfloat16 v) { return __bfloat162float(v); }
static __device__ __forceinline__ float ldf(const void* p, int i, int f32) {
    return f32 ? ((const float*)p)[i]
               : __bfloat162float(((const __hip_bfloat16*)p)[i]);
}
static __device__ __forceinline__ void stf(void* p, int i, float v, int f32) {
    if (f32) ((float*)p)[i] = v;
    else     ((__hip_bfloat16*)p)[i] = __float2bfloat16(v);
}
static __device__ __forceinline__ float leaky02(float x) { return x > 0.f ? x : 0.2f * x; }

static __device__ __forceinline__ float4 bf4(uint2 w) {
    union { uint2 u; __hip_bfloat16 b[4]; } x; x.u = w;
    return make_float4(b2f(x.b[0]), b2f(x.b[1]), b2f(x.b[2]), b2f(x.b[3]));
}
static __device__ __forceinline__ uint2 f4bf(float4 v) {
    union { uint2 u; __hip_bfloat16 b[4]; } x;
    x.b[0] = __float2bfloat16(v.x); x.b[1] = __float2bfloat16(v.y);
    x.b[2] = __float2bfloat16(v.z); x.b[3] = __float2bfloat16(v.w);
    return x.u;
}

// ---------------------------------------------------------------------------
// Runtime dtype detection
// ---------------------------------------------------------------------------
__global__ void detect_kernel(const unsigned int* __restrict__ x0,
                              const unsigned int* __restrict__ ei,
                              int* __restrict__ flags)
{
    __shared__ int cnt_band, cnt_zero;
    if (threadIdx.x == 0) { cnt_band = 0; cnt_zero = 0; }
    __syncthreads();
    unsigned w  = x0[threadIdx.x];
    unsigned eb = ((w & 0xFFFFu) >> 7) & 0xFFu;
    if (eb >= 90u && eb <= 140u) atomicAdd(&cnt_band, 1);
    if (ei[2 * threadIdx.x + 1] == 0u) atomicAdd(&cnt_zero, 1);
    __syncthreads();
    if (threadIdx.x == 0) {
        flags[0] = (cnt_band < 200) ? 1 : 0;   // 1 = fp32
        flags[1] = (cnt_zero >= 250) ? 1 : 0;  // 1 = int64
    }
}

// ---------------------------------------------------------------------------
// Transposed bf16 weight build: WT[n*KP + k] = W[k*N + n]  (zero-pad k>=K)
// Regions (bf16 element offsets), compile-time:
//   emb  N=128 K=92  KP=96  -> 12288
//   w1/w2/mu/var 128x128    -> 16384 each
//   gat  N=256 K=128        -> 32768
//   dec  N=128 K=256        -> 32768
// ---------------------------------------------------------------------------
#define R0_ 12288
#define R1_ (R0_ + 16384)
#define R2_ (R1_ + 16384)
#define R3_ (R2_ + 16384)
#define R4_ (R3_ + 16384)
#define R5_ (R4_ + 32768)
#define R6_ (R5_ + 32768)   // 143360 total

__global__ void wt_kernel(const void* __restrict__ w_emb, const void* __restrict__ w1,
                          const void* __restrict__ w2, const void* __restrict__ wmu,
                          const void* __restrict__ wvar, const void* __restrict__ wgat,
                          const void* __restrict__ wdec,
                          __hip_bfloat16* __restrict__ dst, const int* __restrict__ flags)
{
    const int f32 = flags[0];
    int i = blockIdx.x * blockDim.x + threadIdx.x;
    if (i >= R6_) return;
    float v;
    if (i < R0_) {
        int n = i / 96, k = i - n * 96;
        v = (k < DIN_) ? ldf(w_emb, k * 128 + n, f32) : 0.f;
    } else if (i < R1_) {
        int j = i - R0_; int n = j >> 7, k = j & 127; v = ldf(w1, k * 128 + n, f32);
    } else if (i < R2_) {
        int j = i - R1_; int n = j >> 7, k = j & 127; v = ldf(w2, k * 128 + n, f32);
    } else if (i < R3_) {
        int j = i - R2_; int n = j >> 7, k = j & 127; v = ldf(wmu, k * 128 + n, f32);
    } else if (i < R4_) {
        int j = i - R3_; int n = j >> 7, k = j & 127; v = ldf(wvar, k * 128 + n, f32);
    } else if (i < R5_) {
        int j = i - R4_; int n = j >> 7, k = j & 127; v = ldf(wgat, k * 256 + n, f32);
    } else {
        int j = i - R5_; int n = j >> 8, k = j & 255; v = ldf(wdec, k * 128 + n, f32);
    }
    dst[i] = __float2bfloat16(v);
}

// node features -> bf16 padded [NN][96]
__global__ void xcvt_kernel(const void* __restrict__ xin, __hip_bfloat16* __restrict__ Xin,
                            const int* __restrict__ flags)
{
    const int f32 = flags[0];
    int idx = blockIdx.x * blockDim.x + threadIdx.x;
    if (idx >= NN * 96) return;
    int row = idx / 96, k = idx - row * 96;
    float v = (k < DIN_) ? ldf(xin, row * DIN_ + k, f32) : 0.f;
    Xin[idx] = __float2bfloat16(v);
}

// ---------------------------------------------------------------------------
// CSR build: histogram -> 3-phase scan -> scatter (sorted by dst)
// ---------------------------------------------------------------------------
#define NBS ((NN + 255) / 256)   // 79 scan blocks

__global__ void hist_kernel(const void* __restrict__ ei, int* __restrict__ deg,
                            const int* __restrict__ flags)
{
    int e = blockIdx.x * blockDim.x + threadIdx.x;
    if (e >= EE) return;
    const int i64 = flags[1];
    int d = i64 ? (int)((const long long*)ei)[EE + e] : ((const int*)ei)[EE + e];
    atomicAdd(&deg[d], 1);
}

__global__ void scan1_kernel(const int* __restrict__ deg, int* __restrict__ bsum)
{
    int idx = blockIdx.x * 256 + threadIdx.x;
    int v = (idx < NN) ? deg[idx] : 0;
#pragma unroll
    for (int o = 32; o; o >>= 1) v += __shfl_down(v, o);
    __shared__ int s[4];
    if ((threadIdx.x & 63) == 0) s[threadIdx.x >> 6] = v;
    __syncthreads();
    if (threadIdx.x == 0) bsum[blockIdx.x] = s[0] + s[1] + s[2] + s[3];
}

__global__ void scan2_kernel(const int* __restrict__ bsum, int* __restrict__ boff,
                             int* __restrict__ off)
{
    __shared__ int s[128];
    int t = threadIdx.x;
    int v = (t < NBS) ? bsum[t] : 0;
    s[t] = v;
    __syncthreads();
    for (int st = 1; st < 128; st <<= 1) {
        int u = (t >= st) ? s[t - st] : 0;
        __syncthreads();
        s[t] += u;
        __syncthreads();
    }
    if (t < NBS) boff[t] = s[t] - v;   // exclusive
    if (t == 0) off[NN] = EE;
}

__global__ void scan3_kernel(const int* __restrict__ deg, const int* __restrict__ boff,
                             int* __restrict__ off, int* __restrict__ cur)
{
    __shared__ int s[256];
    int idx = blockIdx.x * 256 + threadIdx.x;
    int t = threadIdx.x;
    int v = (idx < NN) ? deg[idx] : 0;
    s[t] = v;
    __syncthreads();
    for (int st = 1; st < 256; st <<= 1) {
        int u = (t >= st) ? s[t - st] : 0;
        __syncthreads();
        s[t] += u;
        __syncthreads();
    }
    if (idx < NN) { int o = boff[blockIdx.x] + s[t] - v; off[idx] = o; cur[idx] = o; }
}

__global__ void scatter_kernel(const void* __restrict__ ei, int* __restrict__ cur,
                               int* __restrict__ csr, const int* __restrict__ flags)
{
    int e = blockIdx.x * blockDim.x + threadIdx.x;
    if (e >= EE) return;
    const int i64 = flags[1];
    int s, d;
    if (i64) { s = (int)((const long long*)ei)[e]; d = (int)((const long long*)ei)[EE + e]; }
    else     { s = ((const int*)ei)[e];            d = ((const int*)ei)[EE + e]; }
    int pos = atomicAdd(&cur[d], 1);
    csr[pos] = s;
}

// ---------------------------------------------------------------------------
// MFMA GEMM: C[M,NC] = A @ W + bias.  A: [M][KP] bf16 (row k-contiguous),
// WT: [NC][KP] bf16 (transposed, k-contiguous). 16x16x32 bf16 MFMA.
// 256 thr = 4 waves; CG col-groups; wave = (row-tile, col-group);
// CT = NC/(16*CG) col-tiles per wave. M % (16*(4/CG)) == 0 (20000 ok).
// Fragment layouts (m89/m97-verified): A[m=l&15][k=(l>>4)*8+j],
// B(n=l&15, k=(l>>4)*8+j) via WT, C/D col=l&15 row=(l>>4)*4+r.
// OUT_MODE: 0 fp32, 1 bf16, 2 external dual-dtype at out_off.
// ---------------------------------------------------------------------------
template<int KP, int NC, int CG, int OUT_MODE>
__global__ __launch_bounds__(256) void mfma_gemm_kernel(
    const __hip_bfloat16* __restrict__ A,
    const __hip_bfloat16* __restrict__ WT,
    const void* __restrict__ bias,
    void* __restrict__ Cout, int out_off, const int* __restrict__ flags)
{
    const int f32 = flags[0];
    constexpr int MB = 16 * (4 / CG);
    constexpr int CT = NC / (16 * CG);
    int w = threadIdx.x >> 6, l = threadIdx.x & 63;
    int rt = w / CG, cg = w - rt * CG;
    int m0 = blockIdx.x * MB + rt * 16;
    int n0 = cg * (16 * CT);
    int l15 = l & 15, kq = (l >> 4) * 8;
    const __hip_bfloat16* arow = A + (size_t)(m0 + l15) * KP + kq;

    floatx4 acc[CT];
#pragma unroll
    for (int ct = 0; ct < CT; ct++) acc[ct] = (floatx4){0.f, 0.f, 0.f, 0.f};

    for (int kc = 0; kc < KP / 32; kc++) {
        short8 a = *(const short8*)(arow + kc * 32);
#pragma unroll
        for (int ct = 0; ct < CT; ct++) {
            const __hip_bfloat16* brow = WT + (size_t)(n0 + ct * 16 + l15) * KP + kq;
            short8 b = *(const short8*)(brow + kc * 32);
            acc[ct] = __builtin_amdgcn_mfma_f32_16x16x32_bf16(a, b, acc[ct], 0, 0, 0);
        }
    }

    int quad = l >> 4;
#pragma unroll
    for (int ct = 0; ct < CT; ct++) {
        int col = n0 + ct * 16 + l15;
        float bb = bias ? ldf(bias, col, f32) : 0.f;
#pragma unroll
        for (int r = 0; r < 4; r++) {
            int row = m0 + quad * 4 + r;
            float v = acc[ct][r] + bb;
            size_t o = (size_t)row * NC + col;
            if (OUT_MODE == 0)      ((float*)Cout)[o] = v;
            else if (OUT_MODE == 1) ((__hip_bfloat16*)Cout)[o] = __float2bfloat16(v);
            else                    stf(Cout, out_off + (int)o, v, f32);
        }
    }
}

// ---------------------------------------------------------------------------
// BatchNorm (training): column sums / sumsq (fp32 Y), normalize+ReLU -> bf16
// ---------------------------------------------------------------------------
__global__ void bn_stats_kernel(const float* __restrict__ Y,
                                float* __restrict__ sums, float* __restrict__ sumsq)
{
    int c  = threadIdx.x & (CC - 1);
    int rg = threadIdx.x >> 7;
    int stride = gridDim.x * 2;
    float s = 0.f, q = 0.f;
    for (int r = blockIdx.x * 2 + rg; r < NN; r += stride) {
        float v = Y[r * CC + c];
        s += v; q += v * v;
    }
    atomicAdd(&sums[c], s);
    atomicAdd(&sumsq[c], q);
}

__global__ void bn_relu_kernel(const float* __restrict__ Y, __hip_bfloat16* __restrict__ X,
                               const float* __restrict__ sums, const float* __restrict__ sumsq,
                               const void* __restrict__ g, const void* __restrict__ be,
                               const int* __restrict__ flags)
{
    const int f32 = flags[0];
    int idx = blockIdx.x * blockDim.x + threadIdx.x;
    if (idx >= NN * CC) return;
    int c = idx & (CC - 1);
    float mean = sums[c] * (1.f / NN);
    float var  = sumsq[c] * (1.f / NN) - mean * mean;
    float inv  = rsqrtf(fmaxf(var, 0.f) + BN_EPS);
    float v = (Y[idx] - mean) * inv * ldf(g, c, f32) + ldf(be, c, f32);
    X[idx] = __float2bfloat16(v > 0.f ? v : 0.f);
}

// ---------------------------------------------------------------------------
// GIN: H[d] = X[d] + sum_{s in N(d)} X[s]   (bf16 rows, uint2 = 4ch gather)
// ---------------------------------------------------------------------------
__global__ __launch_bounds__(128) void gin_gather_kernel(
    const uint2* __restrict__ X2, uint2* __restrict__ H2,
    const int* __restrict__ off, const int* __restrict__ csr)
{
    int d = blockIdx.x, t = threadIdx.x;
    int g = t >> 5, u = t & 31;        // 4 edge-groups x 32 ch-quads (128 ch)
    float4 acc = make_float4(0.f, 0.f, 0.f, 0.f);
    if (g == 0) acc = bf4(X2[d * 32 + u]);
    int b = off[d], e = off[d + 1];
    __shared__ int ssrc[64];
    __shared__ float4 sred[128];
    for (int chunk = b; chunk < e; chunk += 64) {
        int n = min(64, e - chunk);
        if (t < n) ssrc[t] = csr[chunk + t];
        __syncthreads();
        for (int j = g; j < n; j += 4) {
            float4 v = bf4(X2[ssrc[j] * 32 + u]);
            acc.x += v.x; acc.y += v.y; acc.z += v.z; acc.w += v.w;
        }
        __syncthreads();
    }
    sred[t] = acc;
    __syncthreads();
    if (t < 32) {
        float4 a = sred[t], b4 = sred[t + 32], c4 = sred[t + 64], d4 = sred[t + 96];
        a.x += b4.x + c4.x + d4.x;
        a.y += b4.y + c4.y + d4.y;
        a.z += b4.z + c4.z + d4.z;
        a.w += b4.w + c4.w + d4.w;
        H2[d * 32 + t] = f4bf(a);
    }
}

// ---------------------------------------------------------------------------
// VAE reparameterization + write zin/mu/logvar outputs; Z stored bf16
// ---------------------------------------------------------------------------
__global__ void z_kernel(const float* __restrict__ MU, const float* __restrict__ LV,
                         const void* __restrict__ eps,
                         __hip_bfloat16* __restrict__ Z, void* __restrict__ out,
                         const int* __restrict__ flags)
{
    const int f32 = flags[0];
    int idx = blockIdx.x * blockDim.x + threadIdx.x;
    if (idx >= NN * CC) return;
    float mu = MU[idx], lv = LV[idx];
    float z = ldf(eps, idx, f32) * expf(0.5f * lv) + mu;
    Z[idx] = __float2bfloat16(z);
    stf(out, idx, z, f32);                  // zin
    stf(out, 2 * NN * CC + idx, mu, f32);   // mu
    stf(out, 3 * NN * CC + idx, lv, f32);   // logvar
}

// ---------------------------------------------------------------------------
// GAT attention scores per (node, head), bf16 HH
// ---------------------------------------------------------------------------
__global__ void att_kernel(const __hip_bfloat16* __restrict__ HHb,
                           const void* __restrict__ att_src, const void* __restrict__ att_dst,
                           float* __restrict__ AS, float* __restrict__ AD,
                           const int* __restrict__ flags)
{
    const int f32 = flags[0];
    int wid  = (blockIdx.x * blockDim.x + threadIdx.x) >> 6;
    int lane = threadIdx.x & 63;
    if (wid >= NN * 2) return;
    int n = wid >> 1, h = wid & 1;
    int base = n * 256 + h * CC;
    float v1 = b2f(HHb[base + lane]), v2 = b2f(HHb[base + lane + 64]);
    float s = v1 * ldf(att_src, h * CC + lane, f32) + v2 * ldf(att_src, h * CC + lane + 64, f32);
    float d = v1 * ldf(att_dst, h * CC + lane, f32) + v2 * ldf(att_dst, h * CC + lane + 64, f32);
#pragma unroll
    for (int off = 32; off; off >>= 1) {
        s += __shfl_down(s, off);
        d += __shfl_down(d, off);
    }
    if (lane == 0) { AS[wid] = s; AD[wid] = d; }
}

// ---------------------------------------------------------------------------
// GAT softmax stats per (node, head)
// ---------------------------------------------------------------------------
__global__ void gat_stats_kernel(const float* __restrict__ AS, const float* __restrict__ AD,
                                 const int* __restrict__ off, const int* __restrict__ csr,
                                 float* __restrict__ DMAX, float* __restrict__ DINV)
{
    int wid  = (blockIdx.x * blockDim.x + threadIdx.x) >> 6;
    int lane = threadIdx.x & 63;
    if (wid >= NN * 2) return;
    int n = wid >> 1, h = wid & 1;
    int b = off[n], e = off[n + 1];
    float adh = AD[n * 2 + h];
    float self_l = leaky02(AS[n * 2 + h] + adh);
    float m = (lane == 0) ? self_l : NEG_INF;
    for (int i = b + lane; i < e; i += 64) {
        int s = csr[i];
        m = fmaxf(m, leaky02(AS[s * 2 + h] + adh));
    }
#pragma unroll
    for (int o = 32; o; o >>= 1) m = fmaxf(m, __shfl_xor(m, o));
    float sum = (lane == 0) ? expf(self_l - m) : 0.f;
    for (int i = b + lane; i < e; i += 64) {
        int s = csr[i];
        sum += expf(leaky02(AS[s * 2 + h] + adh) - m);
    }
#pragma unroll
    for (int o = 32; o; o >>= 1) sum += __shfl_xor(sum, o);
    if (lane == 0) { DMAX[wid] = m; DINV[wid] = 1.f / sum; }
}

// ---------------------------------------------------------------------------
// GAT aggregation: OUT[d,h,:] = sum alpha * HH[s,h,:] (+self loop) + b_gat
// ---------------------------------------------------------------------------
__global__ __launch_bounds__(256) void gat_agg_kernel(
    const uint2* __restrict__ HH2,
    const float* __restrict__ AS, const float* __restrict__ AD,
    const float* __restrict__ DMAX, const float* __restrict__ DINV,
    const int* __restrict__ off, const int* __restrict__ csr,
    const void* __restrict__ b_gat, uint2* __restrict__ OUT2,
    const int* __restrict__ flags)
{
    const int f32 = flags[0];
    int d = blockIdx.x, t = threadIdx.x;
    int g = t >> 6, u = t & 63;        // 4 edge-groups x 64 ch-quads (256 ch)
    int hu = u >> 5;                   // head of this channel quad
    float ad0 = AD[d * 2], ad1 = AD[d * 2 + 1];
    float m0 = DMAX[d * 2], m1 = DMAX[d * 2 + 1];
    float i0 = DINV[d * 2], i1 = DINV[d * 2 + 1];
    float4 acc = make_float4(0.f, 0.f, 0.f, 0.f);
    if (g == 0) {      // self loop
        float adh = hu ? ad1 : ad0;
        float a0 = expf(leaky02(AS[d * 2 + hu] + adh) - (hu ? m1 : m0)) * (hu ? i1 : i0);
        float4 v = bf4(HH2[d * 64 + u]);
        acc = make_float4(a0 * v.x, a0 * v.y, a0 * v.z, a0 * v.w);
    }
    int b = off[d], e = off[d + 1];
    __shared__ int ssrc[64];
    __shared__ float salpha[2][64];
    __shared__ float4 sred[256];
    for (int chunk = b; chunk < e; chunk += 64) {
        int n = min(64, e - chunk);
        if (t < n) ssrc[t] = csr[chunk + t];
        __syncthreads();
        if (t < 128) {
            int j = t & 63, hh = t >> 6;
            if (j < n) {
                int s = ssrc[j];
                float adh = hh ? ad1 : ad0;
                salpha[hh][j] = expf(leaky02(AS[s * 2 + hh] + adh) - (hh ? m1 : m0))
                              * (hh ? i1 : i0);
            }
        }
        __syncthreads();
        for (int j = g; j < n; j += 4) {
            float al = salpha[hu][j];
            float4 v = bf4(HH2[ssrc[j] * 64 + u]);
            acc.x += al * v.x; acc.y += al * v.y;
            acc.z += al * v.z; acc.w += al * v.w;
        }
        __syncthreads();
    }
    sred[t] = acc;
    __syncthreads();
    if (t < 64) {
        float4 a = sred[t], b4 = sred[t + 64], c4 = sred[t + 128], d4 = sred[t + 192];
        a.x += b4.x + c4.x + d4.x + ldf(b_gat, 4 * t + 0, f32);
        a.y += b4.y + c4.y + d4.y + ldf(b_gat, 4 * t + 1, f32);
        a.z += b4.z + c4.z + d4.z + ldf(b_gat, 4 * t + 2, f32);
        a.w += b4.w + c4.w + d4.w + ldf(b_gat, 4 * t + 3, f32);
        OUT2[d * 64 + t] = f4bf(a);
    }
}

// ---------------------------------------------------------------------------
extern "C" void kernel_launch(void* const* d_in, const int* in_sizes, int n_in,
                              void* d_out, int out_size, void* d_ws, size_t ws_size,
                              hipStream_t stream)
{
    const void* xin    = d_in[0];
    const void* ei     = d_in[1];
    const void* eps    = d_in[2];
    const void* W_emb  = d_in[3];
    const void* b_emb  = d_in[4];
    const void* g_emb  = d_in[5];
    const void* be_emb = d_in[6];
    const void* W1     = d_in[7];
    const void* b1     = d_in[8];
    const void* g1     = d_in[9];
    const void* be1    = d_in[10];
    const void* W2     = d_in[11];
    const void* b2     = d_in[12];
    const void* W_mu   = d_in[13];
    const void* b_mu   = d_in[14];
    const void* W_var  = d_in[15];
    const void* b_var  = d_in[16];
    const void* W_gat  = d_in[17];
    const void* attS   = d_in[18];
    const void* attD   = d_in[19];
    const void* b_gat  = d_in[20];
    const void* W_dec  = d_in[21];
    const void* b_dec  = d_in[22];

    // workspace layout: 4*NB fp32 slots + tail ≈ 48.5 MB
    float* ws = (float*)d_ws;
    const size_t NB = (size_t)NN * CC;       // 2,560,000
    float* B0 = ws;                          // fp32 MU | bf16 HH (N x 256)
    float* B1 = ws + 1 * NB;                 // fp32 Y/LV | bf16 OUT (N x 256)
    float* B2 = ws + 2 * NB;                 // bf16 Xbf | Hbf
    float* B3 = ws + 3 * NB;                 // bf16 Zbf | Zobf
    __hip_bfloat16* Xbf   = (__hip_bfloat16*)B2;       // N x 128
    __hip_bfloat16* Hbf   = Xbf + NB;                  // N x 128
    __hip_bfloat16* Zbf   = (__hip_bfloat16*)B3;       // N x 128
    __hip_bfloat16* Zobf  = Zbf + NB;                  // N x 128
    __hip_bfloat16* HHbf  = (__hip_bfloat16*)B0;       // N x 256
    __hip_bfloat16* OUTbf = (__hip_bfloat16*)B1;       // N x 256
    float* TAIL  = ws + 4 * NB;
    float* AS    = TAIL;                     // 40000
    float* AD    = TAIL + 40000;             // 40000
    float* DMAX  = TAIL + 80000;             // 40000
    float* DINV  = TAIL + 120000;            // 40000
    float* SUMS  = TAIL + 160000;            // 128
    float* SUMSQ = TAIL + 160128;            // 128
    int*   FLAGS = (int*)(TAIL + 160256);    // 16
    int*   BSUM  = (int*)(TAIL + 160272);    // 128
    int*   BOFF  = (int*)(TAIL + 160400);    // 128
    int*   DEG   = (int*)(TAIL + 160528);    // 20000
    int*   OFF   = DEG + 20000;              // 20008 (padded)
    int*   CUR   = OFF + 20008;              // 20000
    int*   CSR   = CUR + 20000;              // 640000
    __hip_bfloat16* WTB = (__hip_bfloat16*)(CSR + 640000);   // 143360 bf16
    __hip_bfloat16* WTemb = WTB;
    __hip_bfloat16* WT1   = WTB + R0_;
    __hip_bfloat16* WT2   = WTB + R1_;
    __hip_bfloat16* WTmu  = WTB + R2_;
    __hip_bfloat16* WTvar = WTB + R3_;
    __hip_bfloat16* WTgat = WTB + R4_;
    __hip_bfloat16* WTdec = WTB + R5_;
    __hip_bfloat16* Xin   = WTB + R6_;       // NN x 96 bf16

    detect_kernel<<<1, 256, 0, stream>>>((const unsigned int*)xin,
                                         (const unsigned int*)ei, FLAGS);

    // -------- weight transpose->bf16 + padded node features --------
    wt_kernel<<<(R6_ + 255) / 256, 256, 0, stream>>>(
        W_emb, W1, W2, W_mu, W_var, W_gat, W_dec, WTB, FLAGS);
    xcvt_kernel<<<(NN * 96 + 255) / 256, 256, 0, stream>>>(xin, Xin, FLAGS);

    // -------- CSR build (sorted by destination) --------
    hipMemsetAsync(DEG, 0, NN * sizeof(int), stream);
    hist_kernel<<<(EE + 255) / 256, 256, 0, stream>>>(ei, DEG, FLAGS);
    scan1_kernel<<<NBS, 256, 0, stream>>>(DEG, BSUM);
    scan2_kernel<<<1, 128, 0, stream>>>(BSUM, BOFF, OFF);
    scan3_kernel<<<NBS, 256, 0, stream>>>(DEG, BOFF, OFF, CUR);
    scatter_kernel<<<(EE + 255) / 256, 256, 0, stream>>>(ei, CUR, CSR, FLAGS);

    // -------- Stage A: atom embedding = relu(BN(x @ W_emb + b_emb)) -> Xbf ----
    hipMemsetAsync(SUMS, 0, 2 * CC * sizeof(float), stream);
    mfma_gemm_kernel<96, 128, 2, 0><<<NN / 32, 256, 0, stream>>>(
        Xin, WTemb, b_emb, B1, 0, FLAGS);
    bn_stats_kernel<<<256, 256, 0, stream>>>(B1, SUMS, SUMSQ);
    bn_relu_kernel<<<(NN * CC) / 256, 256, 0, stream>>>(B1, Xbf, SUMS, SUMSQ, g_emb, be_emb, FLAGS);

    // -------- Stage B: GIN x2: x = W2( relu(BN(W1(x+agg))) ) --------
    for (int t = 0; t < 2; t++) {
        gin_gather_kernel<<<NN, 128, 0, stream>>>((const uint2*)Xbf, (uint2*)Hbf, OFF, CSR);
        hipMemsetAsync(SUMS, 0, 2 * CC * sizeof(float), stream);
        mfma_gemm_kernel<128, 128, 2, 0><<<NN / 32, 256, 0, stream>>>(
            Hbf, WT1, b1, B1, 0, FLAGS);
        bn_stats_kernel<<<256, 256, 0, stream>>>(B1, SUMS, SUMSQ);
        bn_relu_kernel<<<(NN * CC) / 256, 256, 0, stream>>>(B1, Hbf, SUMS, SUMSQ, g1, be1, FLAGS);
        mfma_gemm_kernel<128, 128, 2, 1><<<NN / 32, 256, 0, stream>>>(
            Hbf, WT2, b2, Xbf, 0, FLAGS);
    }

    // -------- Stage C: VAE heads (Xbf -> MU B0, LV B1, Z -> Zbf + out) --------
    mfma_gemm_kernel<128, 128, 2, 0><<<NN / 32, 256, 0, stream>>>(
        Xbf, WTmu, b_mu, B0, 0, FLAGS);
    mfma_gemm_kernel<128, 128, 2, 0><<<NN / 32, 256, 0, stream>>>(
        Xbf, WTvar, b_var, B1, 0, FLAGS);
    z_kernel<<<(NN * CC) / 256, 256, 0, stream>>>(B0, B1, eps, Zbf, d_out, FLAGS);

    // -------- Stage D: GAT x2; decoder as MFMA GEMM --------
    const __hip_bfloat16* zc = Zbf;
    for (int t = 0; t < 2; t++) {
        mfma_gemm_kernel<128, 256, 4, 1><<<NN / 16, 256, 0, stream>>>(
            zc, WTgat, nullptr, HHbf, 0, FLAGS);
        att_kernel<<<(NN * 2) / 4, 256, 0, stream>>>(HHbf, attS, attD, AS, AD, FLAGS);
        gat_stats_kernel<<<(NN * 2) / 4, 256, 0, stream>>>(AS, AD, OFF, CSR, DMAX, DINV);
        gat_agg_kernel<<<NN, 256, 0, stream>>>(
            (const uint2*)HHbf, AS, AD, DMAX, DINV, OFF, CSR, b_gat, (uint2*)OUTbf, FLAGS);
        if (t == 0) {
            mfma_gemm_kernel<256, 128, 2, 1><<<NN / 32, 256, 0, stream>>>(
                OUTbf, WTdec, b_dec, Zobf, 0, FLAGS);
            zc = Zobf;
        } else {
            mfma_gemm_kernel<256, 128, 2, 2><<<NN / 32, 256, 0, stream>>>(
                OUTbf, WTdec, b_dec, d_out, NN * CC, FLAGS);
        }
    }
}

// Round 8
// 622.811 us; speedup vs baseline: 3.8608x; 1.0394x over previous
//
#include <hip/hip_runtime.h>
#include <hip/hip_bf16.h>

// Problem constants
#define NN   20000          // nodes
#define DIN_ 92             // atom feature dim
#define CC   128            // hidden dim
#define EE   640000         // edges (self loops handled explicitly)
#define BN_EPS 1e-5f
#define NEG_INF (-3.0e38f)

typedef short short8 __attribute__((ext_vector_type(8)));
typedef float floatx4 __attribute__((ext_vector_type(4)));

// ---------------------------------------------------------------------------
// Dual-dtype helpers: flags[0]=1 -> external floats are fp32 (else bf16)
//                     flags[1]=1 -> edge_index is int64 (else int32)
// ---------------------------------------------------------------------------
static __device__ __forceinline__ float b2f(__hip_bfloat16 v) { return __bfloat162float(v); }
static __device__ __forceinline__ float ldf(const void* p, int i, int f32) {
    return f32 ? ((const float*)p)[i]
               : __bfloat162float(((const __hip_bfloat16*)p)[i]);
}
static __device__ __forceinline__ void stf(void* p, int i, float v, int f32) {
    if (f32) ((float*)p)[i] = v;
    else     ((__hip_bfloat16*)p)[i] = __float2bfloat16(v);
}
static __device__ __forceinline__ float leaky02(float x) { return x > 0.f ? x : 0.2f * x; }

// bf16 pair/quad decode via bit ops (bf16 = top half of fp32)
static __device__ __forceinline__ float2 bfp(unsigned w) {
    return make_float2(__uint_as_float(w << 16), __uint_as_float(w & 0xffff0000u));
}
static __device__ __forceinline__ float4 bf4(uint2 w) {
    return make_float4(__uint_as_float(w.x << 16), __uint_as_float(w.x & 0xffff0000u),
                       __uint_as_float(w.y << 16), __uint_as_float(w.y & 0xffff0000u));
}
static __device__ __forceinline__ uint2 f4bf(float4 v) {
    union { uint2 u; __hip_bfloat16 b[4]; } x;
    x.b[0] = __float2bfloat16(v.x); x.b[1] = __float2bfloat16(v.y);
    x.b[2] = __float2bfloat16(v.z); x.b[3] = __float2bfloat16(v.w);
    return x.u;
}
static __device__ __forceinline__ unsigned f2bf(float2 v) {
    union { unsigned u; __hip_bfloat16 b[2]; } x;
    x.b[0] = __float2bfloat16(v.x); x.b[1] = __float2bfloat16(v.y);
    return x.u;
}

// ---------------------------------------------------------------------------
// Runtime dtype detection
// ---------------------------------------------------------------------------
__global__ void detect_kernel(const unsigned int* __restrict__ x0,
                              const unsigned int* __restrict__ ei,
                              int* __restrict__ flags)
{
    __shared__ int cnt_band, cnt_zero;
    if (threadIdx.x == 0) { cnt_band = 0; cnt_zero = 0; }
    __syncthreads();
    unsigned w  = x0[threadIdx.x];
    unsigned eb = ((w & 0xFFFFu) >> 7) & 0xFFu;
    if (eb >= 90u && eb <= 140u) atomicAdd(&cnt_band, 1);
    if (ei[2 * threadIdx.x + 1] == 0u) atomicAdd(&cnt_zero, 1);
    __syncthreads();
    if (threadIdx.x == 0) {
        flags[0] = (cnt_band < 200) ? 1 : 0;   // 1 = fp32
        flags[1] = (cnt_zero >= 250) ? 1 : 0;  // 1 = int64
    }
}

// ---------------------------------------------------------------------------
// Transposed bf16 weight build: WT[n*KP + k] = W[k*N + n]  (zero-pad k>=K)
// mu (R2_) and var (R3_) are CONTIGUOUS -> usable as one NC=256 weight.
// ---------------------------------------------------------------------------
#define R0_ 12288
#define R1_ (R0_ + 16384)
#define R2_ (R1_ + 16384)
#define R3_ (R2_ + 16384)
#define R4_ (R3_ + 16384)
#define R5_ (R4_ + 32768)
#define R6_ (R5_ + 32768)   // 143360 total

__global__ void wt_kernel(const void* __restrict__ w_emb, const void* __restrict__ w1,
                          const void* __restrict__ w2, const void* __restrict__ wmu,
                          const void* __restrict__ wvar, const void* __restrict__ wgat,
                          const void* __restrict__ wdec,
                          __hip_bfloat16* __restrict__ dst, const int* __restrict__ flags)
{
    const int f32 = flags[0];
    int i = blockIdx.x * blockDim.x + threadIdx.x;
    if (i >= R6_) return;
    float v;
    if (i < R0_) {
        int n = i / 96, k = i - n * 96;
        v = (k < DIN_) ? ldf(w_emb, k * 128 + n, f32) : 0.f;
    } else if (i < R1_) {
        int j = i - R0_; int n = j >> 7, k = j & 127; v = ldf(w1, k * 128 + n, f32);
    } else if (i < R2_) {
        int j = i - R1_; int n = j >> 7, k = j & 127; v = ldf(w2, k * 128 + n, f32);
    } else if (i < R3_) {
        int j = i - R2_; int n = j >> 7, k = j & 127; v = ldf(wmu, k * 128 + n, f32);
    } else if (i < R4_) {
        int j = i - R3_; int n = j >> 7, k = j & 127; v = ldf(wvar, k * 128 + n, f32);
    } else if (i < R5_) {
        int j = i - R4_; int n = j >> 7, k = j & 127; v = ldf(wgat, k * 256 + n, f32);
    } else {
        int j = i - R5_; int n = j >> 8, k = j & 255; v = ldf(wdec, k * 128 + n, f32);
    }
    dst[i] = __float2bfloat16(v);
}

// node features -> bf16 padded [NN][96]
__global__ void xcvt_kernel(const void* __restrict__ xin, __hip_bfloat16* __restrict__ Xin,
                            const int* __restrict__ flags)
{
    const int f32 = flags[0];
    int idx = blockIdx.x * blockDim.x + threadIdx.x;
    if (idx >= NN * 96) return;
    int row = idx / 96, k = idx - row * 96;
    float v = (k < DIN_) ? ldf(xin, row * DIN_ + k, f32) : 0.f;
    Xin[idx] = __float2bfloat16(v);
}

// ---------------------------------------------------------------------------
// CSR build: histogram -> 3-phase scan -> scatter (sorted by dst)
// ---------------------------------------------------------------------------
#define NBS ((NN + 255) / 256)   // 79 scan blocks

__global__ void hist_kernel(const void* __restrict__ ei, int* __restrict__ deg,
                            const int* __restrict__ flags)
{
    int e = blockIdx.x * blockDim.x + threadIdx.x;
    if (e >= EE) return;
    const int i64 = flags[1];
    int d = i64 ? (int)((const long long*)ei)[EE + e] : ((const int*)ei)[EE + e];
    atomicAdd(&deg[d], 1);
}

__global__ void scan1_kernel(const int* __restrict__ deg, int* __restrict__ bsum)
{
    int idx = blockIdx.x * 256 + threadIdx.x;
    int v = (idx < NN) ? deg[idx] : 0;
#pragma unroll
    for (int o = 32; o; o >>= 1) v += __shfl_down(v, o);
    __shared__ int s[4];
    if ((threadIdx.x & 63) == 0) s[threadIdx.x >> 6] = v;
    __syncthreads();
    if (threadIdx.x == 0) bsum[blockIdx.x] = s[0] + s[1] + s[2] + s[3];
}

__global__ void scan2_kernel(const int* __restrict__ bsum, int* __restrict__ boff,
                             int* __restrict__ off)
{
    __shared__ int s[128];
    int t = threadIdx.x;
    int v = (t < NBS) ? bsum[t] : 0;
    s[t] = v;
    __syncthreads();
    for (int st = 1; st < 128; st <<= 1) {
        int u = (t >= st) ? s[t - st] : 0;
        __syncthreads();
        s[t] += u;
        __syncthreads();
    }
    if (t < NBS) boff[t] = s[t] - v;   // exclusive
    if (t == 0) off[NN] = EE;
}

__global__ void scan3_kernel(const int* __restrict__ deg, const int* __restrict__ boff,
                             int* __restrict__ off, int* __restrict__ cur)
{
    __shared__ int s[256];
    int idx = blockIdx.x * 256 + threadIdx.x;
    int t = threadIdx.x;
    int v = (idx < NN) ? deg[idx] : 0;
    s[t] = v;
    __syncthreads();
    for (int st = 1; st < 256; st <<= 1) {
        int u = (t >= st) ? s[t - st] : 0;
        __syncthreads();
        s[t] += u;
        __syncthreads();
    }
    if (idx < NN) { int o = boff[blockIdx.x] + s[t] - v; off[idx] = o; cur[idx] = o; }
}

__global__ void scatter_kernel(const void* __restrict__ ei, int* __restrict__ cur,
                               int* __restrict__ csr, const int* __restrict__ flags)
{
    int e = blockIdx.x * blockDim.x + threadIdx.x;
    if (e >= EE) return;
    const int i64 = flags[1];
    int s, d;
    if (i64) { s = (int)((const long long*)ei)[e]; d = (int)((const long long*)ei)[EE + e]; }
    else     { s = ((const int*)ei)[e];            d = ((const int*)ei)[EE + e]; }
    int pos = atomicAdd(&cur[d], 1);
    csr[pos] = s;
}

// ---------------------------------------------------------------------------
// MFMA GEMM (16x16x32 bf16): C[M,NC] = A @ W + bias.
// A:[M][KP] bf16 k-contig, WT:[NC][KP] bf16 k-contig.
// 256 thr = 4 waves; CG col-groups; CT = NC/(16*CG) col-tiles/wave.
// OUT_MODE: 0 fp32, 1 bf16, 2 external dual-dtype at out_off.
// ---------------------------------------------------------------------------
template<int KP, int NC, int CG, int OUT_MODE>
__global__ __launch_bounds__(256) void mfma_gemm_kernel(
    const __hip_bfloat16* __restrict__ A,
    const __hip_bfloat16* __restrict__ WT,
    const void* __restrict__ bias,
    void* __restrict__ Cout, int out_off, const int* __restrict__ flags)
{
    const int f32 = flags[0];
    constexpr int MB = 16 * (4 / CG);
    constexpr int CT = NC / (16 * CG);
    int w = threadIdx.x >> 6, l = threadIdx.x & 63;
    int rt = w / CG, cg = w - rt * CG;
    int m0 = blockIdx.x * MB + rt * 16;
    int n0 = cg * (16 * CT);
    int l15 = l & 15, kq = (l >> 4) * 8;
    const __hip_bfloat16* arow = A + (size_t)(m0 + l15) * KP + kq;

    floatx4 acc[CT];
#pragma unroll
    for (int ct = 0; ct < CT; ct++) acc[ct] = (floatx4){0.f, 0.f, 0.f, 0.f};

    for (int kc = 0; kc < KP / 32; kc++) {
        short8 a = *(const short8*)(arow + kc * 32);
#pragma unroll
        for (int ct = 0; ct < CT; ct++) {
            const __hip_bfloat16* brow = WT + (size_t)(n0 + ct * 16 + l15) * KP + kq;
            short8 b = *(const short8*)(brow + kc * 32);
            acc[ct] = __builtin_amdgcn_mfma_f32_16x16x32_bf16(a, b, acc[ct], 0, 0, 0);
        }
    }

    int quad = l >> 4;
#pragma unroll
    for (int ct = 0; ct < CT; ct++) {
        int col = n0 + ct * 16 + l15;
        float bb = bias ? ldf(bias, col, f32) : 0.f;
#pragma unroll
        for (int r = 0; r < 4; r++) {
            int row = m0 + quad * 4 + r;
            float v = acc[ct][r] + bb;
            size_t o = (size_t)row * NC + col;
            if (OUT_MODE == 0)      ((float*)Cout)[o] = v;
            else if (OUT_MODE == 1) ((__hip_bfloat16*)Cout)[o] = __float2bfloat16(v);
            else                    stf(Cout, out_off + (int)o, v, f32);
        }
    }
}

// ---------------------------------------------------------------------------
// BatchNorm (training): column sums / sumsq (fp32 Y), normalize+ReLU -> bf16
// ---------------------------------------------------------------------------
__global__ void bn_stats_kernel(const float* __restrict__ Y,
                                float* __restrict__ sums, float* __restrict__ sumsq)
{
    int c  = threadIdx.x & (CC - 1);
    int rg = threadIdx.x >> 7;
    int stride = gridDim.x * 2;
    float s = 0.f, q = 0.f;
    for (int r = blockIdx.x * 2 + rg; r < NN; r += stride) {
        float v = Y[r * CC + c];
        s += v; q += v * v;
    }
    atomicAdd(&sums[c], s);
    atomicAdd(&sumsq[c], q);
}

__global__ void bn_relu_kernel(const float* __restrict__ Y, __hip_bfloat16* __restrict__ X,
                               const float* __restrict__ sums, const float* __restrict__ sumsq,
                               const void* __restrict__ g, const void* __restrict__ be,
                               const int* __restrict__ flags)
{
    const int f32 = flags[0];
    int idx = blockIdx.x * blockDim.x + threadIdx.x;
    if (idx >= NN * CC) return;
    int c = idx & (CC - 1);
    float mean = sums[c] * (1.f / NN);
    float var  = sumsq[c] * (1.f / NN) - mean * mean;
    float inv  = rsqrtf(fmaxf(var, 0.f) + BN_EPS);
    float v = (Y[idx] - mean) * inv * ldf(g, c, f32) + ldf(be, c, f32);
    X[idx] = __float2bfloat16(v > 0.f ? v : 0.f);
}

// ---------------------------------------------------------------------------
// GIN: H[d] = X[d] + sum_{s in N(d)} X[s]
// Wave-per-dst: lane l owns channels 2l,2l+1 (dword of the 256 B bf16 row).
// No LDS, no barriers; csr index loads are wave-uniform (scalar).
// ---------------------------------------------------------------------------
__global__ __launch_bounds__(256) void gin_gather_kernel(
    const unsigned* __restrict__ X1, unsigned* __restrict__ H1,
    const int* __restrict__ off, const int* __restrict__ csr)
{
    int wv = (blockIdx.x * blockDim.x + threadIdx.x) >> 6;
    int l  = threadIdx.x & 63;
    if (wv >= NN) return;
    int d = wv;
    float2 v0 = bfp(X1[(size_t)d * 64 + l]);
    float ax = v0.x, ay = v0.y;
    int b = off[d], e = off[d + 1];
    int i = b;
    for (; i + 4 <= e; i += 4) {
        int s0 = csr[i], s1 = csr[i + 1], s2 = csr[i + 2], s3 = csr[i + 3];
        unsigned w0 = X1[(size_t)s0 * 64 + l];
        unsigned w1 = X1[(size_t)s1 * 64 + l];
        unsigned w2 = X1[(size_t)s2 * 64 + l];
        unsigned w3 = X1[(size_t)s3 * 64 + l];
        float2 f0 = bfp(w0), f1 = bfp(w1), f2 = bfp(w2), f3 = bfp(w3);
        ax += f0.x + f1.x + f2.x + f3.x;
        ay += f0.y + f1.y + f2.y + f3.y;
    }
    for (; i < e; i++) {
        float2 f = bfp(X1[(size_t)csr[i] * 64 + l]);
        ax += f.x; ay += f.y;
    }
    H1[(size_t)d * 64 + l] = f2bf(make_float2(ax, ay));
}

// ---------------------------------------------------------------------------
// VAE reparameterization; MULV: [N][256] fp32 (mu | logvar), biases added here
// ---------------------------------------------------------------------------
__global__ void z_kernel(const float* __restrict__ MULV, const void* __restrict__ eps,
                         const void* __restrict__ b_mu, const void* __restrict__ b_var,
                         __hip_bfloat16* __restrict__ Z, void* __restrict__ out,
                         const int* __restrict__ flags)
{
    const int f32 = flags[0];
    int idx = blockIdx.x * blockDim.x + threadIdx.x;
    if (idx >= NN * CC) return;
    int row = idx >> 7, c = idx & 127;
    float mu = MULV[row * 256 + c] + ldf(b_mu, c, f32);
    float lv = MULV[row * 256 + 128 + c] + ldf(b_var, c, f32);
    float z = ldf(eps, idx, f32) * expf(0.5f * lv) + mu;
    Z[idx] = __float2bfloat16(z);
    stf(out, idx, z, f32);                  // zin
    stf(out, 2 * NN * CC + idx, mu, f32);   // mu
    stf(out, 3 * NN * CC + idx, lv, f32);   // logvar
}

// ---------------------------------------------------------------------------
// GAT attention scores per (node, head), bf16 HH
// ---------------------------------------------------------------------------
__global__ void att_kernel(const __hip_bfloat16* __restrict__ HHb,
                           const void* __restrict__ att_src, const void* __restrict__ att_dst,
                           float* __restrict__ AS, float* __restrict__ AD,
                           const int* __restrict__ flags)
{
    const int f32 = flags[0];
    int wid  = (blockIdx.x * blockDim.x + threadIdx.x) >> 6;
    int lane = threadIdx.x & 63;
    if (wid >= NN * 2) return;
    int n = wid >> 1, h = wid & 1;
    int base = n * 256 + h * CC;
    float v1 = b2f(HHb[base + lane]), v2 = b2f(HHb[base + lane + 64]);
    float s = v1 * ldf(att_src, h * CC + lane, f32) + v2 * ldf(att_src, h * CC + lane + 64, f32);
    float d = v1 * ldf(att_dst, h * CC + lane, f32) + v2 * ldf(att_dst, h * CC + lane + 64, f32);
#pragma unroll
    for (int off = 32; off; off >>= 1) {
        s += __shfl_down(s, off);
        d += __shfl_down(d, off);
    }
    if (lane == 0) { AS[wid] = s; AD[wid] = d; }
}

// ---------------------------------------------------------------------------
// GAT softmax stats per (node, head)
// ---------------------------------------------------------------------------
__global__ void gat_stats_kernel(const float* __restrict__ AS, const float* __restrict__ AD,
                                 const int* __restrict__ off, const int* __restrict__ csr,
                                 float* __restrict__ DMAX, float* __restrict__ DINV)
{
    int wid  = (blockIdx.x * blockDim.x + threadIdx.x) >> 6;
    int lane = threadIdx.x & 63;
    if (wid >= NN * 2) return;
    int n = wid >> 1, h = wid & 1;
    int b = off[n], e = off[n + 1];
    float adh = AD[n * 2 + h];
    float self_l = leaky02(AS[n * 2 + h] + adh);
    float m = (lane == 0) ? self_l : NEG_INF;
    for (int i = b + lane; i < e; i += 64) {
        int s = csr[i];
        m = fmaxf(m, leaky02(AS[s * 2 + h] + adh));
    }
#pragma unroll
    for (int o = 32; o; o >>= 1) m = fmaxf(m, __shfl_xor(m, o));
    float sum = (lane == 0) ? expf(self_l - m) : 0.f;
    for (int i = b + lane; i < e; i += 64) {
        int s = csr[i];
        sum += expf(leaky02(AS[s * 2 + h] + adh) - m);
    }
#pragma unroll
    for (int o = 32; o; o >>= 1) sum += __shfl_xor(sum, o);
    if (lane == 0) { DMAX[wid] = m; DINV[wid] = 1.f / sum; }
}

// ---------------------------------------------------------------------------
// GAT aggregation, wave-per-dst: lane l owns channels 4l..4l+3 (uint2 of the
// 512 B bf16 row); head = l>>5. alpha recomputed per lane (AS/AD L2-resident).
// No LDS, no barriers. OUT += b_gat fused.
// ---------------------------------------------------------------------------
__global__ __launch_bounds__(256) void gat_agg_kernel(
    const uint2* __restrict__ HH2,
    const float* __restrict__ AS, const float* __restrict__ AD,
    const float* __restrict__ DMAX, const float* __restrict__ DINV,
    const int* __restrict__ off, const int* __restrict__ csr,
    const void* __restrict__ b_gat, uint2* __restrict__ OUT2,
    const int* __restrict__ flags)
{
    const int f32 = flags[0];
    int wv = (blockIdx.x * blockDim.x + threadIdx.x) >> 6;
    int l  = threadIdx.x & 63;
    if (wv >= NN) return;
    int d = wv, h = l >> 5;
    float adh = AD[d * 2 + h];
    float m   = DMAX[d * 2 + h];
    float inv = DINV[d * 2 + h];
    // self loop
    float a0 = expf(leaky02(AS[d * 2 + h] + adh) - m) * inv;
    float4 v = bf4(HH2[(size_t)d * 64 + l]);
    float4 acc = make_float4(a0 * v.x, a0 * v.y, a0 * v.z, a0 * v.w);
    int b = off[d], e = off[d + 1];
    int i = b;
    for (; i + 4 <= e; i += 4) {
        int s0 = csr[i], s1 = csr[i + 1], s2 = csr[i + 2], s3 = csr[i + 3];
        uint2 w0 = HH2[(size_t)s0 * 64 + l];
        uint2 w1 = HH2[(size_t)s1 * 64 + l];
        uint2 w2 = HH2[(size_t)s2 * 64 + l];
        uint2 w3 = HH2[(size_t)s3 * 64 + l];
        float l0 = leaky02(AS[s0 * 2 + h] + adh);
        float l1 = leaky02(AS[s1 * 2 + h] + adh);
        float l2 = leaky02(AS[s2 * 2 + h] + adh);
        float l3 = leaky02(AS[s3 * 2 + h] + adh);
        float a1 = expf(l0 - m) * inv, a2 = expf(l1 - m) * inv;
        float a3 = expf(l2 - m) * inv, a4 = expf(l3 - m) * inv;
        float4 f0 = bf4(w0), f1 = bf4(w1), f2 = bf4(w2), f3 = bf4(w3);
        acc.x += a1 * f0.x + a2 * f1.x + a3 * f2.x + a4 * f3.x;
        acc.y += a1 * f0.y + a2 * f1.y + a3 * f2.y + a4 * f3.y;
        acc.z += a1 * f0.z + a2 * f1.z + a3 * f2.z + a4 * f3.z;
        acc.w += a1 * f0.w + a2 * f1.w + a3 * f2.w + a4 * f3.w;
    }
    for (; i < e; i++) {
        int s = csr[i];
        uint2 w = HH2[(size_t)s * 64 + l];
        float al = expf(leaky02(AS[s * 2 + h] + adh) - m) * inv;
        float4 f = bf4(w);
        acc.x += al * f.x; acc.y += al * f.y; acc.z += al * f.z; acc.w += al * f.w;
    }
    acc.x += ldf(b_gat, 4 * l + 0, f32);
    acc.y += ldf(b_gat, 4 * l + 1, f32);
    acc.z += ldf(b_gat, 4 * l + 2, f32);
    acc.w += ldf(b_gat, 4 * l + 3, f32);
    OUT2[(size_t)d * 64 + l] = f4bf(acc);
}

// ---------------------------------------------------------------------------
extern "C" void kernel_launch(void* const* d_in, const int* in_sizes, int n_in,
                              void* d_out, int out_size, void* d_ws, size_t ws_size,
                              hipStream_t stream)
{
    const void* xin    = d_in[0];
    const void* ei     = d_in[1];
    const void* eps    = d_in[2];
    const void* W_emb  = d_in[3];
    const void* b_emb  = d_in[4];
    const void* g_emb  = d_in[5];
    const void* be_emb = d_in[6];
    const void* W1     = d_in[7];
    const void* b1     = d_in[8];
    const void* g1     = d_in[9];
    const void* be1    = d_in[10];
    const void* W2     = d_in[11];
    const void* b2     = d_in[12];
    const void* W_mu   = d_in[13];
    const void* b_mu   = d_in[14];
    const void* W_var  = d_in[15];
    const void* b_var  = d_in[16];
    const void* W_gat  = d_in[17];
    const void* attS   = d_in[18];
    const void* attD   = d_in[19];
    const void* b_gat  = d_in[20];
    const void* W_dec  = d_in[21];
    const void* b_dec  = d_in[22];

    // workspace layout: 4*NB fp32 slots + tail ≈ 48.5 MB
    float* ws = (float*)d_ws;
    const size_t NB = (size_t)NN * CC;       // 2,560,000
    float* B0 = ws;                          // fp32 MULV (spans B0,B1) | bf16 HH
    float* B1 = ws + 1 * NB;                 // fp32 Y    | bf16 OUT (N x 256)
    float* B2 = ws + 2 * NB;                 // bf16 Xbf | Hbf
    float* B3 = ws + 3 * NB;                 // bf16 Zbf | Zobf
    __hip_bfloat16* Xbf   = (__hip_bfloat16*)B2;       // N x 128
    __hip_bfloat16* Hbf   = Xbf + NB;                  // N x 128
    __hip_bfloat16* Zbf   = (__hip_bfloat16*)B3;       // N x 128
    __hip_bfloat16* Zobf  = Zbf + NB;                  // N x 128
    __hip_bfloat16* HHbf  = (__hip_bfloat16*)B0;       // N x 256
    __hip_bfloat16* OUTbf = (__hip_bfloat16*)B1;       // N x 256
    float* MULV  = B0;                       // N x 256 fp32 (spans B0,B1)
    float* TAIL  = ws + 4 * NB;
    float* AS    = TAIL;                     // 40000
    float* AD    = TAIL + 40000;             // 40000
    float* DMAX  = TAIL + 80000;             // 40000
    float* DINV  = TAIL + 120000;            // 40000
    float* SUMS  = TAIL + 160000;            // 128
    float* SUMSQ = TAIL + 160128;            // 128
    int*   FLAGS = (int*)(TAIL + 160256);    // 16
    int*   BSUM  = (int*)(TAIL + 160272);    // 128
    int*   BOFF  = (int*)(TAIL + 160400);    // 128
    int*   DEG   = (int*)(TAIL + 160528);    // 20000
    int*   OFF   = DEG + 20000;              // 20008 (padded)
    int*   CUR   = OFF + 20008;              // 20000
    int*   CSR   = CUR + 20000;              // 640000
    __hip_bfloat16* WTB = (__hip_bfloat16*)(CSR + 640000);   // 143360 bf16
    __hip_bfloat16* WTemb = WTB;
    __hip_bfloat16* WT1   = WTB + R0_;
    __hip_bfloat16* WT2   = WTB + R1_;
    __hip_bfloat16* WTmuv = WTB + R2_;       // mu|var contiguous -> NC=256
    __hip_bfloat16* WTgat = WTB + R4_;
    __hip_bfloat16* WTdec = WTB + R5_;
    __hip_bfloat16* Xin   = WTB + R6_;       // NN x 96 bf16

    detect_kernel<<<1, 256, 0, stream>>>((const unsigned int*)xin,
                                         (const unsigned int*)ei, FLAGS);

    // -------- weight transpose->bf16 + padded node features --------
    wt_kernel<<<(R6_ + 255) / 256, 256, 0, stream>>>(
        W_emb, W1, W2, W_mu, W_var, W_gat, W_dec, WTB, FLAGS);
    xcvt_kernel<<<(NN * 96 + 255) / 256, 256, 0, stream>>>(xin, Xin, FLAGS);

    // -------- CSR build (sorted by destination) --------
    hipMemsetAsync(DEG, 0, NN * sizeof(int), stream);
    hist_kernel<<<(EE + 255) / 256, 256, 0, stream>>>(ei, DEG, FLAGS);
    scan1_kernel<<<NBS, 256, 0, stream>>>(DEG, BSUM);
    scan2_kernel<<<1, 128, 0, stream>>>(BSUM, BOFF, OFF);
    scan3_kernel<<<NBS, 256, 0, stream>>>(DEG, BOFF, OFF, CUR);
    scatter_kernel<<<(EE + 255) / 256, 256, 0, stream>>>(ei, CUR, CSR, FLAGS);

    // -------- Stage A: atom embedding = relu(BN(x @ W_emb + b_emb)) -> Xbf ----
    hipMemsetAsync(SUMS, 0, 2 * CC * sizeof(float), stream);
    mfma_gemm_kernel<96, 128, 2, 0><<<NN / 32, 256, 0, stream>>>(
        Xin, WTemb, b_emb, B1, 0, FLAGS);
    bn_stats_kernel<<<256, 256, 0, stream>>>(B1, SUMS, SUMSQ);
    bn_relu_kernel<<<(NN * CC) / 256, 256, 0, stream>>>(B1, Xbf, SUMS, SUMSQ, g_emb, be_emb, FLAGS);

    // -------- Stage B: GIN x2: x = W2( relu(BN(W1(x+agg))) ) --------
    for (int t = 0; t < 2; t++) {
        gin_gather_kernel<<<NN / 4, 256, 0, stream>>>(
            (const unsigned*)Xbf, (unsigned*)Hbf, OFF, CSR);
        hipMemsetAsync(SUMS, 0, 2 * CC * sizeof(float), stream);
        mfma_gemm_kernel<128, 128, 2, 0><<<NN / 32, 256, 0, stream>>>(
            Hbf, WT1, b1, B1, 0, FLAGS);
        bn_stats_kernel<<<256, 256, 0, stream>>>(B1, SUMS, SUMSQ);
        bn_relu_kernel<<<(NN * CC) / 256, 256, 0, stream>>>(B1, Hbf, SUMS, SUMSQ, g1, be1, FLAGS);
        mfma_gemm_kernel<128, 128, 2, 1><<<NN / 32, 256, 0, stream>>>(
            Hbf, WT2, b2, Xbf, 0, FLAGS);
    }

    // -------- Stage C: merged VAE heads (Xbf -> MULV fp32 N x 256) --------
    mfma_gemm_kernel<128, 256, 4, 0><<<NN / 16, 256, 0, stream>>>(
        Xbf, WTmuv, nullptr, MULV, 0, FLAGS);
    z_kernel<<<(NN * CC) / 256, 256, 0, stream>>>(MULV, eps, b_mu, b_var, Zbf, d_out, FLAGS);

    // -------- Stage D: GAT x2; decoder as MFMA GEMM --------
    const __hip_bfloat16* zc = Zbf;
    for (int t = 0; t < 2; t++) {
        mfma_gemm_kernel<128, 256, 4, 1><<<NN / 16, 256, 0, stream>>>(
            zc, WTgat, nullptr, HHbf, 0, FLAGS);
        att_kernel<<<(NN * 2) / 4, 256, 0, stream>>>(HHbf, attS, attD, AS, AD, FLAGS);
        gat_stats_kernel<<<(NN * 2) / 4, 256, 0, stream>>>(AS, AD, OFF, CSR, DMAX, DINV);
        gat_agg_kernel<<<NN / 4, 256, 0, stream>>>(
            (const uint2*)HHbf, AS, AD, DMAX, DINV, OFF, CSR, b_gat, (uint2*)OUTbf, FLAGS);
        if (t == 0) {
            mfma_gemm_kernel<256, 128, 2, 1><<<NN / 32, 256, 0, stream>>>(
                OUTbf, WTdec, b_dec, Zobf, 0, FLAGS);
            zc = Zobf;
        } else {
            mfma_gemm_kernel<256, 128, 2, 2><<<NN / 32, 256, 0, stream>>>(
                OUTbf, WTdec, b_dec, d_out, NN * CC, FLAGS);
        }
    }
}

// Round 9
// 609.083 us; speedup vs baseline: 3.9478x; 1.0225x over previous
//
#include <hip/hip_runtime.h>
#include <hip/hip_bf16.h>

// Problem constants
#define NN   20000          // nodes
#define DIN_ 92             // atom feature dim
#define CC   128            // hidden dim
#define EE   640000         // edges (self loops handled explicitly)
#define BN_EPS 1e-5f
#define NEG_INF (-3.0e38f)

typedef short short8 __attribute__((ext_vector_type(8)));
typedef float floatx4 __attribute__((ext_vector_type(4)));

// ---------------------------------------------------------------------------
// Dual-dtype helpers: flags[0]=1 -> external floats are fp32 (else bf16)
//                     flags[1]=1 -> edge_index is int64 (else int32)
// ---------------------------------------------------------------------------
static __device__ __forceinline__ float b2f(__hip_bfloat16 v) { return __bfloat162float(v); }
static __device__ __forceinline__ float ldf(const void* p, int i, int f32) {
    return f32 ? ((const float*)p)[i]
               : __bfloat162float(((const __hip_bfloat16*)p)[i]);
}
static __device__ __forceinline__ void stf(void* p, int i, float v, int f32) {
    if (f32) ((float*)p)[i] = v;
    else     ((__hip_bfloat16*)p)[i] = __float2bfloat16(v);
}
static __device__ __forceinline__ float leaky02(float x) { return x > 0.f ? x : 0.2f * x; }

// bf16 decode via bit ops (bf16 = top half of fp32)
static __device__ __forceinline__ float2 bfp(unsigned w) {
    return make_float2(__uint_as_float(w << 16), __uint_as_float(w & 0xffff0000u));
}
static __device__ __forceinline__ float4 bf4(unsigned x, unsigned y) {
    return make_float4(__uint_as_float(x << 16), __uint_as_float(x & 0xffff0000u),
                       __uint_as_float(y << 16), __uint_as_float(y & 0xffff0000u));
}
static __device__ __forceinline__ uint2 f4bf(float4 v) {
    union { uint2 u; __hip_bfloat16 b[4]; } x;
    x.b[0] = __float2bfloat16(v.x); x.b[1] = __float2bfloat16(v.y);
    x.b[2] = __float2bfloat16(v.z); x.b[3] = __float2bfloat16(v.w);
    return x.u;
}

// ---------------------------------------------------------------------------
// Runtime dtype detection
// ---------------------------------------------------------------------------
__global__ void detect_kernel(const unsigned int* __restrict__ x0,
                              const unsigned int* __restrict__ ei,
                              int* __restrict__ flags)
{
    __shared__ int cnt_band, cnt_zero;
    if (threadIdx.x == 0) { cnt_band = 0; cnt_zero = 0; }
    __syncthreads();
    unsigned w  = x0[threadIdx.x];
    unsigned eb = ((w & 0xFFFFu) >> 7) & 0xFFu;
    if (eb >= 90u && eb <= 140u) atomicAdd(&cnt_band, 1);
    if (ei[2 * threadIdx.x + 1] == 0u) atomicAdd(&cnt_zero, 1);
    __syncthreads();
    if (threadIdx.x == 0) {
        flags[0] = (cnt_band < 200) ? 1 : 0;   // 1 = fp32
        flags[1] = (cnt_zero >= 250) ? 1 : 0;  // 1 = int64
    }
}

// ---------------------------------------------------------------------------
// Merged conversion: transposed bf16 weights + padded bf16 node features
// WT[n*KP + k] = W[k*N + n] (zero-pad k>=K); mu|var contiguous -> NC=256.
// ---------------------------------------------------------------------------
#define R0_ 12288
#define R1_ (R0_ + 16384)
#define R2_ (R1_ + 16384)
#define R3_ (R2_ + 16384)
#define R4_ (R3_ + 16384)
#define R5_ (R4_ + 32768)
#define R6_ (R5_ + 32768)          // 143360 weight elements
#define TCVT (R6_ + NN * 96)       // + node features

__global__ void cvt_all_kernel(const void* __restrict__ w_emb, const void* __restrict__ w1,
                               const void* __restrict__ w2, const void* __restrict__ wmu,
                               const void* __restrict__ wvar, const void* __restrict__ wgat,
                               const void* __restrict__ wdec, const void* __restrict__ xin,
                               __hip_bfloat16* __restrict__ dst, const int* __restrict__ flags)
{
    const int f32 = flags[0];
    int i = blockIdx.x * blockDim.x + threadIdx.x;
    if (i >= TCVT) return;
    float v;
    if (i < R0_) {
        int n = i / 96, k = i - n * 96;
        v = (k < DIN_) ? ldf(w_emb, k * 128 + n, f32) : 0.f;
    } else if (i < R1_) {
        int j = i - R0_; int n = j >> 7, k = j & 127; v = ldf(w1, k * 128 + n, f32);
    } else if (i < R2_) {
        int j = i - R1_; int n = j >> 7, k = j & 127; v = ldf(w2, k * 128 + n, f32);
    } else if (i < R3_) {
        int j = i - R2_; int n = j >> 7, k = j & 127; v = ldf(wmu, k * 128 + n, f32);
    } else if (i < R4_) {
        int j = i - R3_; int n = j >> 7, k = j & 127; v = ldf(wvar, k * 128 + n, f32);
    } else if (i < R5_) {
        int j = i - R4_; int n = j >> 7, k = j & 127; v = ldf(wgat, k * 256 + n, f32);
    } else if (i < R6_) {
        int j = i - R5_; int n = j >> 8, k = j & 255; v = ldf(wdec, k * 128 + n, f32);
    } else {
        int j = i - R6_; int row = j / 96, k = j - row * 96;
        v = (k < DIN_) ? ldf(xin, row * DIN_ + k, f32) : 0.f;
    }
    dst[i] = __float2bfloat16(v);
}

// ---------------------------------------------------------------------------
// CSR build: histogram -> 3-phase scan -> scatter (sorted by dst)
// ---------------------------------------------------------------------------
#define NBS ((NN + 255) / 256)   // 79 scan blocks

__global__ void hist_kernel(const void* __restrict__ ei, int* __restrict__ deg,
                            const int* __restrict__ flags)
{
    int e = blockIdx.x * blockDim.x + threadIdx.x;
    if (e >= EE) return;
    const int i64 = flags[1];
    int d = i64 ? (int)((const long long*)ei)[EE + e] : ((const int*)ei)[EE + e];
    atomicAdd(&deg[d], 1);
}

__global__ void scan1_kernel(const int* __restrict__ deg, int* __restrict__ bsum)
{
    int idx = blockIdx.x * 256 + threadIdx.x;
    int v = (idx < NN) ? deg[idx] : 0;
#pragma unroll
    for (int o = 32; o; o >>= 1) v += __shfl_down(v, o);
    __shared__ int s[4];
    if ((threadIdx.x & 63) == 0) s[threadIdx.x >> 6] = v;
    __syncthreads();
    if (threadIdx.x == 0) bsum[blockIdx.x] = s[0] + s[1] + s[2] + s[3];
}

__global__ void scan2_kernel(const int* __restrict__ bsum, int* __restrict__ boff,
                             int* __restrict__ off)
{
    __shared__ int s[128];
    int t = threadIdx.x;
    int v = (t < NBS) ? bsum[t] : 0;
    s[t] = v;
    __syncthreads();
    for (int st = 1; st < 128; st <<= 1) {
        int u = (t >= st) ? s[t - st] : 0;
        __syncthreads();
        s[t] += u;
        __syncthreads();
    }
    if (t < NBS) boff[t] = s[t] - v;   // exclusive
    if (t == 0) off[NN] = EE;
}

__global__ void scan3_kernel(const int* __restrict__ deg, const int* __restrict__ boff,
                             int* __restrict__ off, int* __restrict__ cur)
{
    __shared__ int s[256];
    int idx = blockIdx.x * 256 + threadIdx.x;
    int t = threadIdx.x;
    int v = (idx < NN) ? deg[idx] : 0;
    s[t] = v;
    __syncthreads();
    for (int st = 1; st < 256; st <<= 1) {
        int u = (t >= st) ? s[t - st] : 0;
        __syncthreads();
        s[t] += u;
        __syncthreads();
    }
    if (idx < NN) { int o = boff[blockIdx.x] + s[t] - v; off[idx] = o; cur[idx] = o; }
}

__global__ void scatter_kernel(const void* __restrict__ ei, int* __restrict__ cur,
                               int* __restrict__ csr, const int* __restrict__ flags)
{
    int e = blockIdx.x * blockDim.x + threadIdx.x;
    if (e >= EE) return;
    const int i64 = flags[1];
    int s, d;
    if (i64) { s = (int)((const long long*)ei)[e]; d = (int)((const long long*)ei)[EE + e]; }
    else     { s = ((const int*)ei)[e];            d = ((const int*)ei)[EE + e]; }
    int pos = atomicAdd(&cur[d], 1);
    csr[pos] = s;
}

// ---------------------------------------------------------------------------
// MFMA GEMM (16x16x32 bf16): C[M,NC] = A @ W + bias.
// ---------------------------------------------------------------------------
template<int KP, int NC, int CG, int OUT_MODE>
__global__ __launch_bounds__(256) void mfma_gemm_kernel(
    const __hip_bfloat16* __restrict__ A,
    const __hip_bfloat16* __restrict__ WT,
    const void* __restrict__ bias,
    void* __restrict__ Cout, int out_off, const int* __restrict__ flags)
{
    const int f32 = flags[0];
    constexpr int MB = 16 * (4 / CG);
    constexpr int CT = NC / (16 * CG);
    int w = threadIdx.x >> 6, l = threadIdx.x & 63;
    int rt = w / CG, cg = w - rt * CG;
    int m0 = blockIdx.x * MB + rt * 16;
    int n0 = cg * (16 * CT);
    int l15 = l & 15, kq = (l >> 4) * 8;
    const __hip_bfloat16* arow = A + (size_t)(m0 + l15) * KP + kq;

    floatx4 acc[CT];
#pragma unroll
    for (int ct = 0; ct < CT; ct++) acc[ct] = (floatx4){0.f, 0.f, 0.f, 0.f};

    for (int kc = 0; kc < KP / 32; kc++) {
        short8 a = *(const short8*)(arow + kc * 32);
#pragma unroll
        for (int ct = 0; ct < CT; ct++) {
            const __hip_bfloat16* brow = WT + (size_t)(n0 + ct * 16 + l15) * KP + kq;
            short8 b = *(const short8*)(brow + kc * 32);
            acc[ct] = __builtin_amdgcn_mfma_f32_16x16x32_bf16(a, b, acc[ct], 0, 0, 0);
        }
    }

    int quad = l >> 4;
#pragma unroll
    for (int ct = 0; ct < CT; ct++) {
        int col = n0 + ct * 16 + l15;
        float bb = bias ? ldf(bias, col, f32) : 0.f;
#pragma unroll
        for (int r = 0; r < 4; r++) {
            int row = m0 + quad * 4 + r;
            float v = acc[ct][r] + bb;
            size_t o = (size_t)row * NC + col;
            if (OUT_MODE == 0)      ((float*)Cout)[o] = v;
            else if (OUT_MODE == 1) ((__hip_bfloat16*)Cout)[o] = __float2bfloat16(v);
            else                    stf(Cout, out_off + (int)o, v, f32);
        }
    }
}

// ---------------------------------------------------------------------------
// BatchNorm (training): column sums / sumsq (fp32 Y), normalize+ReLU -> bf16
// ---------------------------------------------------------------------------
__global__ void bn_stats_kernel(const float* __restrict__ Y,
                                float* __restrict__ sums, float* __restrict__ sumsq)
{
    int c  = threadIdx.x & (CC - 1);
    int rg = threadIdx.x >> 7;
    int stride = gridDim.x * 2;
    float s = 0.f, q = 0.f;
    for (int r = blockIdx.x * 2 + rg; r < NN; r += stride) {
        float v = Y[r * CC + c];
        s += v; q += v * v;
    }
    atomicAdd(&sums[c], s);
    atomicAdd(&sumsq[c], q);
}

__global__ void bn_relu_kernel(const float* __restrict__ Y, __hip_bfloat16* __restrict__ X,
                               const float* __restrict__ sums, const float* __restrict__ sumsq,
                               const void* __restrict__ g, const void* __restrict__ be,
                               const int* __restrict__ flags)
{
    const int f32 = flags[0];
    int idx = blockIdx.x * blockDim.x + threadIdx.x;
    if (idx >= NN * CC) return;
    int c = idx & (CC - 1);
    float mean = sums[c] * (1.f / NN);
    float var  = sumsq[c] * (1.f / NN) - mean * mean;
    float inv  = rsqrtf(fmaxf(var, 0.f) + BN_EPS);
    float v = (Y[idx] - mean) * inv * ldf(g, c, f32) + ldf(be, c, f32);
    X[idx] = __float2bfloat16(v > 0.f ? v : 0.f);
}

// ---------------------------------------------------------------------------
// GIN: H[d] = X[d] + sum_{s in N(d)} X[s]
// Half-wave per dst: 32 lanes x uint2 (8 B) = full 256 B bf16 row.
// ---------------------------------------------------------------------------
__global__ __launch_bounds__(256) void gin_gather_kernel(
    const uint2* __restrict__ X2, uint2* __restrict__ H2,
    const int* __restrict__ off, const int* __restrict__ csr)
{
    int hw = (blockIdx.x * blockDim.x + threadIdx.x) >> 5;
    int l5 = threadIdx.x & 31;
    if (hw >= NN) return;
    int d = hw;
    uint2 w0 = X2[(size_t)d * 32 + l5];
    float4 acc = bf4(w0.x, w0.y);
    int b = off[d], e = off[d + 1];
    int i = b;
    for (; i + 4 <= e; i += 4) {
        int s0 = csr[i], s1 = csr[i + 1], s2 = csr[i + 2], s3 = csr[i + 3];
        uint2 a0 = X2[(size_t)s0 * 32 + l5];
        uint2 a1 = X2[(size_t)s1 * 32 + l5];
        uint2 a2 = X2[(size_t)s2 * 32 + l5];
        uint2 a3 = X2[(size_t)s3 * 32 + l5];
        float4 f0 = bf4(a0.x, a0.y), f1 = bf4(a1.x, a1.y);
        float4 f2 = bf4(a2.x, a2.y), f3 = bf4(a3.x, a3.y);
        acc.x += f0.x + f1.x + f2.x + f3.x;
        acc.y += f0.y + f1.y + f2.y + f3.y;
        acc.z += f0.z + f1.z + f2.z + f3.z;
        acc.w += f0.w + f1.w + f2.w + f3.w;
    }
    for (; i < e; i++) {
        uint2 a = X2[(size_t)csr[i] * 32 + l5];
        float4 f = bf4(a.x, a.y);
        acc.x += f.x; acc.y += f.y; acc.z += f.z; acc.w += f.w;
    }
    H2[(size_t)d * 32 + l5] = f4bf(acc);
}

// ---------------------------------------------------------------------------
// VAE reparameterization; MULV: [N][256] fp32 (mu | logvar)
// ---------------------------------------------------------------------------
__global__ void z_kernel(const float* __restrict__ MULV, const void* __restrict__ eps,
                         const void* __restrict__ b_mu, const void* __restrict__ b_var,
                         __hip_bfloat16* __restrict__ Z, void* __restrict__ out,
                         const int* __restrict__ flags)
{
    const int f32 = flags[0];
    int idx = blockIdx.x * blockDim.x + threadIdx.x;
    if (idx >= NN * CC) return;
    int row = idx >> 7, c = idx & 127;
    float mu = MULV[row * 256 + c] + ldf(b_mu, c, f32);
    float lv = MULV[row * 256 + 128 + c] + ldf(b_var, c, f32);
    float z = ldf(eps, idx, f32) * expf(0.5f * lv) + mu;
    Z[idx] = __float2bfloat16(z);
    stf(out, idx, z, f32);                  // zin
    stf(out, 2 * NN * CC + idx, mu, f32);   // mu
    stf(out, 3 * NN * CC + idx, lv, f32);   // logvar
}

// ---------------------------------------------------------------------------
// GAT attention scores per (node, head), bf16 HH
// ---------------------------------------------------------------------------
__global__ void att_kernel(const __hip_bfloat16* __restrict__ HHb,
                           const void* __restrict__ att_src, const void* __restrict__ att_dst,
                           float* __restrict__ AS, float* __restrict__ AD,
                           const int* __restrict__ flags)
{
    const int f32 = flags[0];
    int wid  = (blockIdx.x * blockDim.x + threadIdx.x) >> 6;
    int lane = threadIdx.x & 63;
    if (wid >= NN * 2) return;
    int n = wid >> 1, h = wid & 1;
    int base = n * 256 + h * CC;
    float v1 = b2f(HHb[base + lane]), v2 = b2f(HHb[base + lane + 64]);
    float s = v1 * ldf(att_src, h * CC + lane, f32) + v2 * ldf(att_src, h * CC + lane + 64, f32);
    float d = v1 * ldf(att_dst, h * CC + lane, f32) + v2 * ldf(att_dst, h * CC + lane + 64, f32);
#pragma unroll
    for (int off = 32; off; off >>= 1) {
        s += __shfl_down(s, off);
        d += __shfl_down(d, off);
    }
    if (lane == 0) { AS[wid] = s; AD[wid] = d; }
}

// ---------------------------------------------------------------------------
// GAT softmax stats per (node, head) + alpha materialization:
// pass1 max, pass2 sum, pass3 write ALPHA[i*2+h] per CSR edge; SALPHA self.
// ---------------------------------------------------------------------------
__global__ void gat_stats_kernel(const float* __restrict__ AS, const float* __restrict__ AD,
                                 const int* __restrict__ off, const int* __restrict__ csr,
                                 float* __restrict__ ALPHA, float* __restrict__ SALPHA)
{
    int wid  = (blockIdx.x * blockDim.x + threadIdx.x) >> 6;
    int lane = threadIdx.x & 63;
    if (wid >= NN * 2) return;
    int n = wid >> 1, h = wid & 1;
    int b = off[n], e = off[n + 1];
    float adh = AD[n * 2 + h];
    float self_l = leaky02(AS[n * 2 + h] + adh);
    float m = (lane == 0) ? self_l : NEG_INF;
    for (int i = b + lane; i < e; i += 64) {
        int s = csr[i];
        m = fmaxf(m, leaky02(AS[s * 2 + h] + adh));
    }
#pragma unroll
    for (int o = 32; o; o >>= 1) m = fmaxf(m, __shfl_xor(m, o));
    float sum = (lane == 0) ? expf(self_l - m) : 0.f;
    for (int i = b + lane; i < e; i += 64) {
        int s = csr[i];
        sum += expf(leaky02(AS[s * 2 + h] + adh) - m);
    }
#pragma unroll
    for (int o = 32; o; o >>= 1) sum += __shfl_xor(sum, o);
    float inv = 1.f / sum;
    for (int i = b + lane; i < e; i += 64) {
        int s = csr[i];
        ALPHA[i * 2 + h] = expf(leaky02(AS[s * 2 + h] + adh) - m) * inv;
    }
    if (lane == 0) SALPHA[wid] = expf(self_l - m) * inv;
}

// ---------------------------------------------------------------------------
// GAT aggregation, half-wave per dst: 32 lanes x uint4 (16 B) = full 512 B
// bf16 row. alpha pre-materialized (ALPHA/SALPHA) -> zero expf here.
// OUT += b_gat fused.
// ---------------------------------------------------------------------------
__global__ __launch_bounds__(256) void gat_agg_kernel(
    const uint4* __restrict__ HH4,
    const float* __restrict__ ALPHA, const float* __restrict__ SALPHA,
    const int* __restrict__ off, const int* __restrict__ csr,
    const void* __restrict__ b_gat, uint4* __restrict__ OUT4,
    const int* __restrict__ flags)
{
    const int f32 = flags[0];
    int hw = (blockIdx.x * blockDim.x + threadIdx.x) >> 5;
    int l5 = threadIdx.x & 31;
    if (hw >= NN) return;
    int d = hw, h = l5 >> 4;
    uint4 wv = HH4[(size_t)d * 32 + l5];
    float a0 = SALPHA[d * 2 + h];
    float4 p = bf4(wv.x, wv.y), q = bf4(wv.z, wv.w);
    float4 accA = make_float4(a0 * p.x, a0 * p.y, a0 * p.z, a0 * p.w);
    float4 accB = make_float4(a0 * q.x, a0 * q.y, a0 * q.z, a0 * q.w);
    int b = off[d], e = off[d + 1];
    int i = b;
    for (; i + 4 <= e; i += 4) {
        uint4 w0 = HH4[(size_t)csr[i]     * 32 + l5];
        uint4 w1 = HH4[(size_t)csr[i + 1] * 32 + l5];
        uint4 w2 = HH4[(size_t)csr[i + 2] * 32 + l5];
        uint4 w3 = HH4[(size_t)csr[i + 3] * 32 + l5];
        float a1 = ALPHA[(i)     * 2 + h];
        float a2 = ALPHA[(i + 1) * 2 + h];
        float a3 = ALPHA[(i + 2) * 2 + h];
        float a4 = ALPHA[(i + 3) * 2 + h];
        float4 f;
        f = bf4(w0.x, w0.y); accA.x += a1 * f.x; accA.y += a1 * f.y; accA.z += a1 * f.z; accA.w += a1 * f.w;
        f = bf4(w0.z, w0.w); accB.x += a1 * f.x; accB.y += a1 * f.y; accB.z += a1 * f.z; accB.w += a1 * f.w;
        f = bf4(w1.x, w1.y); accA.x += a2 * f.x; accA.y += a2 * f.y; accA.z += a2 * f.z; accA.w += a2 * f.w;
        f = bf4(w1.z, w1.w); accB.x += a2 * f.x; accB.y += a2 * f.y; accB.z += a2 * f.z; accB.w += a2 * f.w;
        f = bf4(w2.x, w2.y); accA.x += a3 * f.x; accA.y += a3 * f.y; accA.z += a3 * f.z; accA.w += a3 * f.w;
        f = bf4(w2.z, w2.w); accB.x += a3 * f.x; accB.y += a3 * f.y; accB.z += a3 * f.z; accB.w += a3 * f.w;
        f = bf4(w3.x, w3.y); accA.x += a4 * f.x; accA.y += a4 * f.y; accA.z += a4 * f.z; accA.w += a4 * f.w;
        f = bf4(w3.z, w3.w); accB.x += a4 * f.x; accB.y += a4 * f.y; accB.z += a4 * f.z; accB.w += a4 * f.w;
    }
    for (; i < e; i++) {
        uint4 w = HH4[(size_t)csr[i] * 32 + l5];
        float al = ALPHA[i * 2 + h];
        float4 f = bf4(w.x, w.y);
        accA.x += al * f.x; accA.y += al * f.y; accA.z += al * f.z; accA.w += al * f.w;
        f = bf4(w.z, w.w);
        accB.x += al * f.x; accB.y += al * f.y; accB.z += al * f.z; accB.w += al * f.w;
    }
    int c0 = 8 * l5;
    accA.x += ldf(b_gat, c0 + 0, f32); accA.y += ldf(b_gat, c0 + 1, f32);
    accA.z += ldf(b_gat, c0 + 2, f32); accA.w += ldf(b_gat, c0 + 3, f32);
    accB.x += ldf(b_gat, c0 + 4, f32); accB.y += ldf(b_gat, c0 + 5, f32);
    accB.z += ldf(b_gat, c0 + 6, f32); accB.w += ldf(b_gat, c0 + 7, f32);
    uint2 oa = f4bf(accA), ob = f4bf(accB);
    uint4 o; o.x = oa.x; o.y = oa.y; o.z = ob.x; o.w = ob.y;
    OUT4[(size_t)d * 32 + l5] = o;
}

// ---------------------------------------------------------------------------
extern "C" void kernel_launch(void* const* d_in, const int* in_sizes, int n_in,
                              void* d_out, int out_size, void* d_ws, size_t ws_size,
                              hipStream_t stream)
{
    const void* xin    = d_in[0];
    const void* ei     = d_in[1];
    const void* eps    = d_in[2];
    const void* W_emb  = d_in[3];
    const void* b_emb  = d_in[4];
    const void* g_emb  = d_in[5];
    const void* be_emb = d_in[6];
    const void* W1     = d_in[7];
    const void* b1     = d_in[8];
    const void* g1     = d_in[9];
    const void* be1    = d_in[10];
    const void* W2     = d_in[11];
    const void* b2     = d_in[12];
    const void* W_mu   = d_in[13];
    const void* b_mu   = d_in[14];
    const void* W_var  = d_in[15];
    const void* b_var  = d_in[16];
    const void* W_gat  = d_in[17];
    const void* attS   = d_in[18];
    const void* attD   = d_in[19];
    const void* b_gat  = d_in[20];
    const void* W_dec  = d_in[21];
    const void* b_dec  = d_in[22];

    // workspace layout: 4*NB fp32 slots + tail ≈ 53.7 MB
    float* ws = (float*)d_ws;
    const size_t NB = (size_t)NN * CC;       // 2,560,000
    float* B0 = ws;                          // fp32 MULV (spans B0,B1) | bf16 HH
    float* B1 = ws + 1 * NB;                 // fp32 Y    | bf16 OUT (N x 256)
    float* B2 = ws + 2 * NB;                 // bf16 Xbf | Hbf
    float* B3 = ws + 3 * NB;                 // bf16 Zbf | Zobf
    __hip_bfloat16* Xbf   = (__hip_bfloat16*)B2;       // N x 128
    __hip_bfloat16* Hbf   = Xbf + NB;                  // N x 128
    __hip_bfloat16* Zbf   = (__hip_bfloat16*)B3;       // N x 128
    __hip_bfloat16* Zobf  = Zbf + NB;                  // N x 128
    __hip_bfloat16* HHbf  = (__hip_bfloat16*)B0;       // N x 256
    __hip_bfloat16* OUTbf = (__hip_bfloat16*)B1;       // N x 256
    float* MULV  = B0;                       // N x 256 fp32 (spans B0,B1)
    float* TAIL  = ws + 4 * NB;
    float* AS     = TAIL;                    // 40000
    float* AD     = TAIL + 40000;            // 40000
    float* SALPHA = TAIL + 80000;            // 40000
    int*   FLAGS  = (int*)(TAIL + 120000);   // 16
    int*   BSUM   = FLAGS + 16;              // 128
    int*   BOFF   = BSUM + 128;              // 128
    int*   DEG    = BOFF + 128;              // 20000  <- zero region start
    float* SUMS6  = (float*)(DEG + 20000);   // 768 (3 pairs, zeroed with DEG)
    int*   OFF    = (int*)(SUMS6 + 768);     // 20008 (padded)
    int*   CUR    = OFF + 20008;             // 20000
    int*   CSR    = CUR + 20000;             // 640000
    float* ALPHA  = (float*)(CSR + 640000);  // 1,280,000
    __hip_bfloat16* WTB = (__hip_bfloat16*)(ALPHA + 1280000);  // 143360 bf16
    __hip_bfloat16* WTemb = WTB;
    __hip_bfloat16* WT1   = WTB + R0_;
    __hip_bfloat16* WT2   = WTB + R1_;
    __hip_bfloat16* WTmuv = WTB + R2_;       // mu|var contiguous -> NC=256
    __hip_bfloat16* WTgat = WTB + R4_;
    __hip_bfloat16* WTdec = WTB + R5_;
    __hip_bfloat16* Xin   = WTB + R6_;       // NN x 96 bf16

    detect_kernel<<<1, 256, 0, stream>>>((const unsigned int*)xin,
                                         (const unsigned int*)ei, FLAGS);

    // -------- merged weight transpose + node-feature conversion --------
    cvt_all_kernel<<<(TCVT + 255) / 256, 256, 0, stream>>>(
        W_emb, W1, W2, W_mu, W_var, W_gat, W_dec, xin, WTB, FLAGS);

    // -------- single memset: DEG + 3 BN stats pairs --------
    hipMemsetAsync(DEG, 0, (20000 + 768) * sizeof(int), stream);

    // -------- CSR build (sorted by destination) --------
    hist_kernel<<<(EE + 255) / 256, 256, 0, stream>>>(ei, DEG, FLAGS);
    scan1_kernel<<<NBS, 256, 0, stream>>>(DEG, BSUM);
    scan2_kernel<<<1, 128, 0, stream>>>(BSUM, BOFF, OFF);
    scan3_kernel<<<NBS, 256, 0, stream>>>(DEG, BOFF, OFF, CUR);
    scatter_kernel<<<(EE + 255) / 256, 256, 0, stream>>>(ei, CUR, CSR, FLAGS);

    // -------- Stage A: atom embedding = relu(BN(x @ W_emb + b_emb)) -> Xbf ----
    mfma_gemm_kernel<96, 128, 2, 0><<<NN / 32, 256, 0, stream>>>(
        Xin, WTemb, b_emb, B1, 0, FLAGS);
    bn_stats_kernel<<<256, 256, 0, stream>>>(B1, SUMS6, SUMS6 + 128);
    bn_relu_kernel<<<(NN * CC) / 256, 256, 0, stream>>>(
        B1, Xbf, SUMS6, SUMS6 + 128, g_emb, be_emb, FLAGS);

    // -------- Stage B: GIN x2: x = W2( relu(BN(W1(x+agg))) ) --------
    for (int t = 0; t < 2; t++) {
        gin_gather_kernel<<<NN / 8, 256, 0, stream>>>(
            (const uint2*)Xbf, (uint2*)Hbf, OFF, CSR);
        mfma_gemm_kernel<128, 128, 2, 0><<<NN / 32, 256, 0, stream>>>(
            Hbf, WT1, b1, B1, 0, FLAGS);
        float* SP = SUMS6 + 256 * (t + 1);
        bn_stats_kernel<<<256, 256, 0, stream>>>(B1, SP, SP + 128);
        bn_relu_kernel<<<(NN * CC) / 256, 256, 0, stream>>>(
            B1, Hbf, SP, SP + 128, g1, be1, FLAGS);
        mfma_gemm_kernel<128, 128, 2, 1><<<NN / 32, 256, 0, stream>>>(
            Hbf, WT2, b2, Xbf, 0, FLAGS);
    }

    // -------- Stage C: merged VAE heads (Xbf -> MULV fp32 N x 256) --------
    mfma_gemm_kernel<128, 256, 4, 0><<<NN / 16, 256, 0, stream>>>(
        Xbf, WTmuv, nullptr, MULV, 0, FLAGS);
    z_kernel<<<(NN * CC) / 256, 256, 0, stream>>>(MULV, eps, b_mu, b_var, Zbf, d_out, FLAGS);

    // -------- Stage D: GAT x2; decoder as MFMA GEMM --------
    const __hip_bfloat16* zc = Zbf;
    for (int t = 0; t < 2; t++) {
        mfma_gemm_kernel<128, 256, 4, 1><<<NN / 16, 256, 0, stream>>>(
            zc, WTgat, nullptr, HHbf, 0, FLAGS);
        att_kernel<<<(NN * 2) / 4, 256, 0, stream>>>(HHbf, attS, attD, AS, AD, FLAGS);
        gat_stats_kernel<<<(NN * 2) / 4, 256, 0, stream>>>(AS, AD, OFF, CSR, ALPHA, SALPHA);
        gat_agg_kernel<<<NN / 8, 256, 0, stream>>>(
            (const uint4*)HHbf, ALPHA, SALPHA, OFF, CSR, b_gat, (uint4*)OUTbf, FLAGS);
        if (t == 0) {
            mfma_gemm_kernel<256, 128, 2, 1><<<NN / 32, 256, 0, stream>>>(
                OUTbf, WTdec, b_dec, Zobf, 0, FLAGS);
            zc = Zobf;
        } else {
            mfma_gemm_kernel<256, 128, 2, 2><<<NN / 32, 256, 0, stream>>>(
                OUTbf, WTdec, b_dec, d_out, NN * CC, FLAGS);
        }
    }
}